// Round 4
// baseline (567.067 us; speedup 1.0000x reference)
//
#include <hip/hip_runtime.h>
#include <cstdint>
#include <cstddef>

// ---------------------------------------------------------------------------
// SimpleGNN: 2x GCNConv(128->128) + ReLU, global mean pool (64 graphs),
// MLP head 128->128->128 + ReLU, L2 row-normalize. All f32.
//
// Strategy: build CSR over incoming edges once (counting sort), then each
// conv layer = dense GEMM (N x 128 @ 128 x 128) followed by a gather-sum
// aggregation (one wave per node, float2 per lane). hw buffer (25.6MB) is
// Infinity-Cache resident, so gathers are L3-served.
// ---------------------------------------------------------------------------

// ---------------- degree / CSR build ----------------

__global__ void k_indeg(const int* __restrict__ dst, int* __restrict__ indeg, int E) {
    int i = blockIdx.x * blockDim.x + threadIdx.x;
    if (i < E) atomicAdd(&indeg[dst[i]], 1);
}

__global__ void k_dinv(const int* __restrict__ indeg, float* __restrict__ dinv, int N) {
    int i = blockIdx.x * blockDim.x + threadIdx.x;
    if (i < N) dinv[i] = rsqrtf((float)(indeg[i] + 1));  // +1 self-loop
}

// inclusive block scan (Hillis-Steele) -> exclusive per-chunk offsets + block totals
__global__ void k_scan1(const int* __restrict__ indeg, int* __restrict__ off,
                        int* __restrict__ partials, int N) {
    __shared__ int s[256];
    int t = threadIdx.x;
    int i = blockIdx.x * 256 + t;
    int v = (i < N) ? indeg[i] : 0;
    s[t] = v;
    __syncthreads();
    for (int d = 1; d < 256; d <<= 1) {
        int x = (t >= d) ? s[t - d] : 0;
        __syncthreads();
        s[t] += x;
        __syncthreads();
    }
    if (i < N) off[i] = s[t] - v;            // exclusive within chunk
    if (t == 255) partials[blockIdx.x] = s[255];
}

__global__ void k_scan2(int* __restrict__ partials, int nb) {
    __shared__ int s[256];
    int t = threadIdx.x;
    int v = (t < nb) ? partials[t] : 0;
    s[t] = v;
    __syncthreads();
    for (int d = 1; d < 256; d <<= 1) {
        int x = (t >= d) ? s[t - d] : 0;
        __syncthreads();
        s[t] += x;
        __syncthreads();
    }
    if (t < nb) partials[t] = s[t] - v;      // exclusive block offsets
}

__global__ void k_scan3(int* __restrict__ off, const int* __restrict__ partials,
                        int N, int E) {
    int i = blockIdx.x * 256 + threadIdx.x;
    if (i < N) off[i] += partials[blockIdx.x];
    if (i == 0) off[N] = E;                  // total indeg == E
}

__global__ void k_fill(const int* __restrict__ src, const int* __restrict__ dst,
                       const float* __restrict__ dinv, const int* __restrict__ off,
                       int* __restrict__ fill, int* __restrict__ csr_src,
                       float* __restrict__ csr_w, int E) {
    int i = blockIdx.x * blockDim.x + threadIdx.x;
    if (i >= E) return;
    int s = src[i], d = dst[i];
    int pos = off[d] + atomicAdd(&fill[d], 1);
    csr_src[pos] = s;
    csr_w[pos]   = dinv[s] * dinv[d];        // symmetric GCN norm
}

// ---------------- dense GEMM: out[N,128] = in[N,128] @ W[128,128] ----------------
// thread computes 4 rows x 4 cols; W float4 load reused across 4 rows.

__global__ void k_gemm(const float* __restrict__ in, const float* __restrict__ W,
                       float* __restrict__ out, int N) {
    int idx = blockIdx.x * blockDim.x + threadIdx.x;
    int nrg = (N + 3) >> 2;
    if (idx >= nrg * 32) return;
    int rg   = idx >> 5;
    int c4   = (idx & 31) << 2;
    int row0 = rg << 2;

    const float* p0 = in + (size_t)row0 * 128;
    const float* p1 = in + (size_t)((row0 + 1 < N) ? row0 + 1 : row0) * 128;
    const float* p2 = in + (size_t)((row0 + 2 < N) ? row0 + 2 : row0) * 128;
    const float* p3 = in + (size_t)((row0 + 3 < N) ? row0 + 3 : row0) * 128;

    float4 a0 = {0.f, 0.f, 0.f, 0.f};
    float4 a1 = a0, a2 = a0, a3 = a0;

#pragma unroll 4
    for (int k = 0; k < 128; ++k) {
        float4 w = *reinterpret_cast<const float4*>(W + k * 128 + c4);
        float h0 = p0[k], h1 = p1[k], h2 = p2[k], h3 = p3[k];
        a0.x = fmaf(h0, w.x, a0.x); a0.y = fmaf(h0, w.y, a0.y);
        a0.z = fmaf(h0, w.z, a0.z); a0.w = fmaf(h0, w.w, a0.w);
        a1.x = fmaf(h1, w.x, a1.x); a1.y = fmaf(h1, w.y, a1.y);
        a1.z = fmaf(h1, w.z, a1.z); a1.w = fmaf(h1, w.w, a1.w);
        a2.x = fmaf(h2, w.x, a2.x); a2.y = fmaf(h2, w.y, a2.y);
        a2.z = fmaf(h2, w.z, a2.z); a2.w = fmaf(h2, w.w, a2.w);
        a3.x = fmaf(h3, w.x, a3.x); a3.y = fmaf(h3, w.y, a3.y);
        a3.z = fmaf(h3, w.z, a3.z); a3.w = fmaf(h3, w.w, a3.w);
    }
    float* o = out + (size_t)row0 * 128 + c4;
    *reinterpret_cast<float4*>(o) = a0;
    if (row0 + 1 < N) *reinterpret_cast<float4*>(o + 128) = a1;
    if (row0 + 2 < N) *reinterpret_cast<float4*>(o + 256) = a2;
    if (row0 + 3 < N) *reinterpret_cast<float4*>(o + 384) = a3;
}

// ---------------- aggregation: out[n] = relu(sum_e w_e*hw[src_e] + hw[n]*dinv^2 + b) ----
// one wave per node; lane owns 2 features (float2). Edge meta batch-loaded
// 64-at-a-time, broadcast via shuffle; gather is one coalesced 512B row.

__global__ void k_aggr(const float* __restrict__ hw, const int* __restrict__ off,
                       const int* __restrict__ csr_src, const float* __restrict__ csr_w,
                       const float* __restrict__ dinv, const float* __restrict__ bias,
                       float* __restrict__ out, int N) {
    int wid  = (blockIdx.x * blockDim.x + threadIdx.x) >> 6;
    int lane = threadIdx.x & 63;
    if (wid >= N) return;
    int n = wid;

    const float2* hw2 = reinterpret_cast<const float2*>(hw);
    float di = dinv[n];
    float sl = di * di;                       // self-loop norm
    float2 acc = hw2[(size_t)n * 64 + lane];
    acc.x *= sl; acc.y *= sl;

    int e = off[n], e1 = off[n + 1];
    while (e < e1) {
        int rem = e1 - e;
        int cnt = rem < 64 ? rem : 64;
        int   s_l = 0;
        float w_l = 0.f;
        if (lane < cnt) { s_l = csr_src[e + lane]; w_l = csr_w[e + lane]; }
        for (int j = 0; j < cnt; ++j) {
            int   s = __shfl(s_l, j);
            float w = __shfl(w_l, j);
            float2 v = hw2[(size_t)s * 64 + lane];
            acc.x = fmaf(v.x, w, acc.x);
            acc.y = fmaf(v.y, w, acc.y);
        }
        e += cnt;
    }
    float2 b = reinterpret_cast<const float2*>(bias)[lane];
    acc.x = fmaxf(acc.x + b.x, 0.f);
    acc.y = fmaxf(acc.y + b.y, 0.f);
    reinterpret_cast<float2*>(out)[(size_t)n * 64 + lane] = acc;
}

// ---------------- global mean pool (batch is sorted) ----------------
// wave processes a contiguous node range; flush atomics only on graph change.

__global__ void k_pool(const float* __restrict__ h, const int* __restrict__ batch,
                       float* __restrict__ pooled, int* __restrict__ cnt,
                       int N, int npw) {
    int wid  = (blockIdx.x * blockDim.x + threadIdx.x) >> 6;
    int lane = threadIdx.x & 63;
    int n0 = wid * npw;
    if (n0 >= N) return;
    int n1 = n0 + npw; if (n1 > N) n1 = N;

    const float2* h2 = reinterpret_cast<const float2*>(h);
    float2 acc = {0.f, 0.f};
    int g = batch[n0];
    int c = 0;
    for (int n = n0; n < n1; ++n) {
        int gn = batch[n];
        if (gn != g) {
            atomicAdd(&pooled[g * 128 + 2 * lane],     acc.x);
            atomicAdd(&pooled[g * 128 + 2 * lane + 1], acc.y);
            if (lane == 0) atomicAdd(&cnt[g], c);
            acc.x = 0.f; acc.y = 0.f; c = 0; g = gn;
        }
        float2 v = h2[(size_t)n * 64 + lane];
        acc.x += v.x; acc.y += v.y; ++c;
    }
    atomicAdd(&pooled[g * 128 + 2 * lane],     acc.x);
    atomicAdd(&pooled[g * 128 + 2 * lane + 1], acc.y);
    if (lane == 0) atomicAdd(&cnt[g], c);
}

// ---------------- MLP head + L2 normalize (tiny: 64 x 128) ----------------

__global__ void k_head(const float* __restrict__ pooled, const int* __restrict__ cnt,
                       const float* __restrict__ pW1, const float* __restrict__ pb1,
                       const float* __restrict__ pW2, const float* __restrict__ pb2,
                       float* __restrict__ out) {
    __shared__ float hg[128];
    __shared__ float z1[128];
    __shared__ float red[128];
    int g = blockIdx.x, t = threadIdx.x;   // 128 threads

    float c = fmaxf((float)cnt[g], 1.0f);
    hg[t] = pooled[g * 128 + t] / c;
    __syncthreads();

    float a = pb1[t];
#pragma unroll 8
    for (int k = 0; k < 128; ++k) a = fmaf(hg[k], pW1[k * 128 + t], a);
    z1[t] = fmaxf(a, 0.f);
    __syncthreads();

    float z = pb2[t];
#pragma unroll 8
    for (int k = 0; k < 128; ++k) z = fmaf(z1[k], pW2[k * 128 + t], z);

    red[t] = z * z;
    __syncthreads();
    for (int d = 64; d > 0; d >>= 1) {
        if (t < d) red[t] += red[t + d];
        __syncthreads();
    }
    float nrm = fmaxf(sqrtf(red[0]), 1e-12f);
    out[g * 128 + t] = z / nrm;
}

// ---------------------------------------------------------------------------

extern "C" void kernel_launch(void* const* d_in, const int* in_sizes, int n_in,
                              void* d_out, int out_size, void* d_ws, size_t ws_size,
                              hipStream_t stream) {
    const float* x    = (const float*)d_in[0];
    const int*   eidx = (const int*)  d_in[1];
    const int*   batch= (const int*)  d_in[2];
    // d_in[3] = num_graphs scalar (derive NG from out_size instead)
    const float* W1   = (const float*)d_in[4];
    const float* b1   = (const float*)d_in[5];
    const float* W2   = (const float*)d_in[6];
    const float* b2   = (const float*)d_in[7];
    const float* pW1  = (const float*)d_in[8];
    const float* pb1  = (const float*)d_in[9];
    const float* pW2  = (const float*)d_in[10];
    const float* pb2  = (const float*)d_in[11];
    float* out = (float*)d_out;

    const int N  = in_sizes[0] / 128;
    const int E  = in_sizes[1] / 2;
    const int NG = out_size / 128;

    const int* src = eidx;      // edge_index[0]
    const int* dst = eidx + E;  // edge_index[1]

    // workspace carve-up (256B aligned)
    char* p = (char*)d_ws;
    auto alloc = [&](size_t bytes) -> void* {
        void* r = (void*)p;
        p += (bytes + 255) & ~(size_t)255;
        return r;
    };
    int*   indeg    = (int*)  alloc((size_t)N * 4);
    int*   off      = (int*)  alloc((size_t)(N + 1) * 4);
    int*   fill     = (int*)  alloc((size_t)N * 4);
    float* dinv     = (float*)alloc((size_t)N * 4);
    int*   partials = (int*)  alloc(1024);
    int*   csr_src  = (int*)  alloc((size_t)E * 4);
    float* csr_w    = (float*)alloc((size_t)E * 4);
    float* bufA     = (float*)alloc((size_t)N * 128 * 4);
    float* bufB     = (float*)alloc((size_t)N * 128 * 4);
    float* pooled   = (float*)alloc((size_t)NG * 128 * 4);
    int*   cnt      = (int*)  alloc((size_t)NG * 4);

    const int eB = (E + 255) / 256;
    const int nB = (N + 255) / 256;   // 196 for N=50000; k_scan2 requires nB<=256

    hipMemsetAsync(indeg,  0, (size_t)N * 4, stream);
    hipMemsetAsync(fill,   0, (size_t)N * 4, stream);
    hipMemsetAsync(pooled, 0, (size_t)NG * 128 * 4, stream);
    hipMemsetAsync(cnt,    0, (size_t)NG * 4, stream);

    k_indeg<<<eB, 256, 0, stream>>>(dst, indeg, E);
    k_dinv <<<nB, 256, 0, stream>>>(indeg, dinv, N);
    k_scan1<<<nB, 256, 0, stream>>>(indeg, off, partials, N);
    k_scan2<<<1,  256, 0, stream>>>(partials, nB);
    k_scan3<<<nB, 256, 0, stream>>>(off, partials, N, E);
    k_fill <<<eB, 256, 0, stream>>>(src, dst, dinv, off, fill, csr_src, csr_w, E);

    const int gThreads = ((N + 3) >> 2) * 32;
    const int gB = (gThreads + 255) / 256;
    const int aB = (N + 3) / 4;       // 4 waves (nodes) per 256-thread block

    // layer 1: hw = x @ W1 ; h1 = relu(aggr(hw) + b1)
    k_gemm<<<gB, 256, 0, stream>>>(x, W1, bufA, N);
    k_aggr<<<aB, 256, 0, stream>>>(bufA, off, csr_src, csr_w, dinv, b1, bufB, N);
    // layer 2
    k_gemm<<<gB, 256, 0, stream>>>(bufB, W2, bufA, N);
    k_aggr<<<aB, 256, 0, stream>>>(bufA, off, csr_src, csr_w, dinv, b2, bufB, N);

    // mean pool
    const int NPW = 32;  // nodes per wave
    const int waves = (N + NPW - 1) / NPW;
    const int pB = (waves * 64 + 255) / 256;
    k_pool<<<pB, 256, 0, stream>>>(bufB, batch, pooled, cnt, N, NPW);

    // head
    k_head<<<NG, 128, 0, stream>>>(pooled, cnt, pW1, pb1, pW2, pb2, out);
}

// Round 5
// 500.020 us; speedup vs baseline: 1.1341x; 1.1341x over previous
//
#include <hip/hip_runtime.h>
#include <cstdint>
#include <cstddef>

// ---------------------------------------------------------------------------
// SimpleGNN: 2x GCNConv(128->128) + ReLU, global mean pool (64 graphs),
// MLP head 128->128->128 + ReLU, L2 row-normalize.
//
// R5 changes vs R4 (567us):
//  - k_fill: AoS int2 {src, w} single 8B scattered store per edge
//            (was 2x 4B -> 146MB partial-line writeback; now ~half)
//  - hw buffer (GEMM output consumed by gather) stored in bf16:
//            gather row 512B -> 256B, k_aggr FETCH ~halves.
//            Accumulation stays f32; threshold is bf16-based (4.84e-3).
// ---------------------------------------------------------------------------

// ---------------- degree / CSR build ----------------

__global__ void k_indeg(const int* __restrict__ dst, int* __restrict__ indeg, int E) {
    int i = blockIdx.x * blockDim.x + threadIdx.x;
    if (i < E) atomicAdd(&indeg[dst[i]], 1);
}

__global__ void k_dinv(const int* __restrict__ indeg, float* __restrict__ dinv, int N) {
    int i = blockIdx.x * blockDim.x + threadIdx.x;
    if (i < N) dinv[i] = rsqrtf((float)(indeg[i] + 1));  // +1 self-loop
}

// inclusive block scan (Hillis-Steele) -> exclusive per-chunk offsets + block totals
__global__ void k_scan1(const int* __restrict__ indeg, int* __restrict__ off,
                        int* __restrict__ partials, int N) {
    __shared__ int s[256];
    int t = threadIdx.x;
    int i = blockIdx.x * 256 + t;
    int v = (i < N) ? indeg[i] : 0;
    s[t] = v;
    __syncthreads();
    for (int d = 1; d < 256; d <<= 1) {
        int x = (t >= d) ? s[t - d] : 0;
        __syncthreads();
        s[t] += x;
        __syncthreads();
    }
    if (i < N) off[i] = s[t] - v;            // exclusive within chunk
    if (t == 255) partials[blockIdx.x] = s[255];
}

__global__ void k_scan2(int* __restrict__ partials, int nb) {
    __shared__ int s[256];
    int t = threadIdx.x;
    int v = (t < nb) ? partials[t] : 0;
    s[t] = v;
    __syncthreads();
    for (int d = 1; d < 256; d <<= 1) {
        int x = (t >= d) ? s[t - d] : 0;
        __syncthreads();
        s[t] += x;
        __syncthreads();
    }
    if (t < nb) partials[t] = s[t] - v;      // exclusive block offsets
}

__global__ void k_scan3(int* __restrict__ off, const int* __restrict__ partials,
                        int N, int E) {
    int i = blockIdx.x * 256 + threadIdx.x;
    if (i < N) off[i] += partials[blockIdx.x];
    if (i == 0) off[N] = E;                  // total indeg == E
}

// AoS fill: one 8B scattered store per edge {src, w}
__global__ void k_fill(const int* __restrict__ src, const int* __restrict__ dst,
                       const float* __restrict__ dinv, const int* __restrict__ off,
                       int* __restrict__ fill, int2* __restrict__ csr, int E) {
    int i = blockIdx.x * blockDim.x + threadIdx.x;
    if (i >= E) return;
    int s = src[i], d = dst[i];
    int pos = off[d] + atomicAdd(&fill[d], 1);
    int2 ew;
    ew.x = s;
    ew.y = __float_as_int(dinv[s] * dinv[d]);  // symmetric GCN norm
    csr[pos] = ew;
}

// ---------------- bf16 helpers ----------------

static __device__ __forceinline__ unsigned f2bf_rne(float f) {
    unsigned u = __float_as_uint(f);
    return (u + 0x7FFFu + ((u >> 16) & 1u)) >> 16;   // round-nearest-even
}
static __device__ __forceinline__ unsigned pack_bf2(float lo, float hi) {
    return f2bf_rne(lo) | (f2bf_rne(hi) << 16);
}
static __device__ __forceinline__ float bf_lo(unsigned v) {
    return __uint_as_float(v << 16);
}
static __device__ __forceinline__ float bf_hi(unsigned v) {
    return __uint_as_float(v & 0xFFFF0000u);
}

// ---------------- dense GEMM: hw[N,128](bf16) = in[N,128](f32) @ W[128,128] ----
// thread computes 4 rows x 4 cols; W float4 load reused across 4 rows.
// Output packed bf16 (2 per uint) for the gather stage.

__global__ void k_gemm(const float* __restrict__ in, const float* __restrict__ W,
                       unsigned* __restrict__ outbf, int N) {
    int idx = blockIdx.x * blockDim.x + threadIdx.x;
    int nrg = (N + 3) >> 2;
    if (idx >= nrg * 32) return;
    int rg   = idx >> 5;
    int c4   = (idx & 31) << 2;
    int row0 = rg << 2;

    const float* p0 = in + (size_t)row0 * 128;
    const float* p1 = in + (size_t)((row0 + 1 < N) ? row0 + 1 : row0) * 128;
    const float* p2 = in + (size_t)((row0 + 2 < N) ? row0 + 2 : row0) * 128;
    const float* p3 = in + (size_t)((row0 + 3 < N) ? row0 + 3 : row0) * 128;

    float4 a0 = {0.f, 0.f, 0.f, 0.f};
    float4 a1 = a0, a2 = a0, a3 = a0;

#pragma unroll 4
    for (int k = 0; k < 128; ++k) {
        float4 w = *reinterpret_cast<const float4*>(W + k * 128 + c4);
        float h0 = p0[k], h1 = p1[k], h2 = p2[k], h3 = p3[k];
        a0.x = fmaf(h0, w.x, a0.x); a0.y = fmaf(h0, w.y, a0.y);
        a0.z = fmaf(h0, w.z, a0.z); a0.w = fmaf(h0, w.w, a0.w);
        a1.x = fmaf(h1, w.x, a1.x); a1.y = fmaf(h1, w.y, a1.y);
        a1.z = fmaf(h1, w.z, a1.z); a1.w = fmaf(h1, w.w, a1.w);
        a2.x = fmaf(h2, w.x, a2.x); a2.y = fmaf(h2, w.y, a2.y);
        a2.z = fmaf(h2, w.z, a2.z); a2.w = fmaf(h2, w.w, a2.w);
        a3.x = fmaf(h3, w.x, a3.x); a3.y = fmaf(h3, w.y, a3.y);
        a3.z = fmaf(h3, w.z, a3.z); a3.w = fmaf(h3, w.w, a3.w);
    }
    // outbf layout: uint index = row*64 + col/2  (2 bf16 per uint)
    unsigned* o = outbf + (size_t)row0 * 64 + (c4 >> 1);
    uint2 u0 = { pack_bf2(a0.x, a0.y), pack_bf2(a0.z, a0.w) };
    *reinterpret_cast<uint2*>(o) = u0;
    if (row0 + 1 < N) {
        uint2 u1 = { pack_bf2(a1.x, a1.y), pack_bf2(a1.z, a1.w) };
        *reinterpret_cast<uint2*>(o + 64) = u1;
    }
    if (row0 + 2 < N) {
        uint2 u2 = { pack_bf2(a2.x, a2.y), pack_bf2(a2.z, a2.w) };
        *reinterpret_cast<uint2*>(o + 128) = u2;
    }
    if (row0 + 3 < N) {
        uint2 u3 = { pack_bf2(a3.x, a3.y), pack_bf2(a3.z, a3.w) };
        *reinterpret_cast<uint2*>(o + 192) = u3;
    }
}

// ---------------- aggregation ----------------
// out[n] = relu(sum_e w_e*hw[src_e] + hw[n]*dinv[n]^2 + b),  hw in bf16.
// One wave per node; lane owns 2 features (one uint = 2 bf16, 256B/row gather).
// Edge meta batch-loaded 64-at-a-time (int2 AoS), broadcast via shuffle.

__global__ void k_aggr(const unsigned* __restrict__ hw, const int* __restrict__ off,
                       const int2* __restrict__ csr, const float* __restrict__ dinv,
                       const float* __restrict__ bias, float* __restrict__ out, int N) {
    int wid  = (blockIdx.x * blockDim.x + threadIdx.x) >> 6;
    int lane = threadIdx.x & 63;
    if (wid >= N) return;
    int n = wid;

    float di = dinv[n];
    float sl = di * di;                       // self-loop norm
    unsigned v0 = hw[(size_t)n * 64 + lane];
    float accx = bf_lo(v0) * sl;
    float accy = bf_hi(v0) * sl;

    int e = off[n], e1 = off[n + 1];
    // full 64-edge batches
    while (e + 64 <= e1) {
        int2 ew = csr[e + lane];
        int   s_l = ew.x;
        float w_l = __int_as_float(ew.y);
#pragma unroll 8
        for (int j = 0; j < 64; ++j) {
            int   s = __shfl(s_l, j);
            float w = __shfl(w_l, j);
            unsigned v = hw[(size_t)s * 64 + lane];
            accx = fmaf(bf_lo(v), w, accx);
            accy = fmaf(bf_hi(v), w, accy);
        }
        e += 64;
    }
    // tail
    if (e < e1) {
        int cnt = e1 - e;
        int   s_l = 0;
        float w_l = 0.f;
        if (lane < cnt) {
            int2 ew = csr[e + lane];
            s_l = ew.x;
            w_l = __int_as_float(ew.y);
        }
        for (int j = 0; j < cnt; ++j) {
            int   s = __shfl(s_l, j);
            float w = __shfl(w_l, j);
            unsigned v = hw[(size_t)s * 64 + lane];
            accx = fmaf(bf_lo(v), w, accx);
            accy = fmaf(bf_hi(v), w, accy);
        }
    }
    float2 b = reinterpret_cast<const float2*>(bias)[lane];
    accx = fmaxf(accx + b.x, 0.f);
    accy = fmaxf(accy + b.y, 0.f);
    float2 r = {accx, accy};
    reinterpret_cast<float2*>(out)[(size_t)n * 64 + lane] = r;
}

// ---------------- global mean pool (batch is sorted) ----------------

__global__ void k_pool(const float* __restrict__ h, const int* __restrict__ batch,
                       float* __restrict__ pooled, int* __restrict__ cnt,
                       int N, int npw) {
    int wid  = (blockIdx.x * blockDim.x + threadIdx.x) >> 6;
    int lane = threadIdx.x & 63;
    int n0 = wid * npw;
    if (n0 >= N) return;
    int n1 = n0 + npw; if (n1 > N) n1 = N;

    const float2* h2 = reinterpret_cast<const float2*>(h);
    float2 acc = {0.f, 0.f};
    int g = batch[n0];
    int c = 0;
    for (int n = n0; n < n1; ++n) {
        int gn = batch[n];
        if (gn != g) {
            atomicAdd(&pooled[g * 128 + 2 * lane],     acc.x);
            atomicAdd(&pooled[g * 128 + 2 * lane + 1], acc.y);
            if (lane == 0) atomicAdd(&cnt[g], c);
            acc.x = 0.f; acc.y = 0.f; c = 0; g = gn;
        }
        float2 v = h2[(size_t)n * 64 + lane];
        acc.x += v.x; acc.y += v.y; ++c;
    }
    atomicAdd(&pooled[g * 128 + 2 * lane],     acc.x);
    atomicAdd(&pooled[g * 128 + 2 * lane + 1], acc.y);
    if (lane == 0) atomicAdd(&cnt[g], c);
}

// ---------------- MLP head + L2 normalize (tiny: 64 x 128) ----------------

__global__ void k_head(const float* __restrict__ pooled, const int* __restrict__ cnt,
                       const float* __restrict__ pW1, const float* __restrict__ pb1,
                       const float* __restrict__ pW2, const float* __restrict__ pb2,
                       float* __restrict__ out) {
    __shared__ float hg[128];
    __shared__ float z1[128];
    __shared__ float red[128];
    int g = blockIdx.x, t = threadIdx.x;   // 128 threads

    float c = fmaxf((float)cnt[g], 1.0f);
    hg[t] = pooled[g * 128 + t] / c;
    __syncthreads();

    float a = pb1[t];
#pragma unroll 8
    for (int k = 0; k < 128; ++k) a = fmaf(hg[k], pW1[k * 128 + t], a);
    z1[t] = fmaxf(a, 0.f);
    __syncthreads();

    float z = pb2[t];
#pragma unroll 8
    for (int k = 0; k < 128; ++k) z = fmaf(z1[k], pW2[k * 128 + t], z);

    red[t] = z * z;
    __syncthreads();
    for (int d = 64; d > 0; d >>= 1) {
        if (t < d) red[t] += red[t + d];
        __syncthreads();
    }
    float nrm = fmaxf(sqrtf(red[0]), 1e-12f);
    out[g * 128 + t] = z / nrm;
}

// ---------------------------------------------------------------------------

extern "C" void kernel_launch(void* const* d_in, const int* in_sizes, int n_in,
                              void* d_out, int out_size, void* d_ws, size_t ws_size,
                              hipStream_t stream) {
    const float* x    = (const float*)d_in[0];
    const int*   eidx = (const int*)  d_in[1];
    const int*   batch= (const int*)  d_in[2];
    const float* W1   = (const float*)d_in[4];
    const float* b1   = (const float*)d_in[5];
    const float* W2   = (const float*)d_in[6];
    const float* b2   = (const float*)d_in[7];
    const float* pW1  = (const float*)d_in[8];
    const float* pb1  = (const float*)d_in[9];
    const float* pW2  = (const float*)d_in[10];
    const float* pb2  = (const float*)d_in[11];
    float* out = (float*)d_out;

    const int N  = in_sizes[0] / 128;
    const int E  = in_sizes[1] / 2;
    const int NG = out_size / 128;

    const int* src = eidx;      // edge_index[0]
    const int* dst = eidx + E;  // edge_index[1]

    // workspace carve-up (256B aligned)
    char* p = (char*)d_ws;
    auto alloc = [&](size_t bytes) -> void* {
        void* r = (void*)p;
        p += (bytes + 255) & ~(size_t)255;
        return r;
    };
    int*      indeg    = (int*)     alloc((size_t)N * 4);
    int*      off      = (int*)     alloc((size_t)(N + 1) * 4);
    int*      fill     = (int*)     alloc((size_t)N * 4);
    float*    dinv     = (float*)   alloc((size_t)N * 4);
    int*      partials = (int*)     alloc(1024);
    int2*     csr      = (int2*)    alloc((size_t)E * 8);
    unsigned* bufH     = (unsigned*)alloc((size_t)N * 64 * 4);   // bf16 hw [N,128]
    float*    bufB     = (float*)   alloc((size_t)N * 128 * 4);  // f32 h
    float*    pooled   = (float*)   alloc((size_t)NG * 128 * 4);
    int*      cnt      = (int*)     alloc((size_t)NG * 4);

    const int eB = (E + 255) / 256;
    const int nB = (N + 255) / 256;   // 196 for N=50000; k_scan2 requires nB<=256

    hipMemsetAsync(indeg,  0, (size_t)N * 4, stream);
    hipMemsetAsync(fill,   0, (size_t)N * 4, stream);
    hipMemsetAsync(pooled, 0, (size_t)NG * 128 * 4, stream);
    hipMemsetAsync(cnt,    0, (size_t)NG * 4, stream);

    k_indeg<<<eB, 256, 0, stream>>>(dst, indeg, E);
    k_dinv <<<nB, 256, 0, stream>>>(indeg, dinv, N);
    k_scan1<<<nB, 256, 0, stream>>>(indeg, off, partials, N);
    k_scan2<<<1,  256, 0, stream>>>(partials, nB);
    k_scan3<<<nB, 256, 0, stream>>>(off, partials, N, E);
    k_fill <<<eB, 256, 0, stream>>>(src, dst, dinv, off, fill, csr, E);

    const int gThreads = ((N + 3) >> 2) * 32;
    const int gB = (gThreads + 255) / 256;
    const int aB = (N + 3) / 4;       // 4 waves (nodes) per 256-thread block

    // layer 1: hw = bf16(x @ W1) ; h1 = relu(aggr(hw) + b1)
    k_gemm<<<gB, 256, 0, stream>>>(x, W1, bufH, N);
    k_aggr<<<aB, 256, 0, stream>>>(bufH, off, csr, dinv, b1, bufB, N);
    // layer 2
    k_gemm<<<gB, 256, 0, stream>>>(bufB, W2, bufH, N);
    k_aggr<<<aB, 256, 0, stream>>>(bufH, off, csr, dinv, b2, bufB, N);

    // mean pool
    const int NPW = 32;  // nodes per wave
    const int waves = (N + NPW - 1) / NPW;
    const int pB = (waves * 64 + 255) / 256;
    k_pool<<<pB, 256, 0, stream>>>(bufB, batch, pooled, cnt, N, NPW);

    // head
    k_head<<<NG, 128, 0, stream>>>(pooled, cnt, pW1, pb1, pW2, pb2, out);
}

// Round 6
// 436.702 us; speedup vs baseline: 1.2985x; 1.1450x over previous
//
#include <hip/hip_runtime.h>
#include <cstdint>
#include <cstddef>

// ---------------------------------------------------------------------------
// SimpleGNN: 2x GCNConv(128->128) + ReLU, global mean pool (64 graphs),
// MLP head 128->128->128 + ReLU, L2 row-normalize.
//
// R6 changes vs R5 (500us, k_aggr 2x100us @ 23% HBM / 25% VALU = MLP-limited):
//  - k_aggr: 2 edges per iteration (half-wave per edge, uint2/lane loads)
//            -> 512B per load instr, 2x bytes in flight, ~half the
//            shuffle/issue overhead per edge. 32-bit voffset addressing.
//  - h (aggr output) stored packed bf16 -> gemm2 + pool read half the bytes,
//            aggr WRITE halves.
//  - k_fill: fill counter seeded with CSR offsets (atomicAdd returns the
//            absolute position; kills the random off[d] read per edge).
// ---------------------------------------------------------------------------

// ---------------- bf16 helpers ----------------

static __device__ __forceinline__ unsigned f2bf_rne(float f) {
    unsigned u = __float_as_uint(f);
    return (u + 0x7FFFu + ((u >> 16) & 1u)) >> 16;   // round-nearest-even
}
static __device__ __forceinline__ unsigned pack_bf2(float lo, float hi) {
    return f2bf_rne(lo) | (f2bf_rne(hi) << 16);
}
static __device__ __forceinline__ float bf_lo(unsigned v) {
    return __uint_as_float(v << 16);
}
static __device__ __forceinline__ float bf_hi(unsigned v) {
    return __uint_as_float(v & 0xFFFF0000u);
}

// ---------------- degree / CSR build ----------------

__global__ void k_indeg(const int* __restrict__ dst, int* __restrict__ indeg, int E) {
    int i = blockIdx.x * blockDim.x + threadIdx.x;
    if (i < E) atomicAdd(&indeg[dst[i]], 1);
}

__global__ void k_dinv(const int* __restrict__ indeg, float* __restrict__ dinv, int N) {
    int i = blockIdx.x * blockDim.x + threadIdx.x;
    if (i < N) dinv[i] = rsqrtf((float)(indeg[i] + 1));  // +1 self-loop
}

// inclusive block scan (Hillis-Steele) -> exclusive per-chunk offsets + block totals
__global__ void k_scan1(const int* __restrict__ indeg, int* __restrict__ off,
                        int* __restrict__ partials, int N) {
    __shared__ int s[256];
    int t = threadIdx.x;
    int i = blockIdx.x * 256 + t;
    int v = (i < N) ? indeg[i] : 0;
    s[t] = v;
    __syncthreads();
    for (int d = 1; d < 256; d <<= 1) {
        int x = (t >= d) ? s[t - d] : 0;
        __syncthreads();
        s[t] += x;
        __syncthreads();
    }
    if (i < N) off[i] = s[t] - v;            // exclusive within chunk
    if (t == 255) partials[blockIdx.x] = s[255];
}

__global__ void k_scan2(int* __restrict__ partials, int nb) {
    __shared__ int s[256];
    int t = threadIdx.x;
    int v = (t < nb) ? partials[t] : 0;
    s[t] = v;
    __syncthreads();
    for (int d = 1; d < 256; d <<= 1) {
        int x = (t >= d) ? s[t - d] : 0;
        __syncthreads();
        s[t] += x;
        __syncthreads();
    }
    if (t < nb) partials[t] = s[t] - v;      // exclusive block offsets
}

__global__ void k_scan3(int* __restrict__ off, int* __restrict__ fillcur,
                        const int* __restrict__ partials, int N, int E) {
    int i = blockIdx.x * 256 + threadIdx.x;
    if (i < N) {
        int v = off[i] + partials[blockIdx.x];
        off[i]     = v;
        fillcur[i] = v;                      // atomic cursor starts at row base
    }
    if (i == 0) off[N] = E;                  // total indeg == E
}

// AoS fill: one 8B scattered store per edge {src, w}; cursor is absolute pos.
__global__ void k_fill(const int* __restrict__ src, const int* __restrict__ dst,
                       const float* __restrict__ dinv, int* __restrict__ fillcur,
                       int2* __restrict__ csr, int E) {
    int i = blockIdx.x * blockDim.x + threadIdx.x;
    if (i >= E) return;
    int s = src[i], d = dst[i];
    int pos = atomicAdd(&fillcur[d], 1);
    int2 ew;
    ew.x = s;
    ew.y = __float_as_int(dinv[s] * dinv[d]);  // symmetric GCN norm
    csr[pos] = ew;
}

// ---------------- dense GEMM: hw[N,128](bf16) = in[N,128] @ W[128,128] ----
// Thread computes 4 rows x 4 cols, iterating K in pairs. Input either f32
// (layer 1: x) or packed bf16 (layer 2: h1). Output packed bf16.

template<bool BF16IN>
__global__ void k_gemm(const void* __restrict__ in_, const float* __restrict__ W,
                       unsigned* __restrict__ outbf, int N) {
    int idx = blockIdx.x * blockDim.x + threadIdx.x;
    int nrg = (N + 3) >> 2;
    if (idx >= nrg * 32) return;
    int rg   = idx >> 5;
    int c4   = (idx & 31) << 2;
    int row0 = rg << 2;
    int r1 = (row0 + 1 < N) ? row0 + 1 : row0;
    int r2 = (row0 + 2 < N) ? row0 + 2 : row0;
    int r3 = (row0 + 3 < N) ? row0 + 3 : row0;

    const float*    pf = (const float*)in_;
    const unsigned* pu = (const unsigned*)in_;

    float4 a0 = {0.f, 0.f, 0.f, 0.f};
    float4 a1 = a0, a2 = a0, a3 = a0;

#pragma unroll 2
    for (int ku = 0; ku < 64; ++ku) {
        float4 wA = *reinterpret_cast<const float4*>(W + (size_t)(2 * ku) * 128 + c4);
        float4 wB = *reinterpret_cast<const float4*>(W + (size_t)(2 * ku + 1) * 128 + c4);
        float h0A, h0B, h1A, h1B, h2A, h2B, h3A, h3B;
        if constexpr (BF16IN) {
            unsigned u0 = pu[(size_t)row0 * 64 + ku];
            unsigned u1 = pu[(size_t)r1   * 64 + ku];
            unsigned u2 = pu[(size_t)r2   * 64 + ku];
            unsigned u3 = pu[(size_t)r3   * 64 + ku];
            h0A = bf_lo(u0); h0B = bf_hi(u0);
            h1A = bf_lo(u1); h1B = bf_hi(u1);
            h2A = bf_lo(u2); h2B = bf_hi(u2);
            h3A = bf_lo(u3); h3B = bf_hi(u3);
        } else {
            h0A = pf[(size_t)row0 * 128 + 2 * ku]; h0B = pf[(size_t)row0 * 128 + 2 * ku + 1];
            h1A = pf[(size_t)r1   * 128 + 2 * ku]; h1B = pf[(size_t)r1   * 128 + 2 * ku + 1];
            h2A = pf[(size_t)r2   * 128 + 2 * ku]; h2B = pf[(size_t)r2   * 128 + 2 * ku + 1];
            h3A = pf[(size_t)r3   * 128 + 2 * ku]; h3B = pf[(size_t)r3   * 128 + 2 * ku + 1];
        }
        a0.x = fmaf(h0A, wA.x, a0.x); a0.y = fmaf(h0A, wA.y, a0.y);
        a0.z = fmaf(h0A, wA.z, a0.z); a0.w = fmaf(h0A, wA.w, a0.w);
        a0.x = fmaf(h0B, wB.x, a0.x); a0.y = fmaf(h0B, wB.y, a0.y);
        a0.z = fmaf(h0B, wB.z, a0.z); a0.w = fmaf(h0B, wB.w, a0.w);
        a1.x = fmaf(h1A, wA.x, a1.x); a1.y = fmaf(h1A, wA.y, a1.y);
        a1.z = fmaf(h1A, wA.z, a1.z); a1.w = fmaf(h1A, wA.w, a1.w);
        a1.x = fmaf(h1B, wB.x, a1.x); a1.y = fmaf(h1B, wB.y, a1.y);
        a1.z = fmaf(h1B, wB.z, a1.z); a1.w = fmaf(h1B, wB.w, a1.w);
        a2.x = fmaf(h2A, wA.x, a2.x); a2.y = fmaf(h2A, wA.y, a2.y);
        a2.z = fmaf(h2A, wA.z, a2.z); a2.w = fmaf(h2A, wA.w, a2.w);
        a2.x = fmaf(h2B, wB.x, a2.x); a2.y = fmaf(h2B, wB.y, a2.y);
        a2.z = fmaf(h2B, wB.z, a2.z); a2.w = fmaf(h2B, wB.w, a2.w);
        a3.x = fmaf(h3A, wA.x, a3.x); a3.y = fmaf(h3A, wA.y, a3.y);
        a3.z = fmaf(h3A, wA.z, a3.z); a3.w = fmaf(h3A, wA.w, a3.w);
        a3.x = fmaf(h3B, wB.x, a3.x); a3.y = fmaf(h3B, wB.y, a3.y);
        a3.z = fmaf(h3B, wB.z, a3.z); a3.w = fmaf(h3B, wB.w, a3.w);
    }
    // outbf: uint index = row*64 + col/2
    unsigned* o = outbf + (size_t)row0 * 64 + (c4 >> 1);
    uint2 u0 = { pack_bf2(a0.x, a0.y), pack_bf2(a0.z, a0.w) };
    *reinterpret_cast<uint2*>(o) = u0;
    if (row0 + 1 < N) {
        uint2 u1 = { pack_bf2(a1.x, a1.y), pack_bf2(a1.z, a1.w) };
        *reinterpret_cast<uint2*>(o + 64) = u1;
    }
    if (row0 + 2 < N) {
        uint2 u2 = { pack_bf2(a2.x, a2.y), pack_bf2(a2.z, a2.w) };
        *reinterpret_cast<uint2*>(o + 128) = u2;
    }
    if (row0 + 3 < N) {
        uint2 u3 = { pack_bf2(a3.x, a3.y), pack_bf2(a3.z, a3.w) };
        *reinterpret_cast<uint2*>(o + 192) = u3;
    }
}

// ---------------- aggregation ----------------
// out[n] = relu(sum_e w_e*hw[src_e] + hw[n]*dinv[n]^2 + b), hw & out bf16.
// One wave per node; 2 edges per iteration: lanes 0-31 gather edge j's row,
// lanes 32-63 edge j+1's (uint2 = 4 bf16 per lane -> 512B per load instr).
// Cross-half combine once at the end.

__global__ void k_aggr(const unsigned* __restrict__ hw, const int* __restrict__ off,
                       const int2* __restrict__ csr, const float* __restrict__ dinv,
                       const float* __restrict__ bias, unsigned* __restrict__ out, int N) {
    int wid  = (blockIdx.x * blockDim.x + threadIdx.x) >> 6;
    int lane = threadIdx.x & 63;
    if (wid >= N) return;
    int n    = wid;
    int half = lane >> 5;
    int li   = lane & 31;

    const uint2* hw2 = reinterpret_cast<const uint2*>(hw);

    float acc0 = 0.f, acc1 = 0.f, acc2 = 0.f, acc3 = 0.f;
    if (half == 0) {                          // self-loop term in half 0 only
        float di = dinv[n];
        float sl = di * di;
        uint2 v0 = hw2[(unsigned)(n << 5) + li];
        acc0 = bf_lo(v0.x) * sl;
        acc1 = bf_hi(v0.x) * sl;
        acc2 = bf_lo(v0.y) * sl;
        acc3 = bf_hi(v0.y) * sl;
    }

    int e = off[n], e1 = off[n + 1];
    while (e < e1) {
        int rem = e1 - e;
        int cnt = rem < 64 ? rem : 64;
        int   s_l = 0;
        float w_l = 0.f;
        if (lane < cnt) {
            int2 ew = csr[e + lane];
            s_l = ew.x;
            w_l = __int_as_float(ew.y);
        }
        int jn = (cnt + 1) >> 1;              // edge pairs this batch
#pragma unroll 4
        for (int j = 0; j < jn; ++j) {
            int   idx = 2 * j + half;         // >=cnt lanes see w=0 -> no-op
            int   s   = __shfl(s_l, idx);
            float w   = __shfl(w_l, idx);
            uint2 v   = hw2[(unsigned)(s << 5) + li];
            acc0 = fmaf(bf_lo(v.x), w, acc0);
            acc1 = fmaf(bf_hi(v.x), w, acc1);
            acc2 = fmaf(bf_lo(v.y), w, acc2);
            acc3 = fmaf(bf_hi(v.y), w, acc3);
        }
        e += cnt;
    }

    // combine halves: lane L(<32) += lane L+32
    acc0 += __shfl(acc0, 32 + li);
    acc1 += __shfl(acc1, 32 + li);
    acc2 += __shfl(acc2, 32 + li);
    acc3 += __shfl(acc3, 32 + li);

    if (half == 0) {
        float4 b = reinterpret_cast<const float4*>(bias)[li];
        acc0 = fmaxf(acc0 + b.x, 0.f);
        acc1 = fmaxf(acc1 + b.y, 0.f);
        acc2 = fmaxf(acc2 + b.z, 0.f);
        acc3 = fmaxf(acc3 + b.w, 0.f);
        uint2 r = { pack_bf2(acc0, acc1), pack_bf2(acc2, acc3) };
        reinterpret_cast<uint2*>(out)[(unsigned)(n << 5) + li] = r;
    }
}

// ---------------- global mean pool (batch is sorted, h in bf16) ----------------

__global__ void k_pool(const unsigned* __restrict__ h, const int* __restrict__ batch,
                       float* __restrict__ pooled, int* __restrict__ cnt,
                       int N, int npw) {
    int wid  = (blockIdx.x * blockDim.x + threadIdx.x) >> 6;
    int lane = threadIdx.x & 63;
    int n0 = wid * npw;
    if (n0 >= N) return;
    int n1 = n0 + npw; if (n1 > N) n1 = N;

    float ax = 0.f, ay = 0.f;
    int g = batch[n0];
    int c = 0;
    for (int n = n0; n < n1; ++n) {
        int gn = batch[n];
        if (gn != g) {
            atomicAdd(&pooled[g * 128 + 2 * lane],     ax);
            atomicAdd(&pooled[g * 128 + 2 * lane + 1], ay);
            if (lane == 0) atomicAdd(&cnt[g], c);
            ax = 0.f; ay = 0.f; c = 0; g = gn;
        }
        unsigned v = h[(size_t)n * 64 + lane];   // features (2*lane, 2*lane+1)
        ax += bf_lo(v); ay += bf_hi(v); ++c;
    }
    atomicAdd(&pooled[g * 128 + 2 * lane],     ax);
    atomicAdd(&pooled[g * 128 + 2 * lane + 1], ay);
    if (lane == 0) atomicAdd(&cnt[g], c);
}

// ---------------- MLP head + L2 normalize (tiny: 64 x 128) ----------------

__global__ void k_head(const float* __restrict__ pooled, const int* __restrict__ cnt,
                       const float* __restrict__ pW1, const float* __restrict__ pb1,
                       const float* __restrict__ pW2, const float* __restrict__ pb2,
                       float* __restrict__ out) {
    __shared__ float hg[128];
    __shared__ float z1[128];
    __shared__ float red[128];
    int g = blockIdx.x, t = threadIdx.x;   // 128 threads

    float c = fmaxf((float)cnt[g], 1.0f);
    hg[t] = pooled[g * 128 + t] / c;
    __syncthreads();

    float a = pb1[t];
#pragma unroll 8
    for (int k = 0; k < 128; ++k) a = fmaf(hg[k], pW1[k * 128 + t], a);
    z1[t] = fmaxf(a, 0.f);
    __syncthreads();

    float z = pb2[t];
#pragma unroll 8
    for (int k = 0; k < 128; ++k) z = fmaf(z1[k], pW2[k * 128 + t], z);

    red[t] = z * z;
    __syncthreads();
    for (int d = 64; d > 0; d >>= 1) {
        if (t < d) red[t] += red[t + d];
        __syncthreads();
    }
    float nrm = fmaxf(sqrtf(red[0]), 1e-12f);
    out[g * 128 + t] = z / nrm;
}

// ---------------------------------------------------------------------------

extern "C" void kernel_launch(void* const* d_in, const int* in_sizes, int n_in,
                              void* d_out, int out_size, void* d_ws, size_t ws_size,
                              hipStream_t stream) {
    const float* x    = (const float*)d_in[0];
    const int*   eidx = (const int*)  d_in[1];
    const int*   batch= (const int*)  d_in[2];
    const float* W1   = (const float*)d_in[4];
    const float* b1   = (const float*)d_in[5];
    const float* W2   = (const float*)d_in[6];
    const float* b2   = (const float*)d_in[7];
    const float* pW1  = (const float*)d_in[8];
    const float* pb1  = (const float*)d_in[9];
    const float* pW2  = (const float*)d_in[10];
    const float* pb2  = (const float*)d_in[11];
    float* out = (float*)d_out;

    const int N  = in_sizes[0] / 128;
    const int E  = in_sizes[1] / 2;
    const int NG = out_size / 128;

    const int* src = eidx;      // edge_index[0]
    const int* dst = eidx + E;  // edge_index[1]

    // workspace carve-up (256B aligned)
    char* p = (char*)d_ws;
    auto alloc = [&](size_t bytes) -> void* {
        void* r = (void*)p;
        p += (bytes + 255) & ~(size_t)255;
        return r;
    };
    int*      indeg    = (int*)     alloc((size_t)N * 4);
    int*      off      = (int*)     alloc((size_t)(N + 1) * 4);
    int*      fillcur  = (int*)     alloc((size_t)N * 4);
    float*    dinv     = (float*)   alloc((size_t)N * 4);
    int*      partials = (int*)     alloc(1024);
    int2*     csr      = (int2*)    alloc((size_t)E * 8);
    unsigned* bufH     = (unsigned*)alloc((size_t)N * 64 * 4);   // bf16 hw [N,128]
    unsigned* bufB     = (unsigned*)alloc((size_t)N * 64 * 4);   // bf16 h  [N,128]
    float*    pooled   = (float*)   alloc((size_t)NG * 128 * 4);
    int*      cnt      = (int*)     alloc((size_t)NG * 4);

    const int eB = (E + 255) / 256;
    const int nB = (N + 255) / 256;   // 196 for N=50000; k_scan2 requires nB<=256

    hipMemsetAsync(indeg,  0, (size_t)N * 4, stream);
    hipMemsetAsync(pooled, 0, (size_t)NG * 128 * 4, stream);
    hipMemsetAsync(cnt,    0, (size_t)NG * 4, stream);

    k_indeg<<<eB, 256, 0, stream>>>(dst, indeg, E);
    k_dinv <<<nB, 256, 0, stream>>>(indeg, dinv, N);
    k_scan1<<<nB, 256, 0, stream>>>(indeg, off, partials, N);
    k_scan2<<<1,  256, 0, stream>>>(partials, nB);
    k_scan3<<<nB, 256, 0, stream>>>(off, fillcur, partials, N, E);
    k_fill <<<eB, 256, 0, stream>>>(src, dst, dinv, fillcur, csr, E);

    const int gThreads = ((N + 3) >> 2) * 32;
    const int gB = (gThreads + 255) / 256;
    const int aB = (N + 3) / 4;       // 4 waves (nodes) per 256-thread block

    // layer 1: hw = bf16(x @ W1) ; h1 = bf16(relu(aggr(hw) + b1))
    k_gemm<false><<<gB, 256, 0, stream>>>((const void*)x, W1, bufH, N);
    k_aggr<<<aB, 256, 0, stream>>>(bufH, off, csr, dinv, b1, bufB, N);
    // layer 2
    k_gemm<true><<<gB, 256, 0, stream>>>((const void*)bufB, W2, bufH, N);
    k_aggr<<<aB, 256, 0, stream>>>(bufH, off, csr, dinv, b2, bufB, N);

    // mean pool
    const int NPW = 32;  // nodes per wave
    const int waves = (N + NPW - 1) / NPW;
    const int pB = (waves * 64 + 255) / 256;
    k_pool<<<pB, 256, 0, stream>>>(bufB, batch, pooled, cnt, N, NPW);

    // head
    k_head<<<NG, 128, 0, stream>>>(pooled, cnt, pW1, pb1, pW2, pb2, out);
}

// Round 7
// 399.184 us; speedup vs baseline: 1.4206x; 1.0940x over previous
//
#include <hip/hip_runtime.h>
#include <cstdint>
#include <cstddef>

// ---------------------------------------------------------------------------
// SimpleGNN: 2x GCNConv(128->128) + ReLU, global mean pool (64 graphs),
// MLP head 128->128->128 + ReLU, L2 row-normalize.
//
// R7 changes vs R6 (437us; k_fill 96us @ WRITE 102MB = 8x writeback amp):
//  - CSR build split into locality-preserving two-pass binning:
//      k_bin:   tile-histogram + chunked reservation -> bucket buffer
//               (bucket = 256 consecutive dst nodes; contiguous ~21-entry
//               chunks per block -> full-line writebacks)
//      k_fill2: one block per bucket; 64KB CSR region + 1KB cursors live in
//               ONE XCD's L2 -> lines fully dirtied before eviction.
//  - k_aggr: 4 edges per wave-iteration (quarter-wave x uint4 per row)
//            -> loads/edge halve again, shuffles/edge halve.
// ---------------------------------------------------------------------------

// ---------------- bf16 helpers ----------------

static __device__ __forceinline__ unsigned f2bf_rne(float f) {
    unsigned u = __float_as_uint(f);
    return (u + 0x7FFFu + ((u >> 16) & 1u)) >> 16;   // round-nearest-even
}
static __device__ __forceinline__ unsigned pack_bf2(float lo, float hi) {
    return f2bf_rne(lo) | (f2bf_rne(hi) << 16);
}
static __device__ __forceinline__ float bf_lo(unsigned v) {
    return __uint_as_float(v << 16);
}
static __device__ __forceinline__ float bf_hi(unsigned v) {
    return __uint_as_float(v & 0xFFFF0000u);
}

// ---------------- degree / CSR offsets ----------------

__global__ void k_indeg(const int* __restrict__ dst, int* __restrict__ indeg, int E) {
    int i = blockIdx.x * blockDim.x + threadIdx.x;
    if (i < E) atomicAdd(&indeg[dst[i]], 1);
}

__global__ void k_dinv(const int* __restrict__ indeg, float* __restrict__ dinv, int N) {
    int i = blockIdx.x * blockDim.x + threadIdx.x;
    if (i < N) dinv[i] = rsqrtf((float)(indeg[i] + 1));  // +1 self-loop
}

__global__ void k_scan1(const int* __restrict__ indeg, int* __restrict__ off,
                        int* __restrict__ partials, int N) {
    __shared__ int s[256];
    int t = threadIdx.x;
    int i = blockIdx.x * 256 + t;
    int v = (i < N) ? indeg[i] : 0;
    s[t] = v;
    __syncthreads();
    for (int d = 1; d < 256; d <<= 1) {
        int x = (t >= d) ? s[t - d] : 0;
        __syncthreads();
        s[t] += x;
        __syncthreads();
    }
    if (i < N) off[i] = s[t] - v;            // exclusive within chunk
    if (t == 255) partials[blockIdx.x] = s[255];
}

__global__ void k_scan2(int* __restrict__ partials, int nb) {
    __shared__ int s[256];
    int t = threadIdx.x;
    int v = (t < nb) ? partials[t] : 0;
    s[t] = v;
    __syncthreads();
    for (int d = 1; d < 256; d <<= 1) {
        int x = (t >= d) ? s[t - d] : 0;
        __syncthreads();
        s[t] += x;
        __syncthreads();
    }
    if (t < nb) partials[t] = s[t] - v;      // exclusive block offsets
}

__global__ void k_scan3(int* __restrict__ off, int* __restrict__ fillcur,
                        const int* __restrict__ partials, int N, int E) {
    int i = blockIdx.x * 256 + threadIdx.x;
    if (i < N) {
        int v = off[i] + partials[blockIdx.x];
        off[i]     = v;
        fillcur[i] = v;                      // atomic cursor starts at row base
    }
    if (i == 0) off[N] = E;                  // total indeg == E
}

// bucket cursor init: bucket b = nodes [b*256, (b+1)*256); region base = off[b*256]
__global__ void k_binit(const int* __restrict__ off, int* __restrict__ bcur, int NB) {
    int b = blockIdx.x * blockDim.x + threadIdx.x;
    if (b < NB) bcur[b] = off[b << 8];
}

// ---------------- pass 1: coarse binning (tile histogram + chunk reservation) ----
// 256 threads x 16 edges = 4096-edge tile. Each (block,bucket) reserves one
// contiguous chunk -> full-line writebacks.

__global__ void k_bin(const int* __restrict__ src, const int* __restrict__ dst,
                      int* __restrict__ bcur, int2* __restrict__ bkt,
                      int E, int NB) {
    __shared__ int cnt[512];
    __shared__ int pos[512];
    int t = threadIdx.x;
    int base_i = blockIdx.x * 4096;

    for (int k = t; k < NB; k += 256) cnt[k] = 0;
    __syncthreads();

    int  b_[16];
    int2 e_[16];
#pragma unroll
    for (int j = 0; j < 16; ++j) {
        int i = base_i + j * 256 + t;        // coalesced
        if (i < E) {
            int s = src[i], d = dst[i];
            e_[j].x = s; e_[j].y = d;
            int b = d >> 8;
            b_[j] = b;
            atomicAdd(&cnt[b], 1);
        } else {
            b_[j] = -1;
        }
    }
    __syncthreads();

    for (int k = t; k < NB; k += 256) {
        int c = cnt[k];
        pos[k] = c ? atomicAdd(&bcur[k], c) : 0;
    }
    __syncthreads();

#pragma unroll
    for (int j = 0; j < 16; ++j) {
        if (b_[j] >= 0) {
            int p = atomicAdd(&pos[b_[j]], 1);
            bkt[p] = e_[j];
        }
    }
}

// ---------------- pass 2: fine placement within bucket (one block per bucket) ----
// CSR region (~64KB) + cursor slice (1KB) are single-XCD-L2 resident.

__global__ void k_fill2(const int2* __restrict__ bkt, const int* __restrict__ off,
                        const float* __restrict__ dinv, int* __restrict__ fillcur,
                        int2* __restrict__ csr, int N) {
    int b  = blockIdx.x;
    int n0 = b << 8;
    int n1 = n0 + 256; if (n1 > N) n1 = N;
    int e0 = off[n0], e1 = off[n1];
    for (int i = e0 + threadIdx.x; i < e1; i += blockDim.x) {
        int2 ed = bkt[i];
        int s = ed.x, d = ed.y;
        int p = atomicAdd(&fillcur[d], 1);
        int2 ew;
        ew.x = s;
        ew.y = __float_as_int(dinv[s] * dinv[d]);
        csr[p] = ew;
    }
}

// ---------------- dense GEMM: hw[N,128](bf16) = in[N,128] @ W[128,128] ----

template<bool BF16IN>
__global__ void k_gemm(const void* __restrict__ in_, const float* __restrict__ W,
                       unsigned* __restrict__ outbf, int N) {
    int idx = blockIdx.x * blockDim.x + threadIdx.x;
    int nrg = (N + 3) >> 2;
    if (idx >= nrg * 32) return;
    int rg   = idx >> 5;
    int c4   = (idx & 31) << 2;
    int row0 = rg << 2;
    int r1 = (row0 + 1 < N) ? row0 + 1 : row0;
    int r2 = (row0 + 2 < N) ? row0 + 2 : row0;
    int r3 = (row0 + 3 < N) ? row0 + 3 : row0;

    const float*    pf = (const float*)in_;
    const unsigned* pu = (const unsigned*)in_;

    float4 a0 = {0.f, 0.f, 0.f, 0.f};
    float4 a1 = a0, a2 = a0, a3 = a0;

#pragma unroll 2
    for (int ku = 0; ku < 64; ++ku) {
        float4 wA = *reinterpret_cast<const float4*>(W + (size_t)(2 * ku) * 128 + c4);
        float4 wB = *reinterpret_cast<const float4*>(W + (size_t)(2 * ku + 1) * 128 + c4);
        float h0A, h0B, h1A, h1B, h2A, h2B, h3A, h3B;
        if constexpr (BF16IN) {
            unsigned u0 = pu[(size_t)row0 * 64 + ku];
            unsigned u1 = pu[(size_t)r1   * 64 + ku];
            unsigned u2 = pu[(size_t)r2   * 64 + ku];
            unsigned u3 = pu[(size_t)r3   * 64 + ku];
            h0A = bf_lo(u0); h0B = bf_hi(u0);
            h1A = bf_lo(u1); h1B = bf_hi(u1);
            h2A = bf_lo(u2); h2B = bf_hi(u2);
            h3A = bf_lo(u3); h3B = bf_hi(u3);
        } else {
            h0A = pf[(size_t)row0 * 128 + 2 * ku]; h0B = pf[(size_t)row0 * 128 + 2 * ku + 1];
            h1A = pf[(size_t)r1   * 128 + 2 * ku]; h1B = pf[(size_t)r1   * 128 + 2 * ku + 1];
            h2A = pf[(size_t)r2   * 128 + 2 * ku]; h2B = pf[(size_t)r2   * 128 + 2 * ku + 1];
            h3A = pf[(size_t)r3   * 128 + 2 * ku]; h3B = pf[(size_t)r3   * 128 + 2 * ku + 1];
        }
        a0.x = fmaf(h0A, wA.x, a0.x); a0.y = fmaf(h0A, wA.y, a0.y);
        a0.z = fmaf(h0A, wA.z, a0.z); a0.w = fmaf(h0A, wA.w, a0.w);
        a0.x = fmaf(h0B, wB.x, a0.x); a0.y = fmaf(h0B, wB.y, a0.y);
        a0.z = fmaf(h0B, wB.z, a0.z); a0.w = fmaf(h0B, wB.w, a0.w);
        a1.x = fmaf(h1A, wA.x, a1.x); a1.y = fmaf(h1A, wA.y, a1.y);
        a1.z = fmaf(h1A, wA.z, a1.z); a1.w = fmaf(h1A, wA.w, a1.w);
        a1.x = fmaf(h1B, wB.x, a1.x); a1.y = fmaf(h1B, wB.y, a1.y);
        a1.z = fmaf(h1B, wB.z, a1.z); a1.w = fmaf(h1B, wB.w, a1.w);
        a2.x = fmaf(h2A, wA.x, a2.x); a2.y = fmaf(h2A, wA.y, a2.y);
        a2.z = fmaf(h2A, wA.z, a2.z); a2.w = fmaf(h2A, wA.w, a2.w);
        a2.x = fmaf(h2B, wB.x, a2.x); a2.y = fmaf(h2B, wB.y, a2.y);
        a2.z = fmaf(h2B, wB.z, a2.z); a2.w = fmaf(h2B, wB.w, a2.w);
        a3.x = fmaf(h3A, wA.x, a3.x); a3.y = fmaf(h3A, wA.y, a3.y);
        a3.z = fmaf(h3A, wA.z, a3.z); a3.w = fmaf(h3A, wA.w, a3.w);
        a3.x = fmaf(h3B, wB.x, a3.x); a3.y = fmaf(h3B, wB.y, a3.y);
        a3.z = fmaf(h3B, wB.z, a3.z); a3.w = fmaf(h3B, wB.w, a3.w);
    }
    unsigned* o = outbf + (size_t)row0 * 64 + (c4 >> 1);
    uint2 u0 = { pack_bf2(a0.x, a0.y), pack_bf2(a0.z, a0.w) };
    *reinterpret_cast<uint2*>(o) = u0;
    if (row0 + 1 < N) {
        uint2 u1 = { pack_bf2(a1.x, a1.y), pack_bf2(a1.z, a1.w) };
        *reinterpret_cast<uint2*>(o + 64) = u1;
    }
    if (row0 + 2 < N) {
        uint2 u2 = { pack_bf2(a2.x, a2.y), pack_bf2(a2.z, a2.w) };
        *reinterpret_cast<uint2*>(o + 128) = u2;
    }
    if (row0 + 3 < N) {
        uint2 u3 = { pack_bf2(a3.x, a3.y), pack_bf2(a3.z, a3.w) };
        *reinterpret_cast<uint2*>(o + 192) = u3;
    }
}

// ---------------- aggregation ----------------
// out[n] = relu(sum_e w_e*hw[src_e] + hw[n]*dinv[n]^2 + b), hw & out bf16.
// One wave per node; 4 edges per iteration: quarter-wave (16 lanes x uint4
// = 256B) gathers one full row. Cross-quarter combine once at the end.

__global__ void k_aggr(const unsigned* __restrict__ hw, const int* __restrict__ off,
                       const int2* __restrict__ csr, const float* __restrict__ dinv,
                       const float* __restrict__ bias, unsigned* __restrict__ out, int N) {
    int wid  = (blockIdx.x * blockDim.x + threadIdx.x) >> 6;
    int lane = threadIdx.x & 63;
    if (wid >= N) return;
    int n  = wid;
    int q  = lane >> 4;                       // quarter 0..3
    int li = lane & 15;                       // lane owns cols 8*li .. 8*li+7

    const uint4* hw4 = reinterpret_cast<const uint4*>(hw);

    float a0 = 0.f, a1 = 0.f, a2 = 0.f, a3 = 0.f;
    float a4 = 0.f, a5 = 0.f, a6 = 0.f, a7 = 0.f;
    if (q == 0) {                             // self-loop term in quarter 0 only
        float di = dinv[n];
        float sl = di * di;
        uint4 v = hw4[(unsigned)(n << 4) + li];
        a0 = bf_lo(v.x) * sl; a1 = bf_hi(v.x) * sl;
        a2 = bf_lo(v.y) * sl; a3 = bf_hi(v.y) * sl;
        a4 = bf_lo(v.z) * sl; a5 = bf_hi(v.z) * sl;
        a6 = bf_lo(v.w) * sl; a7 = bf_hi(v.w) * sl;
    }

    int e = off[n], e1 = off[n + 1];
    while (e < e1) {
        int rem = e1 - e;
        int cnt = rem < 64 ? rem : 64;
        int   s_l = 0;
        float w_l = 0.f;
        if (lane < cnt) {
            int2 ew = csr[e + lane];
            s_l = ew.x;
            w_l = __int_as_float(ew.y);
        }
        int jn = (cnt + 3) >> 2;              // edge quads this batch
#pragma unroll 4
        for (int j = 0; j < jn; ++j) {
            int   idx = 4 * j + q;            // idx>=cnt lanes see w=0 -> no-op
            int   s   = __shfl(s_l, idx);
            float w   = __shfl(w_l, idx);
            uint4 v   = hw4[(unsigned)(s << 4) + li];
            a0 = fmaf(bf_lo(v.x), w, a0); a1 = fmaf(bf_hi(v.x), w, a1);
            a2 = fmaf(bf_lo(v.y), w, a2); a3 = fmaf(bf_hi(v.y), w, a3);
            a4 = fmaf(bf_lo(v.z), w, a4); a5 = fmaf(bf_hi(v.z), w, a5);
            a6 = fmaf(bf_lo(v.w), w, a6); a7 = fmaf(bf_hi(v.w), w, a7);
        }
        e += cnt;
    }

    // combine quarters: q0+=q2, q1+=q3 (partner +32), then q0+=q1 (+16)
    int p1 = (lane + 32) & 63;
    a0 += __shfl(a0, p1); a1 += __shfl(a1, p1);
    a2 += __shfl(a2, p1); a3 += __shfl(a3, p1);
    a4 += __shfl(a4, p1); a5 += __shfl(a5, p1);
    a6 += __shfl(a6, p1); a7 += __shfl(a7, p1);
    int p2 = (lane + 16) & 63;
    a0 += __shfl(a0, p2); a1 += __shfl(a1, p2);
    a2 += __shfl(a2, p2); a3 += __shfl(a3, p2);
    a4 += __shfl(a4, p2); a5 += __shfl(a5, p2);
    a6 += __shfl(a6, p2); a7 += __shfl(a7, p2);

    if (q == 0) {
        const float4* b4 = reinterpret_cast<const float4*>(bias);
        float4 bA = b4[2 * li], bB = b4[2 * li + 1];
        a0 = fmaxf(a0 + bA.x, 0.f); a1 = fmaxf(a1 + bA.y, 0.f);
        a2 = fmaxf(a2 + bA.z, 0.f); a3 = fmaxf(a3 + bA.w, 0.f);
        a4 = fmaxf(a4 + bB.x, 0.f); a5 = fmaxf(a5 + bB.y, 0.f);
        a6 = fmaxf(a6 + bB.z, 0.f); a7 = fmaxf(a7 + bB.w, 0.f);
        uint4 r = { pack_bf2(a0, a1), pack_bf2(a2, a3),
                    pack_bf2(a4, a5), pack_bf2(a6, a7) };
        reinterpret_cast<uint4*>(out)[(unsigned)(n << 4) + li] = r;
    }
}

// ---------------- global mean pool (batch is sorted, h in bf16) ----------------

__global__ void k_pool(const unsigned* __restrict__ h, const int* __restrict__ batch,
                       float* __restrict__ pooled, int* __restrict__ cnt,
                       int N, int npw) {
    int wid  = (blockIdx.x * blockDim.x + threadIdx.x) >> 6;
    int lane = threadIdx.x & 63;
    int n0 = wid * npw;
    if (n0 >= N) return;
    int n1 = n0 + npw; if (n1 > N) n1 = N;

    float ax = 0.f, ay = 0.f;
    int g = batch[n0];
    int c = 0;
    for (int n = n0; n < n1; ++n) {
        int gn = batch[n];
        if (gn != g) {
            atomicAdd(&pooled[g * 128 + 2 * lane],     ax);
            atomicAdd(&pooled[g * 128 + 2 * lane + 1], ay);
            if (lane == 0) atomicAdd(&cnt[g], c);
            ax = 0.f; ay = 0.f; c = 0; g = gn;
        }
        unsigned v = h[(size_t)n * 64 + lane];
        ax += bf_lo(v); ay += bf_hi(v); ++c;
    }
    atomicAdd(&pooled[g * 128 + 2 * lane],     ax);
    atomicAdd(&pooled[g * 128 + 2 * lane + 1], ay);
    if (lane == 0) atomicAdd(&cnt[g], c);
}

// ---------------- MLP head + L2 normalize (tiny: 64 x 128) ----------------

__global__ void k_head(const float* __restrict__ pooled, const int* __restrict__ cnt,
                       const float* __restrict__ pW1, const float* __restrict__ pb1,
                       const float* __restrict__ pW2, const float* __restrict__ pb2,
                       float* __restrict__ out) {
    __shared__ float hg[128];
    __shared__ float z1[128];
    __shared__ float red[128];
    int g = blockIdx.x, t = threadIdx.x;   // 128 threads

    float c = fmaxf((float)cnt[g], 1.0f);
    hg[t] = pooled[g * 128 + t] / c;
    __syncthreads();

    float a = pb1[t];
#pragma unroll 8
    for (int k = 0; k < 128; ++k) a = fmaf(hg[k], pW1[k * 128 + t], a);
    z1[t] = fmaxf(a, 0.f);
    __syncthreads();

    float z = pb2[t];
#pragma unroll 8
    for (int k = 0; k < 128; ++k) z = fmaf(z1[k], pW2[k * 128 + t], z);

    red[t] = z * z;
    __syncthreads();
    for (int d = 64; d > 0; d >>= 1) {
        if (t < d) red[t] += red[t + d];
        __syncthreads();
    }
    float nrm = fmaxf(sqrtf(red[0]), 1e-12f);
    out[g * 128 + t] = z / nrm;
}

// ---------------------------------------------------------------------------

extern "C" void kernel_launch(void* const* d_in, const int* in_sizes, int n_in,
                              void* d_out, int out_size, void* d_ws, size_t ws_size,
                              hipStream_t stream) {
    const float* x    = (const float*)d_in[0];
    const int*   eidx = (const int*)  d_in[1];
    const int*   batch= (const int*)  d_in[2];
    const float* W1   = (const float*)d_in[4];
    const float* b1   = (const float*)d_in[5];
    const float* W2   = (const float*)d_in[6];
    const float* b2   = (const float*)d_in[7];
    const float* pW1  = (const float*)d_in[8];
    const float* pb1  = (const float*)d_in[9];
    const float* pW2  = (const float*)d_in[10];
    const float* pb2  = (const float*)d_in[11];
    float* out = (float*)d_out;

    const int N  = in_sizes[0] / 128;
    const int E  = in_sizes[1] / 2;
    const int NG = out_size / 128;
    const int NB = (N + 255) >> 8;    // coarse buckets of 256 nodes (<=512)

    const int* src = eidx;      // edge_index[0]
    const int* dst = eidx + E;  // edge_index[1]

    // workspace carve-up (256B aligned)
    char* p = (char*)d_ws;
    auto alloc = [&](size_t bytes) -> void* {
        void* r = (void*)p;
        p += (bytes + 255) & ~(size_t)255;
        return r;
    };
    int*      indeg    = (int*)     alloc((size_t)N * 4);
    int*      off      = (int*)     alloc((size_t)(N + 1) * 4);
    int*      fillcur  = (int*)     alloc((size_t)N * 4);
    float*    dinv     = (float*)   alloc((size_t)N * 4);
    int*      partials = (int*)     alloc(1024);
    int*      bcur     = (int*)     alloc((size_t)NB * 4);
    int2*     bkt      = (int2*)    alloc((size_t)E * 8);        // binned {src,dst}
    int2*     csr      = (int2*)    alloc((size_t)E * 8);        // {src, w}
    unsigned* bufH     = (unsigned*)alloc((size_t)N * 64 * 4);   // bf16 hw [N,128]
    unsigned* bufB     = (unsigned*)alloc((size_t)N * 64 * 4);   // bf16 h  [N,128]
    float*    pooled   = (float*)   alloc((size_t)NG * 128 * 4);
    int*      cnt      = (int*)     alloc((size_t)NG * 4);

    const int eB = (E + 255) / 256;
    const int nB = (N + 255) / 256;   // k_scan2 requires nB<=256

    hipMemsetAsync(indeg,  0, (size_t)N * 4, stream);
    hipMemsetAsync(pooled, 0, (size_t)NG * 128 * 4, stream);
    hipMemsetAsync(cnt,    0, (size_t)NG * 4, stream);

    k_indeg<<<eB, 256, 0, stream>>>(dst, indeg, E);
    k_dinv <<<nB, 256, 0, stream>>>(indeg, dinv, N);
    k_scan1<<<nB, 256, 0, stream>>>(indeg, off, partials, N);
    k_scan2<<<1,  256, 0, stream>>>(partials, nB);
    k_scan3<<<nB, 256, 0, stream>>>(off, fillcur, partials, N, E);
    k_binit<<<(NB + 255) / 256, 256, 0, stream>>>(off, bcur, NB);
    k_bin  <<<(E + 4095) / 4096, 256, 0, stream>>>(src, dst, bcur, bkt, E, NB);
    k_fill2<<<NB, 1024, 0, stream>>>(bkt, off, dinv, fillcur, csr, N);

    const int gThreads = ((N + 3) >> 2) * 32;
    const int gB = (gThreads + 255) / 256;
    const int aB = (N + 3) / 4;       // 4 waves (nodes) per 256-thread block

    // layer 1: hw = bf16(x @ W1) ; h1 = bf16(relu(aggr(hw) + b1))
    k_gemm<false><<<gB, 256, 0, stream>>>((const void*)x, W1, bufH, N);
    k_aggr<<<aB, 256, 0, stream>>>(bufH, off, csr, dinv, b1, bufB, N);
    // layer 2
    k_gemm<true><<<gB, 256, 0, stream>>>((const void*)bufB, W2, bufH, N);
    k_aggr<<<aB, 256, 0, stream>>>(bufH, off, csr, dinv, b2, bufB, N);

    // mean pool
    const int NPW = 32;  // nodes per wave
    const int waves = (N + NPW - 1) / NPW;
    const int pB = (waves * 64 + 255) / 256;
    k_pool<<<pB, 256, 0, stream>>>(bufB, batch, pooled, cnt, N, NPW);

    // head
    k_head<<<NG, 128, 0, stream>>>(pooled, cnt, pW1, pb1, pW2, pb2, out);
}

// Round 8
// 309.287 us; speedup vs baseline: 1.8335x; 1.2907x over previous
//
#include <hip/hip_runtime.h>
#include <cstdint>
#include <cstddef>

// ---------------------------------------------------------------------------
// SimpleGNN: 2x GCNConv(128->128) + ReLU, global mean pool (64 graphs),
// MLP head 128->128->128 + ReLU, L2 row-normalize.
//
// R8 changes vs R7 (399us; k_indeg 70us @ WRITE 50MB = E device-atomics):
//  - NO per-edge global atomics anywhere:
//      k_bincount: tiled LDS histogram -> NB-granular global adds (~77K)
//      k_bscan:    scan 196 bucket counts -> bucket bases
//      k_bin:      chunk-reserved scatter of PACKED 4B edges (src|dlocal<<16)
//      k_fill2:    per-bucket LDS histogram + LDS scan + LDS cursors ->
//                  off[], dinv[], csr[] (src-only, 4B/edge). k_indeg, k_dinv,
//                  k_scan1/2/3, fillcur all deleted.
//  - dinv folded into GEMM output: hw'[s] = dinv[s]*(h@W)[s];
//      out[d] = relu(dinv[d]*(sum hw'[src] + hw'[d]) + b)  -> no edge weight.
//      Tail lanes broadcast index N -> zeroed dummy row in bufH.
// Assumes N < 65536 (src packs in 16 bits; N=50000 here).
// ---------------------------------------------------------------------------

// ---------------- bf16 helpers ----------------

static __device__ __forceinline__ unsigned f2bf_rne(float f) {
    unsigned u = __float_as_uint(f);
    return (u + 0x7FFFu + ((u >> 16) & 1u)) >> 16;   // round-nearest-even
}
static __device__ __forceinline__ unsigned pack_bf2(float lo, float hi) {
    return f2bf_rne(lo) | (f2bf_rne(hi) << 16);
}
static __device__ __forceinline__ float bf_lo(unsigned v) {
    return __uint_as_float(v << 16);
}
static __device__ __forceinline__ float bf_hi(unsigned v) {
    return __uint_as_float(v & 0xFFFF0000u);
}

// ---------------- pass 0: bucket counts (bucket = 256 consecutive dst) ----

__global__ void k_bincount(const int* __restrict__ dst, int* __restrict__ bcnt,
                           int E, int NB) {
    __shared__ int h[256];
    int t = threadIdx.x;
    h[t] = 0;
    __syncthreads();
    int base_i = blockIdx.x * 4096;
#pragma unroll
    for (int j = 0; j < 16; ++j) {
        int i = base_i + j * 256 + t;
        if (i < E) atomicAdd(&h[dst[i] >> 8], 1);
    }
    __syncthreads();
    if (t < NB && h[t]) atomicAdd(&bcnt[t], h[t]);
}

// scan bucket counts -> bbase[0..NB], init bcur. NB <= 256.
__global__ void k_bscan(const int* __restrict__ bcnt, int* __restrict__ bbase,
                        int* __restrict__ bcur, int NB) {
    __shared__ int s[256];
    int t = threadIdx.x;
    int v = (t < NB) ? bcnt[t] : 0;
    s[t] = v;
    __syncthreads();
    for (int d = 1; d < 256; d <<= 1) {
        int x = (t >= d) ? s[t - d] : 0;
        __syncthreads();
        s[t] += x;
        __syncthreads();
    }
    if (t < NB) {
        int excl = s[t] - v;
        bbase[t] = excl;
        bcur[t]  = excl;
        if (t == NB - 1) bbase[NB] = s[t];   // total == E
    }
}

// ---------------- pass 1: coarse binning (packed 4B edges) ----------------

__global__ void k_bin(const int* __restrict__ src, const int* __restrict__ dst,
                      int* __restrict__ bcur, int* __restrict__ bkt,
                      int E, int NB) {
    __shared__ int cnt[256];
    __shared__ int pos[256];
    int t = threadIdx.x;
    int base_i = blockIdx.x * 4096;

    cnt[t] = 0;
    __syncthreads();

    int b_[16];
    int v_[16];
#pragma unroll
    for (int j = 0; j < 16; ++j) {
        int i = base_i + j * 256 + t;        // coalesced
        if (i < E) {
            int s = src[i], d = dst[i];
            v_[j] = s | ((d & 255) << 16);   // src(16b) | dlocal(8b)
            int b = d >> 8;
            b_[j] = b;
            atomicAdd(&cnt[b], 1);
        } else {
            b_[j] = -1;
        }
    }
    __syncthreads();

    if (t < NB) {
        int c = cnt[t];
        pos[t] = c ? atomicAdd(&bcur[t], c) : 0;
    }
    __syncthreads();

#pragma unroll
    for (int j = 0; j < 16; ++j) {
        if (b_[j] >= 0) {
            int p = atomicAdd(&pos[b_[j]], 1);
            bkt[p] = v_[j];
        }
    }
}

// ---------------- pass 2: per-bucket local CSR build ----------------
// One block per bucket. LDS histogram -> LDS scan -> off/dinv (coalesced),
// then LDS-cursor placement of src-only csr. Zero global atomics.

__global__ void k_fill2(const int* __restrict__ bkt, const int* __restrict__ bbase,
                        int* __restrict__ off, float* __restrict__ dinv,
                        int* __restrict__ csr, int N, int E, int NB) {
    __shared__ int hist[256];
    __shared__ int loff[256];
    __shared__ int cur[256];
    int b = blockIdx.x, t = threadIdx.x;     // 1024 threads
    if (t < 256) hist[t] = 0;
    __syncthreads();

    int e0 = bbase[b], e1 = bbase[b + 1];
    for (int i = e0 + t; i < e1; i += 1024)
        atomicAdd(&hist[(bkt[i] >> 16) & 255], 1);
    __syncthreads();

    // Hillis-Steele inclusive scan of hist into loff (all threads sync)
    if (t < 256) loff[t] = hist[t];
    __syncthreads();
    for (int d = 1; d < 256; d <<= 1) {
        int x = 0;
        if (t < 256 && t >= d) x = loff[t - d];
        __syncthreads();
        if (t < 256) loff[t] += x;
        __syncthreads();
    }

    if (t < 256) {
        int n = (b << 8) + t;
        if (n < N) {
            int base = e0 + loff[t] - hist[t];   // exclusive
            off[n]  = base;
            cur[t]  = base;
            dinv[n] = rsqrtf((float)(hist[t] + 1));  // +1 self-loop
        }
    }
    if (b == NB - 1 && t == 0) off[N] = E;
    __syncthreads();

    for (int i = e0 + t; i < e1; i += 1024) {
        int v  = bkt[i];
        int dl = (v >> 16) & 255;
        int p  = atomicAdd(&cur[dl], 1);     // LDS atomic
        csr[p] = v & 0xFFFF;                 // src only
    }
}

// ---------------- dense GEMM: hw'[N,128](bf16) = dinv[row]*(in @ W) ----------

template<bool BF16IN>
__global__ void k_gemm(const void* __restrict__ in_, const float* __restrict__ W,
                       const float* __restrict__ dinv, unsigned* __restrict__ outbf,
                       int N) {
    int idx = blockIdx.x * blockDim.x + threadIdx.x;
    int nrg = (N + 3) >> 2;
    if (idx >= nrg * 32) return;
    int rg   = idx >> 5;
    int c4   = (idx & 31) << 2;
    int row0 = rg << 2;
    int r1 = (row0 + 1 < N) ? row0 + 1 : row0;
    int r2 = (row0 + 2 < N) ? row0 + 2 : row0;
    int r3 = (row0 + 3 < N) ? row0 + 3 : row0;

    const float*    pf = (const float*)in_;
    const unsigned* pu = (const unsigned*)in_;

    float4 a0 = {0.f, 0.f, 0.f, 0.f};
    float4 a1 = a0, a2 = a0, a3 = a0;

#pragma unroll 2
    for (int ku = 0; ku < 64; ++ku) {
        float4 wA = *reinterpret_cast<const float4*>(W + (size_t)(2 * ku) * 128 + c4);
        float4 wB = *reinterpret_cast<const float4*>(W + (size_t)(2 * ku + 1) * 128 + c4);
        float h0A, h0B, h1A, h1B, h2A, h2B, h3A, h3B;
        if constexpr (BF16IN) {
            unsigned u0 = pu[(size_t)row0 * 64 + ku];
            unsigned u1 = pu[(size_t)r1   * 64 + ku];
            unsigned u2 = pu[(size_t)r2   * 64 + ku];
            unsigned u3 = pu[(size_t)r3   * 64 + ku];
            h0A = bf_lo(u0); h0B = bf_hi(u0);
            h1A = bf_lo(u1); h1B = bf_hi(u1);
            h2A = bf_lo(u2); h2B = bf_hi(u2);
            h3A = bf_lo(u3); h3B = bf_hi(u3);
        } else {
            h0A = pf[(size_t)row0 * 128 + 2 * ku]; h0B = pf[(size_t)row0 * 128 + 2 * ku + 1];
            h1A = pf[(size_t)r1   * 128 + 2 * ku]; h1B = pf[(size_t)r1   * 128 + 2 * ku + 1];
            h2A = pf[(size_t)r2   * 128 + 2 * ku]; h2B = pf[(size_t)r2   * 128 + 2 * ku + 1];
            h3A = pf[(size_t)r3   * 128 + 2 * ku]; h3B = pf[(size_t)r3   * 128 + 2 * ku + 1];
        }
        a0.x = fmaf(h0A, wA.x, a0.x); a0.y = fmaf(h0A, wA.y, a0.y);
        a0.z = fmaf(h0A, wA.z, a0.z); a0.w = fmaf(h0A, wA.w, a0.w);
        a0.x = fmaf(h0B, wB.x, a0.x); a0.y = fmaf(h0B, wB.y, a0.y);
        a0.z = fmaf(h0B, wB.z, a0.z); a0.w = fmaf(h0B, wB.w, a0.w);
        a1.x = fmaf(h1A, wA.x, a1.x); a1.y = fmaf(h1A, wA.y, a1.y);
        a1.z = fmaf(h1A, wA.z, a1.z); a1.w = fmaf(h1A, wA.w, a1.w);
        a1.x = fmaf(h1B, wB.x, a1.x); a1.y = fmaf(h1B, wB.y, a1.y);
        a1.z = fmaf(h1B, wB.z, a1.z); a1.w = fmaf(h1B, wB.w, a1.w);
        a2.x = fmaf(h2A, wA.x, a2.x); a2.y = fmaf(h2A, wA.y, a2.y);
        a2.z = fmaf(h2A, wA.z, a2.z); a2.w = fmaf(h2A, wA.w, a2.w);
        a2.x = fmaf(h2B, wB.x, a2.x); a2.y = fmaf(h2B, wB.y, a2.y);
        a2.z = fmaf(h2B, wB.z, a2.z); a2.w = fmaf(h2B, wB.w, a2.w);
        a3.x = fmaf(h3A, wA.x, a3.x); a3.y = fmaf(h3A, wA.y, a3.y);
        a3.z = fmaf(h3A, wA.z, a3.z); a3.w = fmaf(h3A, wA.w, a3.w);
        a3.x = fmaf(h3B, wB.x, a3.x); a3.y = fmaf(h3B, wB.y, a3.y);
        a3.z = fmaf(h3B, wB.z, a3.z); a3.w = fmaf(h3B, wB.w, a3.w);
    }
    float d0 = dinv[row0], d1 = dinv[r1], d2 = dinv[r2], d3 = dinv[r3];
    unsigned* o = outbf + (size_t)row0 * 64 + (c4 >> 1);
    uint2 u0 = { pack_bf2(a0.x * d0, a0.y * d0), pack_bf2(a0.z * d0, a0.w * d0) };
    *reinterpret_cast<uint2*>(o) = u0;
    if (row0 + 1 < N) {
        uint2 u1 = { pack_bf2(a1.x * d1, a1.y * d1), pack_bf2(a1.z * d1, a1.w * d1) };
        *reinterpret_cast<uint2*>(o + 64) = u1;
    }
    if (row0 + 2 < N) {
        uint2 u2 = { pack_bf2(a2.x * d2, a2.y * d2), pack_bf2(a2.z * d2, a2.w * d2) };
        *reinterpret_cast<uint2*>(o + 128) = u2;
    }
    if (row0 + 3 < N) {
        uint2 u3 = { pack_bf2(a3.x * d3, a3.y * d3), pack_bf2(a3.z * d3, a3.w * d3) };
        *reinterpret_cast<uint2*>(o + 192) = u3;
    }
}

// ---------------- aggregation ----------------
// out[n] = relu(dinv[n]*(sum_e hw'[src_e] + hw'[n]) + b), hw' & out bf16.
// One wave per node; 4 edges per iteration (quarter-wave x uint4 = 256B/row).
// Tail lanes broadcast index N -> zeroed dummy row.

__global__ void k_aggr(const unsigned* __restrict__ hw, const int* __restrict__ off,
                       const int* __restrict__ csr, const float* __restrict__ dinv,
                       const float* __restrict__ bias, unsigned* __restrict__ out, int N) {
    int wid  = (blockIdx.x * blockDim.x + threadIdx.x) >> 6;
    int lane = threadIdx.x & 63;
    if (wid >= N) return;
    int n  = wid;
    int q  = lane >> 4;                       // quarter 0..3
    int li = lane & 15;                       // lane owns cols 8*li .. 8*li+7

    const uint4* hw4 = reinterpret_cast<const uint4*>(hw);

    float a0 = 0.f, a1 = 0.f, a2 = 0.f, a3 = 0.f;
    float a4 = 0.f, a5 = 0.f, a6 = 0.f, a7 = 0.f;
    if (q == 0) {                             // self term hw'[n] in quarter 0
        uint4 v = hw4[(unsigned)(n << 4) + li];
        a0 = bf_lo(v.x); a1 = bf_hi(v.x);
        a2 = bf_lo(v.y); a3 = bf_hi(v.y);
        a4 = bf_lo(v.z); a5 = bf_hi(v.z);
        a6 = bf_lo(v.w); a7 = bf_hi(v.w);
    }

    int e = off[n], e1 = off[n + 1];
    while (e < e1) {
        int rem = e1 - e;
        int cnt = rem < 64 ? rem : 64;
        int s_l = N;                          // invalid -> zero row
        if (lane < cnt) s_l = csr[e + lane];
        int jn = (cnt + 3) >> 2;              // edge quads this batch
#pragma unroll 4
        for (int j = 0; j < jn; ++j) {
            int   s = __shfl(s_l, 4 * j + q); // idx>=cnt lanes hold N -> zeros
            uint4 v = hw4[(unsigned)(s << 4) + li];
            a0 += bf_lo(v.x); a1 += bf_hi(v.x);
            a2 += bf_lo(v.y); a3 += bf_hi(v.y);
            a4 += bf_lo(v.z); a5 += bf_hi(v.z);
            a6 += bf_lo(v.w); a7 += bf_hi(v.w);
        }
        e += cnt;
    }

    // combine quarters: q0+=q2, q1+=q3 (partner +32), then q0+=q1 (+16)
    int p1 = (lane + 32) & 63;
    a0 += __shfl(a0, p1); a1 += __shfl(a1, p1);
    a2 += __shfl(a2, p1); a3 += __shfl(a3, p1);
    a4 += __shfl(a4, p1); a5 += __shfl(a5, p1);
    a6 += __shfl(a6, p1); a7 += __shfl(a7, p1);
    int p2 = (lane + 16) & 63;
    a0 += __shfl(a0, p2); a1 += __shfl(a1, p2);
    a2 += __shfl(a2, p2); a3 += __shfl(a3, p2);
    a4 += __shfl(a4, p2); a5 += __shfl(a5, p2);
    a6 += __shfl(a6, p2); a7 += __shfl(a7, p2);

    if (q == 0) {
        float di = dinv[n];
        const float4* b4 = reinterpret_cast<const float4*>(bias);
        float4 bA = b4[2 * li], bB = b4[2 * li + 1];
        a0 = fmaxf(fmaf(a0, di, bA.x), 0.f); a1 = fmaxf(fmaf(a1, di, bA.y), 0.f);
        a2 = fmaxf(fmaf(a2, di, bA.z), 0.f); a3 = fmaxf(fmaf(a3, di, bA.w), 0.f);
        a4 = fmaxf(fmaf(a4, di, bB.x), 0.f); a5 = fmaxf(fmaf(a5, di, bB.y), 0.f);
        a6 = fmaxf(fmaf(a6, di, bB.z), 0.f); a7 = fmaxf(fmaf(a7, di, bB.w), 0.f);
        uint4 r = { pack_bf2(a0, a1), pack_bf2(a2, a3),
                    pack_bf2(a4, a5), pack_bf2(a6, a7) };
        reinterpret_cast<uint4*>(out)[(unsigned)(n << 4) + li] = r;
    }
}

// ---------------- global mean pool (batch is sorted, h in bf16) ----------------

__global__ void k_pool(const unsigned* __restrict__ h, const int* __restrict__ batch,
                       float* __restrict__ pooled, int* __restrict__ cnt,
                       int N, int npw) {
    int wid  = (blockIdx.x * blockDim.x + threadIdx.x) >> 6;
    int lane = threadIdx.x & 63;
    int n0 = wid * npw;
    if (n0 >= N) return;
    int n1 = n0 + npw; if (n1 > N) n1 = N;

    float ax = 0.f, ay = 0.f;
    int g = batch[n0];
    int c = 0;
    for (int n = n0; n < n1; ++n) {
        int gn = batch[n];
        if (gn != g) {
            atomicAdd(&pooled[g * 128 + 2 * lane],     ax);
            atomicAdd(&pooled[g * 128 + 2 * lane + 1], ay);
            if (lane == 0) atomicAdd(&cnt[g], c);
            ax = 0.f; ay = 0.f; c = 0; g = gn;
        }
        unsigned v = h[(size_t)n * 64 + lane];
        ax += bf_lo(v); ay += bf_hi(v); ++c;
    }
    atomicAdd(&pooled[g * 128 + 2 * lane],     ax);
    atomicAdd(&pooled[g * 128 + 2 * lane + 1], ay);
    if (lane == 0) atomicAdd(&cnt[g], c);
}

// ---------------- MLP head + L2 normalize (tiny: 64 x 128) ----------------

__global__ void k_head(const float* __restrict__ pooled, const int* __restrict__ cnt,
                       const float* __restrict__ pW1, const float* __restrict__ pb1,
                       const float* __restrict__ pW2, const float* __restrict__ pb2,
                       float* __restrict__ out) {
    __shared__ float hg[128];
    __shared__ float z1[128];
    __shared__ float red[128];
    int g = blockIdx.x, t = threadIdx.x;   // 128 threads

    float c = fmaxf((float)cnt[g], 1.0f);
    hg[t] = pooled[g * 128 + t] / c;
    __syncthreads();

    float a = pb1[t];
#pragma unroll 8
    for (int k = 0; k < 128; ++k) a = fmaf(hg[k], pW1[k * 128 + t], a);
    z1[t] = fmaxf(a, 0.f);
    __syncthreads();

    float z = pb2[t];
#pragma unroll 8
    for (int k = 0; k < 128; ++k) z = fmaf(z1[k], pW2[k * 128 + t], z);

    red[t] = z * z;
    __syncthreads();
    for (int d = 64; d > 0; d >>= 1) {
        if (t < d) red[t] += red[t + d];
        __syncthreads();
    }
    float nrm = fmaxf(sqrtf(red[0]), 1e-12f);
    out[g * 128 + t] = z / nrm;
}

// ---------------------------------------------------------------------------

extern "C" void kernel_launch(void* const* d_in, const int* in_sizes, int n_in,
                              void* d_out, int out_size, void* d_ws, size_t ws_size,
                              hipStream_t stream) {
    const float* x    = (const float*)d_in[0];
    const int*   eidx = (const int*)  d_in[1];
    const int*   batch= (const int*)  d_in[2];
    const float* W1   = (const float*)d_in[4];
    const float* b1   = (const float*)d_in[5];
    const float* W2   = (const float*)d_in[6];
    const float* b2   = (const float*)d_in[7];
    const float* pW1  = (const float*)d_in[8];
    const float* pb1  = (const float*)d_in[9];
    const float* pW2  = (const float*)d_in[10];
    const float* pb2  = (const float*)d_in[11];
    float* out = (float*)d_out;

    const int N  = in_sizes[0] / 128;
    const int E  = in_sizes[1] / 2;
    const int NG = out_size / 128;
    const int NB = (N + 255) >> 8;    // buckets of 256 nodes; NB<=256 (N<65536)

    const int* src = eidx;      // edge_index[0]
    const int* dst = eidx + E;  // edge_index[1]

    // workspace carve-up (256B aligned)
    char* p = (char*)d_ws;
    auto alloc = [&](size_t bytes) -> void* {
        void* r = (void*)p;
        p += (bytes + 255) & ~(size_t)255;
        return r;
    };
    int*      bcnt     = (int*)     alloc((size_t)NB * 4);
    int*      bbase    = (int*)     alloc((size_t)(NB + 1) * 4);
    int*      bcur     = (int*)     alloc((size_t)NB * 4);
    int*      off      = (int*)     alloc((size_t)(N + 1) * 4);
    float*    dinv     = (float*)   alloc((size_t)N * 4);
    int*      bkt      = (int*)     alloc((size_t)E * 4);        // packed edges
    int*      csr      = (int*)     alloc((size_t)E * 4);        // src only
    unsigned* bufH     = (unsigned*)alloc((size_t)(N + 1) * 64 * 4); // bf16 hw' (+zero row)
    unsigned* bufB     = (unsigned*)alloc((size_t)N * 64 * 4);       // bf16 h
    float*    pooled   = (float*)   alloc((size_t)NG * 128 * 4);
    int*      cnt      = (int*)     alloc((size_t)NG * 4);

    const int tB = (E + 4095) / 4096;   // 4096-edge tiles

    hipMemsetAsync(bcnt,   0, (size_t)NB * 4, stream);
    hipMemsetAsync(bufH + (size_t)N * 64, 0, 256, stream);   // zero dummy row
    hipMemsetAsync(pooled, 0, (size_t)NG * 128 * 4, stream);
    hipMemsetAsync(cnt,    0, (size_t)NG * 4, stream);

    // CSR build: count -> scan -> bin -> per-bucket local fill
    k_bincount<<<tB, 256, 0, stream>>>(dst, bcnt, E, NB);
    k_bscan   <<<1, 256, 0, stream>>>(bcnt, bbase, bcur, NB);
    k_bin     <<<tB, 256, 0, stream>>>(src, dst, bcur, bkt, E, NB);
    k_fill2   <<<NB, 1024, 0, stream>>>(bkt, bbase, off, dinv, csr, N, E, NB);

    const int gThreads = ((N + 3) >> 2) * 32;
    const int gB = (gThreads + 255) / 256;
    const int aB = (N + 3) / 4;       // 4 waves (nodes) per 256-thread block

    // layer 1: hw' = bf16(dinv*(x @ W1)) ; h1 = bf16(relu(dinv*aggr + b1))
    k_gemm<false><<<gB, 256, 0, stream>>>((const void*)x, W1, dinv, bufH, N);
    k_aggr<<<aB, 256, 0, stream>>>(bufH, off, csr, dinv, b1, bufB, N);
    // layer 2
    k_gemm<true><<<gB, 256, 0, stream>>>((const void*)bufB, W2, dinv, bufH, N);
    k_aggr<<<aB, 256, 0, stream>>>(bufH, off, csr, dinv, b2, bufB, N);

    // mean pool
    const int NPW = 32;  // nodes per wave
    const int waves = (N + NPW - 1) / NPW;
    const int pB = (waves * 64 + 255) / 256;
    k_pool<<<pB, 256, 0, stream>>>(bufB, batch, pooled, cnt, N, NPW);

    // head
    k_head<<<NG, 128, 0, stream>>>(pooled, cnt, pW1, pb1, pW2, pb2, out);
}

// Round 9
// 279.353 us; speedup vs baseline: 2.0299x; 1.1072x over previous
//
#include <hip/hip_runtime.h>
#include <cstdint>
#include <cstddef>

// ---------------------------------------------------------------------------
// SimpleGNN: 2x GCNConv(128->128) + ReLU, global mean pool (64 graphs),
// MLP head 128->128->128 + ReLU, L2 row-normalize.
//
// R9 changes vs R8 (309us; k_gemm 2x65us latency-bound: VALU 21%, HBM 3%,
// 128 global W-loads/thread thrashing L1 + 256 scalar input loads):
//  - k_gemm: W staged in LDS (f32, 64KB, no extra rounding); input loads
//            vectorized (uint4 = 8 bf16 / 2x float4 per 8-k chunk).
//            512-thread blocks, 64 rows/block, 2 blocks/CU.
// Everything else unchanged from R8.
// ---------------------------------------------------------------------------

// ---------------- bf16 helpers ----------------

static __device__ __forceinline__ unsigned f2bf_rne(float f) {
    unsigned u = __float_as_uint(f);
    return (u + 0x7FFFu + ((u >> 16) & 1u)) >> 16;   // round-nearest-even
}
static __device__ __forceinline__ unsigned pack_bf2(float lo, float hi) {
    return f2bf_rne(lo) | (f2bf_rne(hi) << 16);
}
static __device__ __forceinline__ float bf_lo(unsigned v) {
    return __uint_as_float(v << 16);
}
static __device__ __forceinline__ float bf_hi(unsigned v) {
    return __uint_as_float(v & 0xFFFF0000u);
}

// ---------------- pass 0: bucket counts (bucket = 256 consecutive dst) ----

__global__ void k_bincount(const int* __restrict__ dst, int* __restrict__ bcnt,
                           int E, int NB) {
    __shared__ int h[256];
    int t = threadIdx.x;
    h[t] = 0;
    __syncthreads();
    int base_i = blockIdx.x * 4096;
#pragma unroll
    for (int j = 0; j < 16; ++j) {
        int i = base_i + j * 256 + t;
        if (i < E) atomicAdd(&h[dst[i] >> 8], 1);
    }
    __syncthreads();
    if (t < NB && h[t]) atomicAdd(&bcnt[t], h[t]);
}

// scan bucket counts -> bbase[0..NB], init bcur. NB <= 256.
__global__ void k_bscan(const int* __restrict__ bcnt, int* __restrict__ bbase,
                        int* __restrict__ bcur, int NB) {
    __shared__ int s[256];
    int t = threadIdx.x;
    int v = (t < NB) ? bcnt[t] : 0;
    s[t] = v;
    __syncthreads();
    for (int d = 1; d < 256; d <<= 1) {
        int x = (t >= d) ? s[t - d] : 0;
        __syncthreads();
        s[t] += x;
        __syncthreads();
    }
    if (t < NB) {
        int excl = s[t] - v;
        bbase[t] = excl;
        bcur[t]  = excl;
        if (t == NB - 1) bbase[NB] = s[t];   // total == E
    }
}

// ---------------- pass 1: coarse binning (packed 4B edges) ----------------

__global__ void k_bin(const int* __restrict__ src, const int* __restrict__ dst,
                      int* __restrict__ bcur, int* __restrict__ bkt,
                      int E, int NB) {
    __shared__ int cnt[256];
    __shared__ int pos[256];
    int t = threadIdx.x;
    int base_i = blockIdx.x * 4096;

    cnt[t] = 0;
    __syncthreads();

    int b_[16];
    int v_[16];
#pragma unroll
    for (int j = 0; j < 16; ++j) {
        int i = base_i + j * 256 + t;        // coalesced
        if (i < E) {
            int s = src[i], d = dst[i];
            v_[j] = s | ((d & 255) << 16);   // src(16b) | dlocal(8b)
            int b = d >> 8;
            b_[j] = b;
            atomicAdd(&cnt[b], 1);
        } else {
            b_[j] = -1;
        }
    }
    __syncthreads();

    if (t < NB) {
        int c = cnt[t];
        pos[t] = c ? atomicAdd(&bcur[t], c) : 0;
    }
    __syncthreads();

#pragma unroll
    for (int j = 0; j < 16; ++j) {
        if (b_[j] >= 0) {
            int p = atomicAdd(&pos[b_[j]], 1);
            bkt[p] = v_[j];
        }
    }
}

// ---------------- pass 2: per-bucket local CSR build ----------------
// One block per bucket. LDS histogram -> LDS scan -> off/dinv (coalesced),
// then LDS-cursor placement of src-only csr. Zero global atomics.

__global__ void k_fill2(const int* __restrict__ bkt, const int* __restrict__ bbase,
                        int* __restrict__ off, float* __restrict__ dinv,
                        int* __restrict__ csr, int N, int E, int NB) {
    __shared__ int hist[256];
    __shared__ int loff[256];
    __shared__ int cur[256];
    int b = blockIdx.x, t = threadIdx.x;     // 1024 threads
    if (t < 256) hist[t] = 0;
    __syncthreads();

    int e0 = bbase[b], e1 = bbase[b + 1];
    for (int i = e0 + t; i < e1; i += 1024)
        atomicAdd(&hist[(bkt[i] >> 16) & 255], 1);
    __syncthreads();

    // Hillis-Steele inclusive scan of hist into loff (all threads sync)
    if (t < 256) loff[t] = hist[t];
    __syncthreads();
    for (int d = 1; d < 256; d <<= 1) {
        int x = 0;
        if (t < 256 && t >= d) x = loff[t - d];
        __syncthreads();
        if (t < 256) loff[t] += x;
        __syncthreads();
    }

    if (t < 256) {
        int n = (b << 8) + t;
        if (n < N) {
            int base = e0 + loff[t] - hist[t];   // exclusive
            off[n]  = base;
            cur[t]  = base;
            dinv[n] = rsqrtf((float)(hist[t] + 1));  // +1 self-loop
        }
    }
    if (b == NB - 1 && t == 0) off[N] = E;
    __syncthreads();

    for (int i = e0 + t; i < e1; i += 1024) {
        int v  = bkt[i];
        int dl = (v >> 16) & 255;
        int p  = atomicAdd(&cur[dl], 1);     // LDS atomic
        csr[p] = v & 0xFFFF;                 // src only
    }
}

// ---------------- dense GEMM: hw'[N,128](bf16) = dinv[row]*(in @ W) ----------
// W staged in LDS (f32, 64KB). 512 threads = 16 row-groups x 32 col-threads;
// thread computes 4 rows x 4 cols. Input loads vectorized 8-k at a time.

template<bool BF16IN>
__global__ __launch_bounds__(512) void k_gemm(
        const void* __restrict__ in_, const float* __restrict__ W,
        const float* __restrict__ dinv, unsigned* __restrict__ outbf, int N) {
    __shared__ float Ws[128 * 128];          // 64 KB
    int t = threadIdx.x;

    // stage W: 512 threads x 8 sweeps x float4, coalesced
#pragma unroll
    for (int i = 0; i < 8; ++i) {
        int o = i * 2048 + t * 4;
        *reinterpret_cast<float4*>(&Ws[o]) = *reinterpret_cast<const float4*>(W + o);
    }
    __syncthreads();

    int rg   = blockIdx.x * 16 + (t >> 5);   // global row-group (4 rows)
    int row0 = rg << 2;
    if (row0 >= N) return;                   // no further barriers below
    int c4   = (t & 31) << 2;
    int r1 = (row0 + 1 < N) ? row0 + 1 : row0;
    int r2 = (row0 + 2 < N) ? row0 + 2 : row0;
    int r3 = (row0 + 3 < N) ? row0 + 3 : row0;

    const uint4*  pu4 = (const uint4*)in_;   // bf16 row = 16 uint4
    const float4* pf4 = (const float4*)in_;  // f32  row = 32 float4

    float4 a0 = {0.f, 0.f, 0.f, 0.f};
    float4 a1 = a0, a2 = a0, a3 = a0;

#pragma unroll 2
    for (int ku = 0; ku < 16; ++ku) {        // 8 k-values per iter
        float h0[8], h1[8], h2[8], h3[8];
        if constexpr (BF16IN) {
            uint4 u0 = pu4[(size_t)row0 * 16 + ku];
            uint4 u1 = pu4[(size_t)r1   * 16 + ku];
            uint4 u2 = pu4[(size_t)r2   * 16 + ku];
            uint4 u3 = pu4[(size_t)r3   * 16 + ku];
            h0[0] = bf_lo(u0.x); h0[1] = bf_hi(u0.x); h0[2] = bf_lo(u0.y); h0[3] = bf_hi(u0.y);
            h0[4] = bf_lo(u0.z); h0[5] = bf_hi(u0.z); h0[6] = bf_lo(u0.w); h0[7] = bf_hi(u0.w);
            h1[0] = bf_lo(u1.x); h1[1] = bf_hi(u1.x); h1[2] = bf_lo(u1.y); h1[3] = bf_hi(u1.y);
            h1[4] = bf_lo(u1.z); h1[5] = bf_hi(u1.z); h1[6] = bf_lo(u1.w); h1[7] = bf_hi(u1.w);
            h2[0] = bf_lo(u2.x); h2[1] = bf_hi(u2.x); h2[2] = bf_lo(u2.y); h2[3] = bf_hi(u2.y);
            h2[4] = bf_lo(u2.z); h2[5] = bf_hi(u2.z); h2[6] = bf_lo(u2.w); h2[7] = bf_hi(u2.w);
            h3[0] = bf_lo(u3.x); h3[1] = bf_hi(u3.x); h3[2] = bf_lo(u3.y); h3[3] = bf_hi(u3.y);
            h3[4] = bf_lo(u3.z); h3[5] = bf_hi(u3.z); h3[6] = bf_lo(u3.w); h3[7] = bf_hi(u3.w);
        } else {
            float4 fA, fB;
            fA = pf4[(size_t)row0 * 32 + 2 * ku]; fB = pf4[(size_t)row0 * 32 + 2 * ku + 1];
            h0[0]=fA.x; h0[1]=fA.y; h0[2]=fA.z; h0[3]=fA.w; h0[4]=fB.x; h0[5]=fB.y; h0[6]=fB.z; h0[7]=fB.w;
            fA = pf4[(size_t)r1 * 32 + 2 * ku];   fB = pf4[(size_t)r1 * 32 + 2 * ku + 1];
            h1[0]=fA.x; h1[1]=fA.y; h1[2]=fA.z; h1[3]=fA.w; h1[4]=fB.x; h1[5]=fB.y; h1[6]=fB.z; h1[7]=fB.w;
            fA = pf4[(size_t)r2 * 32 + 2 * ku];   fB = pf4[(size_t)r2 * 32 + 2 * ku + 1];
            h2[0]=fA.x; h2[1]=fA.y; h2[2]=fA.z; h2[3]=fA.w; h2[4]=fB.x; h2[5]=fB.y; h2[6]=fB.z; h2[7]=fB.w;
            fA = pf4[(size_t)r3 * 32 + 2 * ku];   fB = pf4[(size_t)r3 * 32 + 2 * ku + 1];
            h3[0]=fA.x; h3[1]=fA.y; h3[2]=fA.z; h3[3]=fA.w; h3[4]=fB.x; h3[5]=fB.y; h3[6]=fB.z; h3[7]=fB.w;
        }
#pragma unroll
        for (int kk = 0; kk < 8; ++kk) {
            float4 w = *reinterpret_cast<const float4*>(&Ws[(ku * 8 + kk) * 128 + c4]);
            a0.x = fmaf(h0[kk], w.x, a0.x); a0.y = fmaf(h0[kk], w.y, a0.y);
            a0.z = fmaf(h0[kk], w.z, a0.z); a0.w = fmaf(h0[kk], w.w, a0.w);
            a1.x = fmaf(h1[kk], w.x, a1.x); a1.y = fmaf(h1[kk], w.y, a1.y);
            a1.z = fmaf(h1[kk], w.z, a1.z); a1.w = fmaf(h1[kk], w.w, a1.w);
            a2.x = fmaf(h2[kk], w.x, a2.x); a2.y = fmaf(h2[kk], w.y, a2.y);
            a2.z = fmaf(h2[kk], w.z, a2.z); a2.w = fmaf(h2[kk], w.w, a2.w);
            a3.x = fmaf(h3[kk], w.x, a3.x); a3.y = fmaf(h3[kk], w.y, a3.y);
            a3.z = fmaf(h3[kk], w.z, a3.z); a3.w = fmaf(h3[kk], w.w, a3.w);
        }
    }
    float d0 = dinv[row0], d1 = dinv[r1], d2 = dinv[r2], d3 = dinv[r3];
    unsigned* o = outbf + (size_t)row0 * 64 + (c4 >> 1);
    uint2 u0 = { pack_bf2(a0.x * d0, a0.y * d0), pack_bf2(a0.z * d0, a0.w * d0) };
    *reinterpret_cast<uint2*>(o) = u0;
    if (row0 + 1 < N) {
        uint2 u1 = { pack_bf2(a1.x * d1, a1.y * d1), pack_bf2(a1.z * d1, a1.w * d1) };
        *reinterpret_cast<uint2*>(o + 64) = u1;
    }
    if (row0 + 2 < N) {
        uint2 u2 = { pack_bf2(a2.x * d2, a2.y * d2), pack_bf2(a2.z * d2, a2.w * d2) };
        *reinterpret_cast<uint2*>(o + 128) = u2;
    }
    if (row0 + 3 < N) {
        uint2 u3 = { pack_bf2(a3.x * d3, a3.y * d3), pack_bf2(a3.z * d3, a3.w * d3) };
        *reinterpret_cast<uint2*>(o + 192) = u3;
    }
}

// ---------------- aggregation ----------------
// out[n] = relu(dinv[n]*(sum_e hw'[src_e] + hw'[n]) + b), hw' & out bf16.
// One wave per node; 4 edges per iteration (quarter-wave x uint4 = 256B/row).
// Tail lanes broadcast index N -> zeroed dummy row.

__global__ void k_aggr(const unsigned* __restrict__ hw, const int* __restrict__ off,
                       const int* __restrict__ csr, const float* __restrict__ dinv,
                       const float* __restrict__ bias, unsigned* __restrict__ out, int N) {
    int wid  = (blockIdx.x * blockDim.x + threadIdx.x) >> 6;
    int lane = threadIdx.x & 63;
    if (wid >= N) return;
    int n  = wid;
    int q  = lane >> 4;                       // quarter 0..3
    int li = lane & 15;                       // lane owns cols 8*li .. 8*li+7

    const uint4* hw4 = reinterpret_cast<const uint4*>(hw);

    float a0 = 0.f, a1 = 0.f, a2 = 0.f, a3 = 0.f;
    float a4 = 0.f, a5 = 0.f, a6 = 0.f, a7 = 0.f;
    if (q == 0) {                             // self term hw'[n] in quarter 0
        uint4 v = hw4[(unsigned)(n << 4) + li];
        a0 = bf_lo(v.x); a1 = bf_hi(v.x);
        a2 = bf_lo(v.y); a3 = bf_hi(v.y);
        a4 = bf_lo(v.z); a5 = bf_hi(v.z);
        a6 = bf_lo(v.w); a7 = bf_hi(v.w);
    }

    int e = off[n], e1 = off[n + 1];
    while (e < e1) {
        int rem = e1 - e;
        int cnt = rem < 64 ? rem : 64;
        int s_l = N;                          // invalid -> zero row
        if (lane < cnt) s_l = csr[e + lane];
        int jn = (cnt + 3) >> 2;              // edge quads this batch
#pragma unroll 4
        for (int j = 0; j < jn; ++j) {
            int   s = __shfl(s_l, 4 * j + q); // idx>=cnt lanes hold N -> zeros
            uint4 v = hw4[(unsigned)(s << 4) + li];
            a0 += bf_lo(v.x); a1 += bf_hi(v.x);
            a2 += bf_lo(v.y); a3 += bf_hi(v.y);
            a4 += bf_lo(v.z); a5 += bf_hi(v.z);
            a6 += bf_lo(v.w); a7 += bf_hi(v.w);
        }
        e += cnt;
    }

    // combine quarters: q0+=q2, q1+=q3 (partner +32), then q0+=q1 (+16)
    int p1 = (lane + 32) & 63;
    a0 += __shfl(a0, p1); a1 += __shfl(a1, p1);
    a2 += __shfl(a2, p1); a3 += __shfl(a3, p1);
    a4 += __shfl(a4, p1); a5 += __shfl(a5, p1);
    a6 += __shfl(a6, p1); a7 += __shfl(a7, p1);
    int p2 = (lane + 16) & 63;
    a0 += __shfl(a0, p2); a1 += __shfl(a1, p2);
    a2 += __shfl(a2, p2); a3 += __shfl(a3, p2);
    a4 += __shfl(a4, p2); a5 += __shfl(a5, p2);
    a6 += __shfl(a6, p2); a7 += __shfl(a7, p2);

    if (q == 0) {
        float di = dinv[n];
        const float4* b4 = reinterpret_cast<const float4*>(bias);
        float4 bA = b4[2 * li], bB = b4[2 * li + 1];
        a0 = fmaxf(fmaf(a0, di, bA.x), 0.f); a1 = fmaxf(fmaf(a1, di, bA.y), 0.f);
        a2 = fmaxf(fmaf(a2, di, bA.z), 0.f); a3 = fmaxf(fmaf(a3, di, bA.w), 0.f);
        a4 = fmaxf(fmaf(a4, di, bB.x), 0.f); a5 = fmaxf(fmaf(a5, di, bB.y), 0.f);
        a6 = fmaxf(fmaf(a6, di, bB.z), 0.f); a7 = fmaxf(fmaf(a7, di, bB.w), 0.f);
        uint4 r = { pack_bf2(a0, a1), pack_bf2(a2, a3),
                    pack_bf2(a4, a5), pack_bf2(a6, a7) };
        reinterpret_cast<uint4*>(out)[(unsigned)(n << 4) + li] = r;
    }
}

// ---------------- global mean pool (batch is sorted, h in bf16) ----------------

__global__ void k_pool(const unsigned* __restrict__ h, const int* __restrict__ batch,
                       float* __restrict__ pooled, int* __restrict__ cnt,
                       int N, int npw) {
    int wid  = (blockIdx.x * blockDim.x + threadIdx.x) >> 6;
    int lane = threadIdx.x & 63;
    int n0 = wid * npw;
    if (n0 >= N) return;
    int n1 = n0 + npw; if (n1 > N) n1 = N;

    float ax = 0.f, ay = 0.f;
    int g = batch[n0];
    int c = 0;
    for (int n = n0; n < n1; ++n) {
        int gn = batch[n];
        if (gn != g) {
            atomicAdd(&pooled[g * 128 + 2 * lane],     ax);
            atomicAdd(&pooled[g * 128 + 2 * lane + 1], ay);
            if (lane == 0) atomicAdd(&cnt[g], c);
            ax = 0.f; ay = 0.f; c = 0; g = gn;
        }
        unsigned v = h[(size_t)n * 64 + lane];
        ax += bf_lo(v); ay += bf_hi(v); ++c;
    }
    atomicAdd(&pooled[g * 128 + 2 * lane],     ax);
    atomicAdd(&pooled[g * 128 + 2 * lane + 1], ay);
    if (lane == 0) atomicAdd(&cnt[g], c);
}

// ---------------- MLP head + L2 normalize (tiny: 64 x 128) ----------------

__global__ void k_head(const float* __restrict__ pooled, const int* __restrict__ cnt,
                       const float* __restrict__ pW1, const float* __restrict__ pb1,
                       const float* __restrict__ pW2, const float* __restrict__ pb2,
                       float* __restrict__ out) {
    __shared__ float hg[128];
    __shared__ float z1[128];
    __shared__ float red[128];
    int g = blockIdx.x, t = threadIdx.x;   // 128 threads

    float c = fmaxf((float)cnt[g], 1.0f);
    hg[t] = pooled[g * 128 + t] / c;
    __syncthreads();

    float a = pb1[t];
#pragma unroll 8
    for (int k = 0; k < 128; ++k) a = fmaf(hg[k], pW1[k * 128 + t], a);
    z1[t] = fmaxf(a, 0.f);
    __syncthreads();

    float z = pb2[t];
#pragma unroll 8
    for (int k = 0; k < 128; ++k) z = fmaf(z1[k], pW2[k * 128 + t], z);

    red[t] = z * z;
    __syncthreads();
    for (int d = 64; d > 0; d >>= 1) {
        if (t < d) red[t] += red[t + d];
        __syncthreads();
    }
    float nrm = fmaxf(sqrtf(red[0]), 1e-12f);
    out[g * 128 + t] = z / nrm;
}

// ---------------------------------------------------------------------------

extern "C" void kernel_launch(void* const* d_in, const int* in_sizes, int n_in,
                              void* d_out, int out_size, void* d_ws, size_t ws_size,
                              hipStream_t stream) {
    const float* x    = (const float*)d_in[0];
    const int*   eidx = (const int*)  d_in[1];
    const int*   batch= (const int*)  d_in[2];
    const float* W1   = (const float*)d_in[4];
    const float* b1   = (const float*)d_in[5];
    const float* W2   = (const float*)d_in[6];
    const float* b2   = (const float*)d_in[7];
    const float* pW1  = (const float*)d_in[8];
    const float* pb1  = (const float*)d_in[9];
    const float* pW2  = (const float*)d_in[10];
    const float* pb2  = (const float*)d_in[11];
    float* out = (float*)d_out;

    const int N  = in_sizes[0] / 128;
    const int E  = in_sizes[1] / 2;
    const int NG = out_size / 128;
    const int NB = (N + 255) >> 8;    // buckets of 256 nodes; NB<=256 (N<65536)

    const int* src = eidx;      // edge_index[0]
    const int* dst = eidx + E;  // edge_index[1]

    // workspace carve-up (256B aligned)
    char* p = (char*)d_ws;
    auto alloc = [&](size_t bytes) -> void* {
        void* r = (void*)p;
        p += (bytes + 255) & ~(size_t)255;
        return r;
    };
    int*      bcnt     = (int*)     alloc((size_t)NB * 4);
    int*      bbase    = (int*)     alloc((size_t)(NB + 1) * 4);
    int*      bcur     = (int*)     alloc((size_t)NB * 4);
    int*      off      = (int*)     alloc((size_t)(N + 1) * 4);
    float*    dinv     = (float*)   alloc((size_t)N * 4);
    int*      bkt      = (int*)     alloc((size_t)E * 4);        // packed edges
    int*      csr      = (int*)     alloc((size_t)E * 4);        // src only
    unsigned* bufH     = (unsigned*)alloc((size_t)(N + 1) * 64 * 4); // bf16 hw' (+zero row)
    unsigned* bufB     = (unsigned*)alloc((size_t)N * 64 * 4);       // bf16 h
    float*    pooled   = (float*)   alloc((size_t)NG * 128 * 4);
    int*      cnt      = (int*)     alloc((size_t)NG * 4);

    const int tB = (E + 4095) / 4096;   // 4096-edge tiles

    hipMemsetAsync(bcnt,   0, (size_t)NB * 4, stream);
    hipMemsetAsync(bufH + (size_t)N * 64, 0, 256, stream);   // zero dummy row
    hipMemsetAsync(pooled, 0, (size_t)NG * 128 * 4, stream);
    hipMemsetAsync(cnt,    0, (size_t)NG * 4, stream);

    // CSR build: count -> scan -> bin -> per-bucket local fill
    k_bincount<<<tB, 256, 0, stream>>>(dst, bcnt, E, NB);
    k_bscan   <<<1, 256, 0, stream>>>(bcnt, bbase, bcur, NB);
    k_bin     <<<tB, 256, 0, stream>>>(src, dst, bcur, bkt, E, NB);
    k_fill2   <<<NB, 1024, 0, stream>>>(bkt, bbase, off, dinv, csr, N, E, NB);

    const int nrg = (N + 3) >> 2;               // 4-row groups
    const int gB  = (nrg + 15) / 16;            // 16 row-groups (64 rows)/block
    const int aB  = (N + 3) / 4;                // 4 waves (nodes) per block

    // layer 1: hw' = bf16(dinv*(x @ W1)) ; h1 = bf16(relu(dinv*aggr + b1))
    k_gemm<false><<<gB, 512, 0, stream>>>((const void*)x, W1, dinv, bufH, N);
    k_aggr<<<aB, 256, 0, stream>>>(bufH, off, csr, dinv, b1, bufB, N);
    // layer 2
    k_gemm<true><<<gB, 512, 0, stream>>>((const void*)bufB, W2, dinv, bufH, N);
    k_aggr<<<aB, 256, 0, stream>>>(bufH, off, csr, dinv, b2, bufB, N);

    // mean pool
    const int NPW = 32;  // nodes per wave
    const int waves = (N + NPW - 1) / NPW;
    const int pB = (waves * 64 + 255) / 256;
    k_pool<<<pB, 256, 0, stream>>>(bufB, batch, pooled, cnt, N, NPW);

    // head
    k_head<<<NG, 128, 0, stream>>>(pooled, cnt, pW1, pb1, pW2, pb2, out);
}

// Round 10
// 262.183 us; speedup vs baseline: 2.1629x; 1.0655x over previous
//
#include <hip/hip_runtime.h>
#include <cstdint>
#include <cstddef>

// ---------------------------------------------------------------------------
// SimpleGNN: 2x GCNConv(128->128) + ReLU, global mean pool (64 graphs),
// MLP head 128->128->128 + ReLU, L2 row-normalize.
//
// R10 changes vs R9 (279us; k_gemm 2x53us f32-VALU latency-bound):
//  - k_gemm -> MFMA (mfma_f32_16x16x32_bf16). W pre-transposed to bf16
//    WbfT[col][k] by k_wprep. Per wave: 16 output rows x 128 cols,
//    4 A-frags + 2 passes x (16 B-frags + 16 MFMA). Epilogue via padded
//    per-wave LDS tile -> dinv scale -> packed bf16.
//  - x and W rounded to bf16 (output was already bf16; absmax est ~2e-3
//    vs 4.84e-3 threshold).
// Everything else unchanged from R9.
// ---------------------------------------------------------------------------

using short8 = __attribute__((ext_vector_type(8))) short;   // 8 bf16 (4 VGPRs)
using f32x4v = __attribute__((ext_vector_type(4))) float;   // 4 fp32

// ---------------- bf16 helpers ----------------

static __device__ __forceinline__ unsigned f2bf_rne(float f) {
    unsigned u = __float_as_uint(f);
    return (u + 0x7FFFu + ((u >> 16) & 1u)) >> 16;   // round-nearest-even
}
static __device__ __forceinline__ unsigned pack_bf2(float lo, float hi) {
    return f2bf_rne(lo) | (f2bf_rne(hi) << 16);
}
static __device__ __forceinline__ float bf_lo(unsigned v) {
    return __uint_as_float(v << 16);
}
static __device__ __forceinline__ float bf_hi(unsigned v) {
    return __uint_as_float(v & 0xFFFF0000u);
}

// ---------------- pass 0: bucket counts (bucket = 256 consecutive dst) ----

__global__ void k_bincount(const int* __restrict__ dst, int* __restrict__ bcnt,
                           int E, int NB) {
    __shared__ int h[256];
    int t = threadIdx.x;
    h[t] = 0;
    __syncthreads();
    int base_i = blockIdx.x * 4096;
#pragma unroll
    for (int j = 0; j < 16; ++j) {
        int i = base_i + j * 256 + t;
        if (i < E) atomicAdd(&h[dst[i] >> 8], 1);
    }
    __syncthreads();
    if (t < NB && h[t]) atomicAdd(&bcnt[t], h[t]);
}

// scan bucket counts -> bbase[0..NB], init bcur. NB <= 256.
__global__ void k_bscan(const int* __restrict__ bcnt, int* __restrict__ bbase,
                        int* __restrict__ bcur, int NB) {
    __shared__ int s[256];
    int t = threadIdx.x;
    int v = (t < NB) ? bcnt[t] : 0;
    s[t] = v;
    __syncthreads();
    for (int d = 1; d < 256; d <<= 1) {
        int x = (t >= d) ? s[t - d] : 0;
        __syncthreads();
        s[t] += x;
        __syncthreads();
    }
    if (t < NB) {
        int excl = s[t] - v;
        bbase[t] = excl;
        bcur[t]  = excl;
        if (t == NB - 1) bbase[NB] = s[t];   // total == E
    }
}

// ---------------- pass 1: coarse binning (packed 4B edges) ----------------

__global__ void k_bin(const int* __restrict__ src, const int* __restrict__ dst,
                      int* __restrict__ bcur, int* __restrict__ bkt,
                      int E, int NB) {
    __shared__ int cnt[256];
    __shared__ int pos[256];
    int t = threadIdx.x;
    int base_i = blockIdx.x * 4096;

    cnt[t] = 0;
    __syncthreads();

    int b_[16];
    int v_[16];
#pragma unroll
    for (int j = 0; j < 16; ++j) {
        int i = base_i + j * 256 + t;        // coalesced
        if (i < E) {
            int s = src[i], d = dst[i];
            v_[j] = s | ((d & 255) << 16);   // src(16b) | dlocal(8b)
            int b = d >> 8;
            b_[j] = b;
            atomicAdd(&cnt[b], 1);
        } else {
            b_[j] = -1;
        }
    }
    __syncthreads();

    if (t < NB) {
        int c = cnt[t];
        pos[t] = c ? atomicAdd(&bcur[t], c) : 0;
    }
    __syncthreads();

#pragma unroll
    for (int j = 0; j < 16; ++j) {
        if (b_[j] >= 0) {
            int p = atomicAdd(&pos[b_[j]], 1);
            bkt[p] = v_[j];
        }
    }
}

// ---------------- pass 2: per-bucket local CSR build ----------------

__global__ void k_fill2(const int* __restrict__ bkt, const int* __restrict__ bbase,
                        int* __restrict__ off, float* __restrict__ dinv,
                        int* __restrict__ csr, int N, int E, int NB) {
    __shared__ int hist[256];
    __shared__ int loff[256];
    __shared__ int cur[256];
    int b = blockIdx.x, t = threadIdx.x;     // 1024 threads
    if (t < 256) hist[t] = 0;
    __syncthreads();

    int e0 = bbase[b], e1 = bbase[b + 1];
    for (int i = e0 + t; i < e1; i += 1024)
        atomicAdd(&hist[(bkt[i] >> 16) & 255], 1);
    __syncthreads();

    if (t < 256) loff[t] = hist[t];
    __syncthreads();
    for (int d = 1; d < 256; d <<= 1) {
        int x = 0;
        if (t < 256 && t >= d) x = loff[t - d];
        __syncthreads();
        if (t < 256) loff[t] += x;
        __syncthreads();
    }

    if (t < 256) {
        int n = (b << 8) + t;
        if (n < N) {
            int base = e0 + loff[t] - hist[t];   // exclusive
            off[n]  = base;
            cur[t]  = base;
            dinv[n] = rsqrtf((float)(hist[t] + 1));  // +1 self-loop
        }
    }
    if (b == NB - 1 && t == 0) off[N] = E;
    __syncthreads();

    for (int i = e0 + t; i < e1; i += 1024) {
        int v  = bkt[i];
        int dl = (v >> 16) & 255;
        int p  = atomicAdd(&cur[dl], 1);     // LDS atomic
        csr[p] = v & 0xFFFF;                 // src only
    }
}

// ---------------- W prep: WbfT[col][k] = bf16(W[k][col]), per weight ----------

__global__ void k_wprep(const float* __restrict__ Wa, const float* __restrict__ Wb,
                        unsigned short* __restrict__ Ta, unsigned short* __restrict__ Tb) {
    const float* W = blockIdx.x ? Wb : Wa;
    unsigned short* T = blockIdx.x ? Tb : Ta;
    for (int idx = threadIdx.x; idx < 16384; idx += 256) {
        int k = idx >> 7, c = idx & 127;
        T[c * 128 + k] = (unsigned short)f2bf_rne(W[idx]);   // W[k*128+c]
    }
}

// ---------------- MFMA GEMM: hw'[N,128](bf16) = dinv[row]*(in @ W) ----------
// 256 threads = 4 waves; wave = 16 rows x 128 cols. A from in (bf16 or f32),
// B from WbfT (bf16 [col][k]). Frag layouts (m89/m91-verified):
//   A: lane l <- A[l&15][(l>>4)*8 + j]      (contiguous 16B/lane)
//   B: lane l <- B[(l>>4)*8 + j][l&15]      = WbfT[col][k..k+7], contiguous
//   D: lane l, reg r -> C[(l>>4)*4 + r][l&15]

template<bool BF16IN>
__global__ __launch_bounds__(256) void k_gemm(
        const void* __restrict__ in_, const unsigned short* __restrict__ WT,
        const float* __restrict__ dinv, unsigned* __restrict__ outbf, int N) {
    __shared__ float sC[4][16][132];         // per-wave padded C tile (33.8KB)
    int t = threadIdx.x;
    int w  = t >> 6;
    int l  = t & 63;
    int lo = l & 15;
    int hi = l >> 4;
    int rbase = blockIdx.x * 64 + w * 16;
    int row   = rbase + lo;
    int rowc  = (row < N) ? row : (N - 1);

    // A-frags for all 4 k-steps
    short8 a[4];
    if constexpr (BF16IN) {
        const uint4* pu = (const uint4*)in_;
#pragma unroll
        for (int ks = 0; ks < 4; ++ks)
            a[ks] = __builtin_bit_cast(short8, pu[(size_t)rowc * 16 + ks * 4 + hi]);
    } else {
        const float4* pf = (const float4*)in_;
#pragma unroll
        for (int ks = 0; ks < 4; ++ks) {
            float4 fA = pf[(size_t)rowc * 32 + ks * 8 + hi * 2];
            float4 fB = pf[(size_t)rowc * 32 + ks * 8 + hi * 2 + 1];
            short8 s;
            s[0] = (short)f2bf_rne(fA.x); s[1] = (short)f2bf_rne(fA.y);
            s[2] = (short)f2bf_rne(fA.z); s[3] = (short)f2bf_rne(fA.w);
            s[4] = (short)f2bf_rne(fB.x); s[5] = (short)f2bf_rne(fB.y);
            s[6] = (short)f2bf_rne(fB.z); s[7] = (short)f2bf_rne(fB.w);
            a[ks] = s;
        }
    }

    f32x4v acc[8];
#pragma unroll
    for (int i = 0; i < 8; ++i) acc[i] = (f32x4v){0.f, 0.f, 0.f, 0.f};

    const uint4* wt4 = (const uint4*)WT;     // col-row = 128 bf16 = 16 uint4
#pragma unroll
    for (int cp = 0; cp < 2; ++cp) {
        short8 b[4][4];                      // [ct][ks]
#pragma unroll
        for (int ct = 0; ct < 4; ++ct) {
            int col = cp * 64 + ct * 16 + lo;
#pragma unroll
            for (int ks = 0; ks < 4; ++ks)
                b[ct][ks] = __builtin_bit_cast(short8, wt4[col * 16 + ks * 4 + hi]);
        }
#pragma unroll
        for (int ks = 0; ks < 4; ++ks)
#pragma unroll
            for (int ct = 0; ct < 4; ++ct)
                acc[cp * 4 + ct] = __builtin_amdgcn_mfma_f32_16x16x32_bf16(
                    a[ks], b[ct][ks], acc[cp * 4 + ct], 0, 0, 0);
    }

    // epilogue: scatter C to LDS, repack rows as bf16 with dinv scale
#pragma unroll
    for (int i = 0; i < 8; ++i) {
        int colb = (i >> 2) * 64 + (i & 3) * 16 + lo;
#pragma unroll
        for (int r = 0; r < 4; ++r)
            sC[w][hi * 4 + r][colb] = acc[i][r];
    }
    __syncthreads();

    if (row < N) {
        float d = dinv[rowc];
#pragma unroll
        for (int j = 0; j < 4; ++j) {
            float4 fA = *reinterpret_cast<const float4*>(&sC[w][lo][hi * 32 + j * 8]);
            float4 fB = *reinterpret_cast<const float4*>(&sC[w][lo][hi * 32 + j * 8 + 4]);
            uint4 o = { pack_bf2(fA.x * d, fA.y * d), pack_bf2(fA.z * d, fA.w * d),
                        pack_bf2(fB.x * d, fB.y * d), pack_bf2(fB.z * d, fB.w * d) };
            reinterpret_cast<uint4*>(outbf)[(size_t)row * 16 + hi * 4 + j] = o;
        }
    }
}

// ---------------- aggregation ----------------
// out[n] = relu(dinv[n]*(sum_e hw'[src_e] + hw'[n]) + b), hw' & out bf16.

__global__ void k_aggr(const unsigned* __restrict__ hw, const int* __restrict__ off,
                       const int* __restrict__ csr, const float* __restrict__ dinv,
                       const float* __restrict__ bias, unsigned* __restrict__ out, int N) {
    int wid  = (blockIdx.x * blockDim.x + threadIdx.x) >> 6;
    int lane = threadIdx.x & 63;
    if (wid >= N) return;
    int n  = wid;
    int q  = lane >> 4;                       // quarter 0..3
    int li = lane & 15;                       // lane owns cols 8*li .. 8*li+7

    const uint4* hw4 = reinterpret_cast<const uint4*>(hw);

    float a0 = 0.f, a1 = 0.f, a2 = 0.f, a3 = 0.f;
    float a4 = 0.f, a5 = 0.f, a6 = 0.f, a7 = 0.f;
    if (q == 0) {                             // self term hw'[n] in quarter 0
        uint4 v = hw4[(unsigned)(n << 4) + li];
        a0 = bf_lo(v.x); a1 = bf_hi(v.x);
        a2 = bf_lo(v.y); a3 = bf_hi(v.y);
        a4 = bf_lo(v.z); a5 = bf_hi(v.z);
        a6 = bf_lo(v.w); a7 = bf_hi(v.w);
    }

    int e = off[n], e1 = off[n + 1];
    while (e < e1) {
        int rem = e1 - e;
        int cnt = rem < 64 ? rem : 64;
        int s_l = N;                          // invalid -> zero row
        if (lane < cnt) s_l = csr[e + lane];
        int jn = (cnt + 3) >> 2;              // edge quads this batch
#pragma unroll 4
        for (int j = 0; j < jn; ++j) {
            int   s = __shfl(s_l, 4 * j + q); // idx>=cnt lanes hold N -> zeros
            uint4 v = hw4[(unsigned)(s << 4) + li];
            a0 += bf_lo(v.x); a1 += bf_hi(v.x);
            a2 += bf_lo(v.y); a3 += bf_hi(v.y);
            a4 += bf_lo(v.z); a5 += bf_hi(v.z);
            a6 += bf_lo(v.w); a7 += bf_hi(v.w);
        }
        e += cnt;
    }

    // combine quarters: q0+=q2, q1+=q3 (partner +32), then q0+=q1 (+16)
    int p1 = (lane + 32) & 63;
    a0 += __shfl(a0, p1); a1 += __shfl(a1, p1);
    a2 += __shfl(a2, p1); a3 += __shfl(a3, p1);
    a4 += __shfl(a4, p1); a5 += __shfl(a5, p1);
    a6 += __shfl(a6, p1); a7 += __shfl(a7, p1);
    int p2 = (lane + 16) & 63;
    a0 += __shfl(a0, p2); a1 += __shfl(a1, p2);
    a2 += __shfl(a2, p2); a3 += __shfl(a3, p2);
    a4 += __shfl(a4, p2); a5 += __shfl(a5, p2);
    a6 += __shfl(a6, p2); a7 += __shfl(a7, p2);

    if (q == 0) {
        float di = dinv[n];
        const float4* b4 = reinterpret_cast<const float4*>(bias);
        float4 bA = b4[2 * li], bB = b4[2 * li + 1];
        a0 = fmaxf(fmaf(a0, di, bA.x), 0.f); a1 = fmaxf(fmaf(a1, di, bA.y), 0.f);
        a2 = fmaxf(fmaf(a2, di, bA.z), 0.f); a3 = fmaxf(fmaf(a3, di, bA.w), 0.f);
        a4 = fmaxf(fmaf(a4, di, bB.x), 0.f); a5 = fmaxf(fmaf(a5, di, bB.y), 0.f);
        a6 = fmaxf(fmaf(a6, di, bB.z), 0.f); a7 = fmaxf(fmaf(a7, di, bB.w), 0.f);
        uint4 r = { pack_bf2(a0, a1), pack_bf2(a2, a3),
                    pack_bf2(a4, a5), pack_bf2(a6, a7) };
        reinterpret_cast<uint4*>(out)[(unsigned)(n << 4) + li] = r;
    }
}

// ---------------- global mean pool (batch is sorted, h in bf16) ----------------

__global__ void k_pool(const unsigned* __restrict__ h, const int* __restrict__ batch,
                       float* __restrict__ pooled, int* __restrict__ cnt,
                       int N, int npw) {
    int wid  = (blockIdx.x * blockDim.x + threadIdx.x) >> 6;
    int lane = threadIdx.x & 63;
    int n0 = wid * npw;
    if (n0 >= N) return;
    int n1 = n0 + npw; if (n1 > N) n1 = N;

    float ax = 0.f, ay = 0.f;
    int g = batch[n0];
    int c = 0;
    for (int n = n0; n < n1; ++n) {
        int gn = batch[n];
        if (gn != g) {
            atomicAdd(&pooled[g * 128 + 2 * lane],     ax);
            atomicAdd(&pooled[g * 128 + 2 * lane + 1], ay);
            if (lane == 0) atomicAdd(&cnt[g], c);
            ax = 0.f; ay = 0.f; c = 0; g = gn;
        }
        unsigned v = h[(size_t)n * 64 + lane];
        ax += bf_lo(v); ay += bf_hi(v); ++c;
    }
    atomicAdd(&pooled[g * 128 + 2 * lane],     ax);
    atomicAdd(&pooled[g * 128 + 2 * lane + 1], ay);
    if (lane == 0) atomicAdd(&cnt[g], c);
}

// ---------------- MLP head + L2 normalize (tiny: 64 x 128) ----------------

__global__ void k_head(const float* __restrict__ pooled, const int* __restrict__ cnt,
                       const float* __restrict__ pW1, const float* __restrict__ pb1,
                       const float* __restrict__ pW2, const float* __restrict__ pb2,
                       float* __restrict__ out) {
    __shared__ float hg[128];
    __shared__ float z1[128];
    __shared__ float red[128];
    int g = blockIdx.x, t = threadIdx.x;   // 128 threads

    float c = fmaxf((float)cnt[g], 1.0f);
    hg[t] = pooled[g * 128 + t] / c;
    __syncthreads();

    float a = pb1[t];
#pragma unroll 8
    for (int k = 0; k < 128; ++k) a = fmaf(hg[k], pW1[k * 128 + t], a);
    z1[t] = fmaxf(a, 0.f);
    __syncthreads();

    float z = pb2[t];
#pragma unroll 8
    for (int k = 0; k < 128; ++k) z = fmaf(z1[k], pW2[k * 128 + t], z);

    red[t] = z * z;
    __syncthreads();
    for (int d = 64; d > 0; d >>= 1) {
        if (t < d) red[t] += red[t + d];
        __syncthreads();
    }
    float nrm = fmaxf(sqrtf(red[0]), 1e-12f);
    out[g * 128 + t] = z / nrm;
}

// ---------------------------------------------------------------------------

extern "C" void kernel_launch(void* const* d_in, const int* in_sizes, int n_in,
                              void* d_out, int out_size, void* d_ws, size_t ws_size,
                              hipStream_t stream) {
    const float* x    = (const float*)d_in[0];
    const int*   eidx = (const int*)  d_in[1];
    const int*   batch= (const int*)  d_in[2];
    const float* W1   = (const float*)d_in[4];
    const float* b1   = (const float*)d_in[5];
    const float* W2   = (const float*)d_in[6];
    const float* b2   = (const float*)d_in[7];
    const float* pW1  = (const float*)d_in[8];
    const float* pb1  = (const float*)d_in[9];
    const float* pW2  = (const float*)d_in[10];
    const float* pb2  = (const float*)d_in[11];
    float* out = (float*)d_out;

    const int N  = in_sizes[0] / 128;
    const int E  = in_sizes[1] / 2;
    const int NG = out_size / 128;
    const int NB = (N + 255) >> 8;    // buckets of 256 nodes; NB<=256 (N<65536)

    const int* src = eidx;      // edge_index[0]
    const int* dst = eidx + E;  // edge_index[1]

    // workspace carve-up (256B aligned)
    char* p = (char*)d_ws;
    auto alloc = [&](size_t bytes) -> void* {
        void* r = (void*)p;
        p += (bytes + 255) & ~(size_t)255;
        return r;
    };
    int*      bcnt     = (int*)     alloc((size_t)NB * 4);
    int*      bbase    = (int*)     alloc((size_t)(NB + 1) * 4);
    int*      bcur     = (int*)     alloc((size_t)NB * 4);
    int*      off      = (int*)     alloc((size_t)(N + 1) * 4);
    float*    dinv     = (float*)   alloc((size_t)N * 4);
    int*      bkt      = (int*)     alloc((size_t)E * 4);        // packed edges
    int*      csr      = (int*)     alloc((size_t)E * 4);        // src only
    unsigned short* wbt1 = (unsigned short*)alloc(16384 * 2);    // bf16 W1^T
    unsigned short* wbt2 = (unsigned short*)alloc(16384 * 2);    // bf16 W2^T
    unsigned* bufH     = (unsigned*)alloc((size_t)(N + 1) * 64 * 4); // bf16 hw' (+zero row)
    unsigned* bufB     = (unsigned*)alloc((size_t)N * 64 * 4);       // bf16 h
    float*    pooled   = (float*)   alloc((size_t)NG * 128 * 4);
    int*      cnt      = (int*)     alloc((size_t)NG * 4);

    const int tB = (E + 4095) / 4096;   // 4096-edge tiles

    hipMemsetAsync(bcnt,   0, (size_t)NB * 4, stream);
    hipMemsetAsync(bufH + (size_t)N * 64, 0, 256, stream);   // zero dummy row
    hipMemsetAsync(pooled, 0, (size_t)NG * 128 * 4, stream);
    hipMemsetAsync(cnt,    0, (size_t)NG * 4, stream);

    // CSR build: count -> scan -> bin -> per-bucket local fill
    k_bincount<<<tB, 256, 0, stream>>>(dst, bcnt, E, NB);
    k_bscan   <<<1, 256, 0, stream>>>(bcnt, bbase, bcur, NB);
    k_bin     <<<tB, 256, 0, stream>>>(src, dst, bcur, bkt, E, NB);
    k_fill2   <<<NB, 1024, 0, stream>>>(bkt, bbase, off, dinv, csr, N, E, NB);
    k_wprep   <<<2, 256, 0, stream>>>(W1, W2, wbt1, wbt2);

    const int gB = (N + 63) / 64;               // 64 rows per 256-thread block
    const int aB = (N + 3) / 4;                 // 4 waves (nodes) per block

    // layer 1: hw' = bf16(dinv*(x @ W1)) ; h1 = bf16(relu(dinv*aggr + b1))
    k_gemm<false><<<gB, 256, 0, stream>>>((const void*)x, wbt1, dinv, bufH, N);
    k_aggr<<<aB, 256, 0, stream>>>(bufH, off, csr, dinv, b1, bufB, N);
    // layer 2
    k_gemm<true><<<gB, 256, 0, stream>>>((const void*)bufB, wbt2, dinv, bufH, N);
    k_aggr<<<aB, 256, 0, stream>>>(bufH, off, csr, dinv, b2, bufB, N);

    // mean pool
    const int NPW = 32;  // nodes per wave
    const int waves = (N + NPW - 1) / NPW;
    const int pB = (waves * 64 + 255) / 256;
    k_pool<<<pB, 256, 0, stream>>>(bufB, batch, pooled, cnt, N, NPW);

    // head
    k_head<<<NG, 128, 0, stream>>>(pooled, cnt, pW1, pb1, pW2, pb2, out);
}

// Round 11
// 252.821 us; speedup vs baseline: 2.2430x; 1.0370x over previous
//
#include <hip/hip_runtime.h>
#include <cstdint>
#include <cstddef>

// ---------------------------------------------------------------------------
// SimpleGNN: 2x GCNConv(128->128) + ReLU, global mean pool (64 graphs),
// MLP head 128->128->128 + ReLU, L2 row-normalize.
//
// R11 changes vs R10 (262us; k_aggr 2x52us, VGPR=16 -> 1 gather in flight,
// L2-miss-latency bound at 2.9-3.2 TB/s beyond-L2):
//  - k_aggr: 4-deep software pipeline in the edge-quad loop. 4 independent
//    shuffles -> 4 addresses -> 4 uint4 loads issued back-to-back, then
//    accumulate. 4x outstanding misses per lane (~40 VGPR, still 8 waves/SIMD).
// Everything else unchanged from R10.
// ---------------------------------------------------------------------------

using short8 = __attribute__((ext_vector_type(8))) short;   // 8 bf16 (4 VGPRs)
using f32x4v = __attribute__((ext_vector_type(4))) float;   // 4 fp32

// ---------------- bf16 helpers ----------------

static __device__ __forceinline__ unsigned f2bf_rne(float f) {
    unsigned u = __float_as_uint(f);
    return (u + 0x7FFFu + ((u >> 16) & 1u)) >> 16;   // round-nearest-even
}
static __device__ __forceinline__ unsigned pack_bf2(float lo, float hi) {
    return f2bf_rne(lo) | (f2bf_rne(hi) << 16);
}
static __device__ __forceinline__ float bf_lo(unsigned v) {
    return __uint_as_float(v << 16);
}
static __device__ __forceinline__ float bf_hi(unsigned v) {
    return __uint_as_float(v & 0xFFFF0000u);
}

// ---------------- pass 0: bucket counts (bucket = 256 consecutive dst) ----

__global__ void k_bincount(const int* __restrict__ dst, int* __restrict__ bcnt,
                           int E, int NB) {
    __shared__ int h[256];
    int t = threadIdx.x;
    h[t] = 0;
    __syncthreads();
    int base_i = blockIdx.x * 4096;
#pragma unroll
    for (int j = 0; j < 16; ++j) {
        int i = base_i + j * 256 + t;
        if (i < E) atomicAdd(&h[dst[i] >> 8], 1);
    }
    __syncthreads();
    if (t < NB && h[t]) atomicAdd(&bcnt[t], h[t]);
}

// scan bucket counts -> bbase[0..NB], init bcur. NB <= 256.
__global__ void k_bscan(const int* __restrict__ bcnt, int* __restrict__ bbase,
                        int* __restrict__ bcur, int NB) {
    __shared__ int s[256];
    int t = threadIdx.x;
    int v = (t < NB) ? bcnt[t] : 0;
    s[t] = v;
    __syncthreads();
    for (int d = 1; d < 256; d <<= 1) {
        int x = (t >= d) ? s[t - d] : 0;
        __syncthreads();
        s[t] += x;
        __syncthreads();
    }
    if (t < NB) {
        int excl = s[t] - v;
        bbase[t] = excl;
        bcur[t]  = excl;
        if (t == NB - 1) bbase[NB] = s[t];   // total == E
    }
}

// ---------------- pass 1: coarse binning (packed 4B edges) ----------------

__global__ void k_bin(const int* __restrict__ src, const int* __restrict__ dst,
                      int* __restrict__ bcur, int* __restrict__ bkt,
                      int E, int NB) {
    __shared__ int cnt[256];
    __shared__ int pos[256];
    int t = threadIdx.x;
    int base_i = blockIdx.x * 4096;

    cnt[t] = 0;
    __syncthreads();

    int b_[16];
    int v_[16];
#pragma unroll
    for (int j = 0; j < 16; ++j) {
        int i = base_i + j * 256 + t;        // coalesced
        if (i < E) {
            int s = src[i], d = dst[i];
            v_[j] = s | ((d & 255) << 16);   // src(16b) | dlocal(8b)
            int b = d >> 8;
            b_[j] = b;
            atomicAdd(&cnt[b], 1);
        } else {
            b_[j] = -1;
        }
    }
    __syncthreads();

    if (t < NB) {
        int c = cnt[t];
        pos[t] = c ? atomicAdd(&bcur[t], c) : 0;
    }
    __syncthreads();

#pragma unroll
    for (int j = 0; j < 16; ++j) {
        if (b_[j] >= 0) {
            int p = atomicAdd(&pos[b_[j]], 1);
            bkt[p] = v_[j];
        }
    }
}

// ---------------- pass 2: per-bucket local CSR build ----------------

__global__ void k_fill2(const int* __restrict__ bkt, const int* __restrict__ bbase,
                        int* __restrict__ off, float* __restrict__ dinv,
                        int* __restrict__ csr, int N, int E, int NB) {
    __shared__ int hist[256];
    __shared__ int loff[256];
    __shared__ int cur[256];
    int b = blockIdx.x, t = threadIdx.x;     // 1024 threads
    if (t < 256) hist[t] = 0;
    __syncthreads();

    int e0 = bbase[b], e1 = bbase[b + 1];
    for (int i = e0 + t; i < e1; i += 1024)
        atomicAdd(&hist[(bkt[i] >> 16) & 255], 1);
    __syncthreads();

    if (t < 256) loff[t] = hist[t];
    __syncthreads();
    for (int d = 1; d < 256; d <<= 1) {
        int x = 0;
        if (t < 256 && t >= d) x = loff[t - d];
        __syncthreads();
        if (t < 256) loff[t] += x;
        __syncthreads();
    }

    if (t < 256) {
        int n = (b << 8) + t;
        if (n < N) {
            int base = e0 + loff[t] - hist[t];   // exclusive
            off[n]  = base;
            cur[t]  = base;
            dinv[n] = rsqrtf((float)(hist[t] + 1));  // +1 self-loop
        }
    }
    if (b == NB - 1 && t == 0) off[N] = E;
    __syncthreads();

    for (int i = e0 + t; i < e1; i += 1024) {
        int v  = bkt[i];
        int dl = (v >> 16) & 255;
        int p  = atomicAdd(&cur[dl], 1);     // LDS atomic
        csr[p] = v & 0xFFFF;                 // src only
    }
}

// ---------------- W prep: WbfT[col][k] = bf16(W[k][col]), per weight ----------

__global__ void k_wprep(const float* __restrict__ Wa, const float* __restrict__ Wb,
                        unsigned short* __restrict__ Ta, unsigned short* __restrict__ Tb) {
    const float* W = blockIdx.x ? Wb : Wa;
    unsigned short* T = blockIdx.x ? Tb : Ta;
    for (int idx = threadIdx.x; idx < 16384; idx += 256) {
        int k = idx >> 7, c = idx & 127;
        T[c * 128 + k] = (unsigned short)f2bf_rne(W[idx]);   // W[k*128+c]
    }
}

// ---------------- MFMA GEMM: hw'[N,128](bf16) = dinv[row]*(in @ W) ----------
// 256 threads = 4 waves; wave = 16 rows x 128 cols.

template<bool BF16IN>
__global__ __launch_bounds__(256) void k_gemm(
        const void* __restrict__ in_, const unsigned short* __restrict__ WT,
        const float* __restrict__ dinv, unsigned* __restrict__ outbf, int N) {
    __shared__ float sC[4][16][132];         // per-wave padded C tile (33.8KB)
    int t = threadIdx.x;
    int w  = t >> 6;
    int l  = t & 63;
    int lo = l & 15;
    int hi = l >> 4;
    int rbase = blockIdx.x * 64 + w * 16;
    int row   = rbase + lo;
    int rowc  = (row < N) ? row : (N - 1);

    // A-frags for all 4 k-steps
    short8 a[4];
    if constexpr (BF16IN) {
        const uint4* pu = (const uint4*)in_;
#pragma unroll
        for (int ks = 0; ks < 4; ++ks)
            a[ks] = __builtin_bit_cast(short8, pu[(size_t)rowc * 16 + ks * 4 + hi]);
    } else {
        const float4* pf = (const float4*)in_;
#pragma unroll
        for (int ks = 0; ks < 4; ++ks) {
            float4 fA = pf[(size_t)rowc * 32 + ks * 8 + hi * 2];
            float4 fB = pf[(size_t)rowc * 32 + ks * 8 + hi * 2 + 1];
            short8 s;
            s[0] = (short)f2bf_rne(fA.x); s[1] = (short)f2bf_rne(fA.y);
            s[2] = (short)f2bf_rne(fA.z); s[3] = (short)f2bf_rne(fA.w);
            s[4] = (short)f2bf_rne(fB.x); s[5] = (short)f2bf_rne(fB.y);
            s[6] = (short)f2bf_rne(fB.z); s[7] = (short)f2bf_rne(fB.w);
            a[ks] = s;
        }
    }

    f32x4v acc[8];
#pragma unroll
    for (int i = 0; i < 8; ++i) acc[i] = (f32x4v){0.f, 0.f, 0.f, 0.f};

    const uint4* wt4 = (const uint4*)WT;     // col-row = 128 bf16 = 16 uint4
#pragma unroll
    for (int cp = 0; cp < 2; ++cp) {
        short8 b[4][4];                      // [ct][ks]
#pragma unroll
        for (int ct = 0; ct < 4; ++ct) {
            int col = cp * 64 + ct * 16 + lo;
#pragma unroll
            for (int ks = 0; ks < 4; ++ks)
                b[ct][ks] = __builtin_bit_cast(short8, wt4[col * 16 + ks * 4 + hi]);
        }
#pragma unroll
        for (int ks = 0; ks < 4; ++ks)
#pragma unroll
            for (int ct = 0; ct < 4; ++ct)
                acc[cp * 4 + ct] = __builtin_amdgcn_mfma_f32_16x16x32_bf16(
                    a[ks], b[ct][ks], acc[cp * 4 + ct], 0, 0, 0);
    }

    // epilogue: scatter C to LDS, repack rows as bf16 with dinv scale
#pragma unroll
    for (int i = 0; i < 8; ++i) {
        int colb = (i >> 2) * 64 + (i & 3) * 16 + lo;
#pragma unroll
        for (int r = 0; r < 4; ++r)
            sC[w][hi * 4 + r][colb] = acc[i][r];
    }
    __syncthreads();

    if (row < N) {
        float d = dinv[rowc];
#pragma unroll
        for (int j = 0; j < 4; ++j) {
            float4 fA = *reinterpret_cast<const float4*>(&sC[w][lo][hi * 32 + j * 8]);
            float4 fB = *reinterpret_cast<const float4*>(&sC[w][lo][hi * 32 + j * 8 + 4]);
            uint4 o = { pack_bf2(fA.x * d, fA.y * d), pack_bf2(fA.z * d, fA.w * d),
                        pack_bf2(fB.x * d, fB.y * d), pack_bf2(fB.z * d, fB.w * d) };
            reinterpret_cast<uint4*>(outbf)[(size_t)row * 16 + hi * 4 + j] = o;
        }
    }
}

// ---------------- aggregation ----------------
// out[n] = relu(dinv[n]*(sum_e hw'[src_e] + hw'[n]) + b), hw' & out bf16.
// One wave per node; 4 edges per quad (quarter-wave x uint4 = 256B/row),
// 4 quads (16 edges) pipelined per iteration for 4x outstanding loads.

__global__ void k_aggr(const unsigned* __restrict__ hw, const int* __restrict__ off,
                       const int* __restrict__ csr, const float* __restrict__ dinv,
                       const float* __restrict__ bias, unsigned* __restrict__ out, int N) {
    int wid  = (blockIdx.x * blockDim.x + threadIdx.x) >> 6;
    int lane = threadIdx.x & 63;
    if (wid >= N) return;
    int n  = wid;
    int q  = lane >> 4;                       // quarter 0..3
    int li = lane & 15;                       // lane owns cols 8*li .. 8*li+7

    const uint4* hw4 = reinterpret_cast<const uint4*>(hw);

    float a0 = 0.f, a1 = 0.f, a2 = 0.f, a3 = 0.f;
    float a4 = 0.f, a5 = 0.f, a6 = 0.f, a7 = 0.f;
    if (q == 0) {                             // self term hw'[n] in quarter 0
        uint4 v = hw4[(unsigned)(n << 4) + li];
        a0 = bf_lo(v.x); a1 = bf_hi(v.x);
        a2 = bf_lo(v.y); a3 = bf_hi(v.y);
        a4 = bf_lo(v.z); a5 = bf_hi(v.z);
        a6 = bf_lo(v.w); a7 = bf_hi(v.w);
    }

    int e = off[n], e1 = off[n + 1];
    while (e < e1) {
        int rem = e1 - e;
        int cnt = rem < 64 ? rem : 64;
        int s_l = N;                          // invalid -> zero row
        if (lane < cnt) s_l = csr[e + lane];
        int jn = (cnt + 3) >> 2;              // edge quads this batch
        int j = 0;
        // 4-deep pipelined: 4 independent gathers in flight per lane
        for (; j + 4 <= jn; j += 4) {
            int s0 = __shfl(s_l, 4 * j + q);
            int s1 = __shfl(s_l, 4 * j + 4 + q);
            int s2 = __shfl(s_l, 4 * j + 8 + q);
            int s3 = __shfl(s_l, 4 * j + 12 + q);
            uint4 v0 = hw4[(unsigned)(s0 << 4) + li];
            uint4 v1 = hw4[(unsigned)(s1 << 4) + li];
            uint4 v2 = hw4[(unsigned)(s2 << 4) + li];
            uint4 v3 = hw4[(unsigned)(s3 << 4) + li];
            a0 += bf_lo(v0.x); a1 += bf_hi(v0.x);
            a2 += bf_lo(v0.y); a3 += bf_hi(v0.y);
            a4 += bf_lo(v0.z); a5 += bf_hi(v0.z);
            a6 += bf_lo(v0.w); a7 += bf_hi(v0.w);
            a0 += bf_lo(v1.x); a1 += bf_hi(v1.x);
            a2 += bf_lo(v1.y); a3 += bf_hi(v1.y);
            a4 += bf_lo(v1.z); a5 += bf_hi(v1.z);
            a6 += bf_lo(v1.w); a7 += bf_hi(v1.w);
            a0 += bf_lo(v2.x); a1 += bf_hi(v2.x);
            a2 += bf_lo(v2.y); a3 += bf_hi(v2.y);
            a4 += bf_lo(v2.z); a5 += bf_hi(v2.z);
            a6 += bf_lo(v2.w); a7 += bf_hi(v2.w);
            a0 += bf_lo(v3.x); a1 += bf_hi(v3.x);
            a2 += bf_lo(v3.y); a3 += bf_hi(v3.y);
            a4 += bf_lo(v3.z); a5 += bf_hi(v3.z);
            a6 += bf_lo(v3.w); a7 += bf_hi(v3.w);
        }
        for (; j < jn; ++j) {
            int   s = __shfl(s_l, 4 * j + q); // idx>=cnt lanes hold N -> zeros
            uint4 v = hw4[(unsigned)(s << 4) + li];
            a0 += bf_lo(v.x); a1 += bf_hi(v.x);
            a2 += bf_lo(v.y); a3 += bf_hi(v.y);
            a4 += bf_lo(v.z); a5 += bf_hi(v.z);
            a6 += bf_lo(v.w); a7 += bf_hi(v.w);
        }
        e += cnt;
    }

    // combine quarters: q0+=q2, q1+=q3 (partner +32), then q0+=q1 (+16)
    int p1 = (lane + 32) & 63;
    a0 += __shfl(a0, p1); a1 += __shfl(a1, p1);
    a2 += __shfl(a2, p1); a3 += __shfl(a3, p1);
    a4 += __shfl(a4, p1); a5 += __shfl(a5, p1);
    a6 += __shfl(a6, p1); a7 += __shfl(a7, p1);
    int p2 = (lane + 16) & 63;
    a0 += __shfl(a0, p2); a1 += __shfl(a1, p2);
    a2 += __shfl(a2, p2); a3 += __shfl(a3, p2);
    a4 += __shfl(a4, p2); a5 += __shfl(a5, p2);
    a6 += __shfl(a6, p2); a7 += __shfl(a7, p2);

    if (q == 0) {
        float di = dinv[n];
        const float4* b4 = reinterpret_cast<const float4*>(bias);
        float4 bA = b4[2 * li], bB = b4[2 * li + 1];
        a0 = fmaxf(fmaf(a0, di, bA.x), 0.f); a1 = fmaxf(fmaf(a1, di, bA.y), 0.f);
        a2 = fmaxf(fmaf(a2, di, bA.z), 0.f); a3 = fmaxf(fmaf(a3, di, bA.w), 0.f);
        a4 = fmaxf(fmaf(a4, di, bB.x), 0.f); a5 = fmaxf(fmaf(a5, di, bB.y), 0.f);
        a6 = fmaxf(fmaf(a6, di, bB.z), 0.f); a7 = fmaxf(fmaf(a7, di, bB.w), 0.f);
        uint4 r = { pack_bf2(a0, a1), pack_bf2(a2, a3),
                    pack_bf2(a4, a5), pack_bf2(a6, a7) };
        reinterpret_cast<uint4*>(out)[(unsigned)(n << 4) + li] = r;
    }
}

// ---------------- global mean pool (batch is sorted, h in bf16) ----------------

__global__ void k_pool(const unsigned* __restrict__ h, const int* __restrict__ batch,
                       float* __restrict__ pooled, int* __restrict__ cnt,
                       int N, int npw) {
    int wid  = (blockIdx.x * blockDim.x + threadIdx.x) >> 6;
    int lane = threadIdx.x & 63;
    int n0 = wid * npw;
    if (n0 >= N) return;
    int n1 = n0 + npw; if (n1 > N) n1 = N;

    float ax = 0.f, ay = 0.f;
    int g = batch[n0];
    int c = 0;
    for (int n = n0; n < n1; ++n) {
        int gn = batch[n];
        if (gn != g) {
            atomicAdd(&pooled[g * 128 + 2 * lane],     ax);
            atomicAdd(&pooled[g * 128 + 2 * lane + 1], ay);
            if (lane == 0) atomicAdd(&cnt[g], c);
            ax = 0.f; ay = 0.f; c = 0; g = gn;
        }
        unsigned v = h[(size_t)n * 64 + lane];
        ax += bf_lo(v); ay += bf_hi(v); ++c;
    }
    atomicAdd(&pooled[g * 128 + 2 * lane],     ax);
    atomicAdd(&pooled[g * 128 + 2 * lane + 1], ay);
    if (lane == 0) atomicAdd(&cnt[g], c);
}

// ---------------- MLP head + L2 normalize (tiny: 64 x 128) ----------------

__global__ void k_head(const float* __restrict__ pooled, const int* __restrict__ cnt,
                       const float* __restrict__ pW1, const float* __restrict__ pb1,
                       const float* __restrict__ pW2, const float* __restrict__ pb2,
                       float* __restrict__ out) {
    __shared__ float hg[128];
    __shared__ float z1[128];
    __shared__ float red[128];
    int g = blockIdx.x, t = threadIdx.x;   // 128 threads

    float c = fmaxf((float)cnt[g], 1.0f);
    hg[t] = pooled[g * 128 + t] / c;
    __syncthreads();

    float a = pb1[t];
#pragma unroll 8
    for (int k = 0; k < 128; ++k) a = fmaf(hg[k], pW1[k * 128 + t], a);
    z1[t] = fmaxf(a, 0.f);
    __syncthreads();

    float z = pb2[t];
#pragma unroll 8
    for (int k = 0; k < 128; ++k) z = fmaf(z1[k], pW2[k * 128 + t], z);

    red[t] = z * z;
    __syncthreads();
    for (int d = 64; d > 0; d >>= 1) {
        if (t < d) red[t] += red[t + d];
        __syncthreads();
    }
    float nrm = fmaxf(sqrtf(red[0]), 1e-12f);
    out[g * 128 + t] = z / nrm;
}

// ---------------------------------------------------------------------------

extern "C" void kernel_launch(void* const* d_in, const int* in_sizes, int n_in,
                              void* d_out, int out_size, void* d_ws, size_t ws_size,
                              hipStream_t stream) {
    const float* x    = (const float*)d_in[0];
    const int*   eidx = (const int*)  d_in[1];
    const int*   batch= (const int*)  d_in[2];
    const float* W1   = (const float*)d_in[4];
    const float* b1   = (const float*)d_in[5];
    const float* W2   = (const float*)d_in[6];
    const float* b2   = (const float*)d_in[7];
    const float* pW1  = (const float*)d_in[8];
    const float* pb1  = (const float*)d_in[9];
    const float* pW2  = (const float*)d_in[10];
    const float* pb2  = (const float*)d_in[11];
    float* out = (float*)d_out;

    const int N  = in_sizes[0] / 128;
    const int E  = in_sizes[1] / 2;
    const int NG = out_size / 128;
    const int NB = (N + 255) >> 8;    // buckets of 256 nodes; NB<=256 (N<65536)

    const int* src = eidx;      // edge_index[0]
    const int* dst = eidx + E;  // edge_index[1]

    // workspace carve-up (256B aligned)
    char* p = (char*)d_ws;
    auto alloc = [&](size_t bytes) -> void* {
        void* r = (void*)p;
        p += (bytes + 255) & ~(size_t)255;
        return r;
    };
    int*      bcnt     = (int*)     alloc((size_t)NB * 4);
    int*      bbase    = (int*)     alloc((size_t)(NB + 1) * 4);
    int*      bcur     = (int*)     alloc((size_t)NB * 4);
    int*      off      = (int*)     alloc((size_t)(N + 1) * 4);
    float*    dinv     = (float*)   alloc((size_t)N * 4);
    int*      bkt      = (int*)     alloc((size_t)E * 4);        // packed edges
    int*      csr      = (int*)     alloc((size_t)E * 4);        // src only
    unsigned short* wbt1 = (unsigned short*)alloc(16384 * 2);    // bf16 W1^T
    unsigned short* wbt2 = (unsigned short*)alloc(16384 * 2);    // bf16 W2^T
    unsigned* bufH     = (unsigned*)alloc((size_t)(N + 1) * 64 * 4); // bf16 hw' (+zero row)
    unsigned* bufB     = (unsigned*)alloc((size_t)N * 64 * 4);       // bf16 h
    float*    pooled   = (float*)   alloc((size_t)NG * 128 * 4);
    int*      cnt      = (int*)     alloc((size_t)NG * 4);

    const int tB = (E + 4095) / 4096;   // 4096-edge tiles

    hipMemsetAsync(bcnt,   0, (size_t)NB * 4, stream);
    hipMemsetAsync(bufH + (size_t)N * 64, 0, 256, stream);   // zero dummy row
    hipMemsetAsync(pooled, 0, (size_t)NG * 128 * 4, stream);
    hipMemsetAsync(cnt,    0, (size_t)NG * 4, stream);

    // CSR build: count -> scan -> bin -> per-bucket local fill
    k_bincount<<<tB, 256, 0, stream>>>(dst, bcnt, E, NB);
    k_bscan   <<<1, 256, 0, stream>>>(bcnt, bbase, bcur, NB);
    k_bin     <<<tB, 256, 0, stream>>>(src, dst, bcur, bkt, E, NB);
    k_fill2   <<<NB, 1024, 0, stream>>>(bkt, bbase, off, dinv, csr, N, E, NB);
    k_wprep   <<<2, 256, 0, stream>>>(W1, W2, wbt1, wbt2);

    const int gB = (N + 63) / 64;               // 64 rows per 256-thread block
    const int aB = (N + 3) / 4;                 // 4 waves (nodes) per block

    // layer 1: hw' = bf16(dinv*(x @ W1)) ; h1 = bf16(relu(dinv*aggr + b1))
    k_gemm<false><<<gB, 256, 0, stream>>>((const void*)x, wbt1, dinv, bufH, N);
    k_aggr<<<aB, 256, 0, stream>>>(bufH, off, csr, dinv, b1, bufB, N);
    // layer 2
    k_gemm<true><<<gB, 256, 0, stream>>>((const void*)bufB, wbt2, dinv, bufH, N);
    k_aggr<<<aB, 256, 0, stream>>>(bufH, off, csr, dinv, b2, bufB, N);

    // mean pool
    const int NPW = 32;  // nodes per wave
    const int waves = (N + NPW - 1) / NPW;
    const int pB = (waves * 64 + 255) / 256;
    k_pool<<<pB, 256, 0, stream>>>(bufB, batch, pooled, cnt, N, NPW);

    // head
    k_head<<<NG, 128, 0, stream>>>(pooled, cnt, pW1, pb1, pW2, pb2, out);
}

// Round 12
// 237.889 us; speedup vs baseline: 2.3837x; 1.0628x over previous
//
#include <hip/hip_runtime.h>
#include <cstdint>
#include <cstddef>

// ---------------------------------------------------------------------------
// SimpleGNN: 2x GCNConv(128->128) + ReLU, global mean pool (64 graphs),
// MLP head 128->128->128 + ReLU, L2 row-normalize.
//
// R12 changes vs R11 (253us; ledger implies k_gemm ~40us each hiding under
// the top-5 cut + k_wprep ~10us serial; k_aggr 48us at ~structural gather):
//  - k_gemm: W staged to LDS in-kernel (f32 coalesced read -> bf16 wbf[col][k],
//    pitch 136 shorts = exactly the b128 8-req/bank floor). B-frags via
//    ds_read_b128. k_wprep DELETED; zero global WT traffic. LDS aliased
//    (wbf 34.8KB <-> epilogue C-tile 33.8KB) via barrier. 4 blocks/CU.
//  - k_aggr: 8-deep gather pipeline (8 uint4 in flight, ~48 VGPR).
// ---------------------------------------------------------------------------

using short8 = __attribute__((ext_vector_type(8))) short;   // 8 bf16 (4 VGPRs)
using f32x4v = __attribute__((ext_vector_type(4))) float;   // 4 fp32

// ---------------- bf16 helpers ----------------

static __device__ __forceinline__ unsigned f2bf_rne(float f) {
    unsigned u = __float_as_uint(f);
    return (u + 0x7FFFu + ((u >> 16) & 1u)) >> 16;   // round-nearest-even
}
static __device__ __forceinline__ unsigned pack_bf2(float lo, float hi) {
    return f2bf_rne(lo) | (f2bf_rne(hi) << 16);
}
static __device__ __forceinline__ float bf_lo(unsigned v) {
    return __uint_as_float(v << 16);
}
static __device__ __forceinline__ float bf_hi(unsigned v) {
    return __uint_as_float(v & 0xFFFF0000u);
}

// ---------------- pass 0: bucket counts (bucket = 256 consecutive dst) ----

__global__ void k_bincount(const int* __restrict__ dst, int* __restrict__ bcnt,
                           int E, int NB) {
    __shared__ int h[256];
    int t = threadIdx.x;
    h[t] = 0;
    __syncthreads();
    int base_i = blockIdx.x * 4096;
#pragma unroll
    for (int j = 0; j < 16; ++j) {
        int i = base_i + j * 256 + t;
        if (i < E) atomicAdd(&h[dst[i] >> 8], 1);
    }
    __syncthreads();
    if (t < NB && h[t]) atomicAdd(&bcnt[t], h[t]);
}

// scan bucket counts -> bbase[0..NB], init bcur. NB <= 256.
__global__ void k_bscan(const int* __restrict__ bcnt, int* __restrict__ bbase,
                        int* __restrict__ bcur, int NB) {
    __shared__ int s[256];
    int t = threadIdx.x;
    int v = (t < NB) ? bcnt[t] : 0;
    s[t] = v;
    __syncthreads();
    for (int d = 1; d < 256; d <<= 1) {
        int x = (t >= d) ? s[t - d] : 0;
        __syncthreads();
        s[t] += x;
        __syncthreads();
    }
    if (t < NB) {
        int excl = s[t] - v;
        bbase[t] = excl;
        bcur[t]  = excl;
        if (t == NB - 1) bbase[NB] = s[t];   // total == E
    }
}

// ---------------- pass 1: coarse binning (packed 4B edges) ----------------

__global__ void k_bin(const int* __restrict__ src, const int* __restrict__ dst,
                      int* __restrict__ bcur, int* __restrict__ bkt,
                      int E, int NB) {
    __shared__ int cnt[256];
    __shared__ int pos[256];
    int t = threadIdx.x;
    int base_i = blockIdx.x * 4096;

    cnt[t] = 0;
    __syncthreads();

    int b_[16];
    int v_[16];
#pragma unroll
    for (int j = 0; j < 16; ++j) {
        int i = base_i + j * 256 + t;        // coalesced
        if (i < E) {
            int s = src[i], d = dst[i];
            v_[j] = s | ((d & 255) << 16);   // src(16b) | dlocal(8b)
            int b = d >> 8;
            b_[j] = b;
            atomicAdd(&cnt[b], 1);
        } else {
            b_[j] = -1;
        }
    }
    __syncthreads();

    if (t < NB) {
        int c = cnt[t];
        pos[t] = c ? atomicAdd(&bcur[t], c) : 0;
    }
    __syncthreads();

#pragma unroll
    for (int j = 0; j < 16; ++j) {
        if (b_[j] >= 0) {
            int p = atomicAdd(&pos[b_[j]], 1);
            bkt[p] = v_[j];
        }
    }
}

// ---------------- pass 2: per-bucket local CSR build ----------------

__global__ void k_fill2(const int* __restrict__ bkt, const int* __restrict__ bbase,
                        int* __restrict__ off, float* __restrict__ dinv,
                        int* __restrict__ csr, int N, int E, int NB) {
    __shared__ int hist[256];
    __shared__ int loff[256];
    __shared__ int cur[256];
    int b = blockIdx.x, t = threadIdx.x;     // 1024 threads
    if (t < 256) hist[t] = 0;
    __syncthreads();

    int e0 = bbase[b], e1 = bbase[b + 1];
    for (int i = e0 + t; i < e1; i += 1024)
        atomicAdd(&hist[(bkt[i] >> 16) & 255], 1);
    __syncthreads();

    if (t < 256) loff[t] = hist[t];
    __syncthreads();
    for (int d = 1; d < 256; d <<= 1) {
        int x = 0;
        if (t < 256 && t >= d) x = loff[t - d];
        __syncthreads();
        if (t < 256) loff[t] += x;
        __syncthreads();
    }

    if (t < 256) {
        int n = (b << 8) + t;
        if (n < N) {
            int base = e0 + loff[t] - hist[t];   // exclusive
            off[n]  = base;
            cur[t]  = base;
            dinv[n] = rsqrtf((float)(hist[t] + 1));  // +1 self-loop
        }
    }
    if (b == NB - 1 && t == 0) off[N] = E;
    __syncthreads();

    for (int i = e0 + t; i < e1; i += 1024) {
        int v  = bkt[i];
        int dl = (v >> 16) & 255;
        int p  = atomicAdd(&cur[dl], 1);     // LDS atomic
        csr[p] = v & 0xFFFF;                 // src only
    }
}

// ---------------- MFMA GEMM: hw'[N,128](bf16) = dinv[row]*(in @ W) ----------
// 256 threads = 4 waves; wave = 16 rows x 128 cols.
// W f32 read coalesced once per block -> bf16 LDS wbf[col][k] (pitch 136
// shorts; b128 reads hit the uniform 8-req/bank floor). After compute, the
// same LDS is reused (barrier) as the padded f32 C tile for the epilogue.

template<bool BF16IN>
__global__ __launch_bounds__(256) void k_gemm(
        const void* __restrict__ in_, const float* __restrict__ W,
        const float* __restrict__ dinv, unsigned* __restrict__ outbf, int N) {
    __shared__ __align__(16) char smem[34816];      // max(wbf 34816, sC 33792)
    unsigned short* wbf = (unsigned short*)smem;    // [128 cols][pitch 136]
    float*          sCf = (float*)smem;             // [4][16][132]

    int t = threadIdx.x;
    int w  = t >> 6;
    int l  = t & 63;
    int lo = l & 15;
    int hi = l >> 4;

    // ---- stage W: coalesced f32 reads, bf16 LDS writes (once per block) ----
#pragma unroll
    for (int i = 0; i < 16; ++i) {
        int idx = (i * 256 + t) * 4;         // 4 consecutive cols, same k
        float4 wv = *reinterpret_cast<const float4*>(W + idx);
        int k = idx >> 7, c = idx & 127;
        wbf[(c    ) * 136 + k] = (unsigned short)f2bf_rne(wv.x);
        wbf[(c + 1) * 136 + k] = (unsigned short)f2bf_rne(wv.y);
        wbf[(c + 2) * 136 + k] = (unsigned short)f2bf_rne(wv.z);
        wbf[(c + 3) * 136 + k] = (unsigned short)f2bf_rne(wv.w);
    }
    __syncthreads();

    int rbase = blockIdx.x * 64 + w * 16;
    int row   = rbase + lo;
    int rowc  = (row < N) ? row : (N - 1);

    // A-frags for all 4 k-steps: lane l <- A[l&15][(l>>4)*8 + j]
    short8 a[4];
    if constexpr (BF16IN) {
        const uint4* pu = (const uint4*)in_;
#pragma unroll
        for (int ks = 0; ks < 4; ++ks)
            a[ks] = __builtin_bit_cast(short8, pu[(size_t)rowc * 16 + ks * 4 + hi]);
    } else {
        const float4* pf = (const float4*)in_;
#pragma unroll
        for (int ks = 0; ks < 4; ++ks) {
            float4 fA = pf[(size_t)rowc * 32 + ks * 8 + hi * 2];
            float4 fB = pf[(size_t)rowc * 32 + ks * 8 + hi * 2 + 1];
            short8 s;
            s[0] = (short)f2bf_rne(fA.x); s[1] = (short)f2bf_rne(fA.y);
            s[2] = (short)f2bf_rne(fA.z); s[3] = (short)f2bf_rne(fA.w);
            s[4] = (short)f2bf_rne(fB.x); s[5] = (short)f2bf_rne(fB.y);
            s[6] = (short)f2bf_rne(fB.z); s[7] = (short)f2bf_rne(fB.w);
            a[ks] = s;
        }
    }

    f32x4v acc[8];
#pragma unroll
    for (int i = 0; i < 8; ++i) acc[i] = (f32x4v){0.f, 0.f, 0.f, 0.f};

    // B-frag: lane l <- wbf[col][ks*32 + (l>>4)*8 .. +7], 16B ds_read_b128
#pragma unroll
    for (int cp = 0; cp < 2; ++cp) {
        short8 b[4][4];                      // [ct][ks]
#pragma unroll
        for (int ct = 0; ct < 4; ++ct) {
            int col = cp * 64 + ct * 16 + lo;
#pragma unroll
            for (int ks = 0; ks < 4; ++ks)
                b[ct][ks] = *reinterpret_cast<const short8*>(
                    &wbf[col * 136 + ks * 32 + hi * 8]);
        }
#pragma unroll
        for (int ks = 0; ks < 4; ++ks)
#pragma unroll
            for (int ct = 0; ct < 4; ++ct)
                acc[cp * 4 + ct] = __builtin_amdgcn_mfma_f32_16x16x32_bf16(
                    a[ks], b[ct][ks], acc[cp * 4 + ct], 0, 0, 0);
    }
    __syncthreads();                         // all wbf reads done; reuse as sC

    // epilogue: scatter C to LDS (D: lane l reg r -> C[(l>>4)*4+r][l&15]),
    // then repack rows as bf16 with dinv scale
#pragma unroll
    for (int i = 0; i < 8; ++i) {
        int colb = (i >> 2) * 64 + (i & 3) * 16 + lo;
#pragma unroll
        for (int r = 0; r < 4; ++r)
            sCf[(w * 16 + hi * 4 + r) * 132 + colb] = acc[i][r];
    }
    __syncthreads();

    if (row < N) {
        float d = dinv[rowc];
#pragma unroll
        for (int j = 0; j < 4; ++j) {
            float4 fA = *reinterpret_cast<const float4*>(
                &sCf[(w * 16 + lo) * 132 + hi * 32 + j * 8]);
            float4 fB = *reinterpret_cast<const float4*>(
                &sCf[(w * 16 + lo) * 132 + hi * 32 + j * 8 + 4]);
            uint4 o = { pack_bf2(fA.x * d, fA.y * d), pack_bf2(fA.z * d, fA.w * d),
                        pack_bf2(fB.x * d, fB.y * d), pack_bf2(fB.z * d, fB.w * d) };
            reinterpret_cast<uint4*>(outbf)[(size_t)row * 16 + hi * 4 + j] = o;
        }
    }
}

// ---------------- aggregation ----------------
// out[n] = relu(dinv[n]*(sum_e hw'[src_e] + hw'[n]) + b), hw' & out bf16.
// One wave per node; 4 edges per quad (quarter-wave x uint4 = 256B/row),
// 8 quads (32 edges) pipelined per iteration -> 8 outstanding gathers/lane.

__global__ void k_aggr(const unsigned* __restrict__ hw, const int* __restrict__ off,
                       const int* __restrict__ csr, const float* __restrict__ dinv,
                       const float* __restrict__ bias, unsigned* __restrict__ out, int N) {
    int wid  = (blockIdx.x * blockDim.x + threadIdx.x) >> 6;
    int lane = threadIdx.x & 63;
    if (wid >= N) return;
    int n  = wid;
    int q  = lane >> 4;                       // quarter 0..3
    int li = lane & 15;                       // lane owns cols 8*li .. 8*li+7

    const uint4* hw4 = reinterpret_cast<const uint4*>(hw);

    float a0 = 0.f, a1 = 0.f, a2 = 0.f, a3 = 0.f;
    float a4 = 0.f, a5 = 0.f, a6 = 0.f, a7 = 0.f;
    if (q == 0) {                             // self term hw'[n] in quarter 0
        uint4 v = hw4[(unsigned)(n << 4) + li];
        a0 = bf_lo(v.x); a1 = bf_hi(v.x);
        a2 = bf_lo(v.y); a3 = bf_hi(v.y);
        a4 = bf_lo(v.z); a5 = bf_hi(v.z);
        a6 = bf_lo(v.w); a7 = bf_hi(v.w);
    }

#define ACC8(v) \
    a0 += bf_lo(v.x); a1 += bf_hi(v.x); \
    a2 += bf_lo(v.y); a3 += bf_hi(v.y); \
    a4 += bf_lo(v.z); a5 += bf_hi(v.z); \
    a6 += bf_lo(v.w); a7 += bf_hi(v.w);

    int e = off[n], e1 = off[n + 1];
    while (e < e1) {
        int rem = e1 - e;
        int cnt = rem < 64 ? rem : 64;
        int s_l = N;                          // invalid -> zero row
        if (lane < cnt) s_l = csr[e + lane];
        int jn = (cnt + 3) >> 2;              // edge quads this batch
        int j = 0;
        // 8-deep pipelined: 8 independent gathers in flight per lane
        for (; j + 8 <= jn; j += 8) {
            int s0 = __shfl(s_l, 4 * j + q);
            int s1 = __shfl(s_l, 4 * j + 4 + q);
            int s2 = __shfl(s_l, 4 * j + 8 + q);
            int s3 = __shfl(s_l, 4 * j + 12 + q);
            int s4 = __shfl(s_l, 4 * j + 16 + q);
            int s5 = __shfl(s_l, 4 * j + 20 + q);
            int s6 = __shfl(s_l, 4 * j + 24 + q);
            int s7 = __shfl(s_l, 4 * j + 28 + q);
            uint4 v0 = hw4[(unsigned)(s0 << 4) + li];
            uint4 v1 = hw4[(unsigned)(s1 << 4) + li];
            uint4 v2 = hw4[(unsigned)(s2 << 4) + li];
            uint4 v3 = hw4[(unsigned)(s3 << 4) + li];
            uint4 v4 = hw4[(unsigned)(s4 << 4) + li];
            uint4 v5 = hw4[(unsigned)(s5 << 4) + li];
            uint4 v6 = hw4[(unsigned)(s6 << 4) + li];
            uint4 v7 = hw4[(unsigned)(s7 << 4) + li];
            ACC8(v0) ACC8(v1) ACC8(v2) ACC8(v3)
            ACC8(v4) ACC8(v5) ACC8(v6) ACC8(v7)
        }
        for (; j + 4 <= jn; j += 4) {
            int s0 = __shfl(s_l, 4 * j + q);
            int s1 = __shfl(s_l, 4 * j + 4 + q);
            int s2 = __shfl(s_l, 4 * j + 8 + q);
            int s3 = __shfl(s_l, 4 * j + 12 + q);
            uint4 v0 = hw4[(unsigned)(s0 << 4) + li];
            uint4 v1 = hw4[(unsigned)(s1 << 4) + li];
            uint4 v2 = hw4[(unsigned)(s2 << 4) + li];
            uint4 v3 = hw4[(unsigned)(s3 << 4) + li];
            ACC8(v0) ACC8(v1) ACC8(v2) ACC8(v3)
        }
        for (; j < jn; ++j) {
            int   s = __shfl(s_l, 4 * j + q); // idx>=cnt lanes hold N -> zeros
            uint4 v = hw4[(unsigned)(s << 4) + li];
            ACC8(v)
        }
        e += cnt;
    }
#undef ACC8

    // combine quarters: q0+=q2, q1+=q3 (partner +32), then q0+=q1 (+16)
    int p1 = (lane + 32) & 63;
    a0 += __shfl(a0, p1); a1 += __shfl(a1, p1);
    a2 += __shfl(a2, p1); a3 += __shfl(a3, p1);
    a4 += __shfl(a4, p1); a5 += __shfl(a5, p1);
    a6 += __shfl(a6, p1); a7 += __shfl(a7, p1);
    int p2 = (lane + 16) & 63;
    a0 += __shfl(a0, p2); a1 += __shfl(a1, p2);
    a2 += __shfl(a2, p2); a3 += __shfl(a3, p2);
    a4 += __shfl(a4, p2); a5 += __shfl(a5, p2);
    a6 += __shfl(a6, p2); a7 += __shfl(a7, p2);

    if (q == 0) {
        float di = dinv[n];
        const float4* b4 = reinterpret_cast<const float4*>(bias);
        float4 bA = b4[2 * li], bB = b4[2 * li + 1];
        a0 = fmaxf(fmaf(a0, di, bA.x), 0.f); a1 = fmaxf(fmaf(a1, di, bA.y), 0.f);
        a2 = fmaxf(fmaf(a2, di, bA.z), 0.f); a3 = fmaxf(fmaf(a3, di, bA.w), 0.f);
        a4 = fmaxf(fmaf(a4, di, bB.x), 0.f); a5 = fmaxf(fmaf(a5, di, bB.y), 0.f);
        a6 = fmaxf(fmaf(a6, di, bB.z), 0.f); a7 = fmaxf(fmaf(a7, di, bB.w), 0.f);
        uint4 r = { pack_bf2(a0, a1), pack_bf2(a2, a3),
                    pack_bf2(a4, a5), pack_bf2(a6, a7) };
        reinterpret_cast<uint4*>(out)[(unsigned)(n << 4) + li] = r;
    }
}

// ---------------- global mean pool (batch is sorted, h in bf16) ----------------

__global__ void k_pool(const unsigned* __restrict__ h, const int* __restrict__ batch,
                       float* __restrict__ pooled, int* __restrict__ cnt,
                       int N, int npw) {
    int wid  = (blockIdx.x * blockDim.x + threadIdx.x) >> 6;
    int lane = threadIdx.x & 63;
    int n0 = wid * npw;
    if (n0 >= N) return;
    int n1 = n0 + npw; if (n1 > N) n1 = N;

    float ax = 0.f, ay = 0.f;
    int g = batch[n0];
    int c = 0;
    for (int n = n0; n < n1; ++n) {
        int gn = batch[n];
        if (gn != g) {
            atomicAdd(&pooled[g * 128 + 2 * lane],     ax);
            atomicAdd(&pooled[g * 128 + 2 * lane + 1], ay);
            if (lane == 0) atomicAdd(&cnt[g], c);
            ax = 0.f; ay = 0.f; c = 0; g = gn;
        }
        unsigned v = h[(size_t)n * 64 + lane];
        ax += bf_lo(v); ay += bf_hi(v); ++c;
    }
    atomicAdd(&pooled[g * 128 + 2 * lane],     ax);
    atomicAdd(&pooled[g * 128 + 2 * lane + 1], ay);
    if (lane == 0) atomicAdd(&cnt[g], c);
}

// ---------------- MLP head + L2 normalize (tiny: 64 x 128) ----------------

__global__ void k_head(const float* __restrict__ pooled, const int* __restrict__ cnt,
                       const float* __restrict__ pW1, const float* __restrict__ pb1,
                       const float* __restrict__ pW2, const float* __restrict__ pb2,
                       float* __restrict__ out) {
    __shared__ float hg[128];
    __shared__ float z1[128];
    __shared__ float red[128];
    int g = blockIdx.x, t = threadIdx.x;   // 128 threads

    float c = fmaxf((float)cnt[g], 1.0f);
    hg[t] = pooled[g * 128 + t] / c;
    __syncthreads();

    float a = pb1[t];
#pragma unroll 8
    for (int k = 0; k < 128; ++k) a = fmaf(hg[k], pW1[k * 128 + t], a);
    z1[t] = fmaxf(a, 0.f);
    __syncthreads();

    float z = pb2[t];
#pragma unroll 8
    for (int k = 0; k < 128; ++k) z = fmaf(z1[k], pW2[k * 128 + t], z);

    red[t] = z * z;
    __syncthreads();
    for (int d = 64; d > 0; d >>= 1) {
        if (t < d) red[t] += red[t + d];
        __syncthreads();
    }
    float nrm = fmaxf(sqrtf(red[0]), 1e-12f);
    out[g * 128 + t] = z / nrm;
}

// ---------------------------------------------------------------------------

extern "C" void kernel_launch(void* const* d_in, const int* in_sizes, int n_in,
                              void* d_out, int out_size, void* d_ws, size_t ws_size,
                              hipStream_t stream) {
    const float* x    = (const float*)d_in[0];
    const int*   eidx = (const int*)  d_in[1];
    const int*   batch= (const int*)  d_in[2];
    const float* W1   = (const float*)d_in[4];
    const float* b1   = (const float*)d_in[5];
    const float* W2   = (const float*)d_in[6];
    const float* b2   = (const float*)d_in[7];
    const float* pW1  = (const float*)d_in[8];
    const float* pb1  = (const float*)d_in[9];
    const float* pW2  = (const float*)d_in[10];
    const float* pb2  = (const float*)d_in[11];
    float* out = (float*)d_out;

    const int N  = in_sizes[0] / 128;
    const int E  = in_sizes[1] / 2;
    const int NG = out_size / 128;
    const int NB = (N + 255) >> 8;    // buckets of 256 nodes; NB<=256 (N<65536)

    const int* src = eidx;      // edge_index[0]
    const int* dst = eidx + E;  // edge_index[1]

    // workspace carve-up (256B aligned)
    char* p = (char*)d_ws;
    auto alloc = [&](size_t bytes) -> void* {
        void* r = (void*)p;
        p += (bytes + 255) & ~(size_t)255;
        return r;
    };
    int*      bcnt     = (int*)     alloc((size_t)NB * 4);
    int*      bbase    = (int*)     alloc((size_t)(NB + 1) * 4);
    int*      bcur     = (int*)     alloc((size_t)NB * 4);
    int*      off      = (int*)     alloc((size_t)(N + 1) * 4);
    float*    dinv     = (float*)   alloc((size_t)N * 4);
    int*      bkt      = (int*)     alloc((size_t)E * 4);        // packed edges
    int*      csr      = (int*)     alloc((size_t)E * 4);        // src only
    unsigned* bufH     = (unsigned*)alloc((size_t)(N + 1) * 64 * 4); // bf16 hw' (+zero row)
    unsigned* bufB     = (unsigned*)alloc((size_t)N * 64 * 4);       // bf16 h
    float*    pooled   = (float*)   alloc((size_t)NG * 128 * 4);
    int*      cnt      = (int*)     alloc((size_t)NG * 4);

    const int tB = (E + 4095) / 4096;   // 4096-edge tiles

    hipMemsetAsync(bcnt,   0, (size_t)NB * 4, stream);
    hipMemsetAsync(bufH + (size_t)N * 64, 0, 256, stream);   // zero dummy row
    hipMemsetAsync(pooled, 0, (size_t)NG * 128 * 4, stream);
    hipMemsetAsync(cnt,    0, (size_t)NG * 4, stream);

    // CSR build: count -> scan -> bin -> per-bucket local fill
    k_bincount<<<tB, 256, 0, stream>>>(dst, bcnt, E, NB);
    k_bscan   <<<1, 256, 0, stream>>>(bcnt, bbase, bcur, NB);
    k_bin     <<<tB, 256, 0, stream>>>(src, dst, bcur, bkt, E, NB);
    k_fill2   <<<NB, 1024, 0, stream>>>(bkt, bbase, off, dinv, csr, N, E, NB);

    const int gB = (N + 63) / 64;               // 64 rows per 256-thread block
    const int aB = (N + 3) / 4;                 // 4 waves (nodes) per block

    // layer 1: hw' = bf16(dinv*(x @ W1)) ; h1 = bf16(relu(dinv*aggr + b1))
    k_gemm<false><<<gB, 256, 0, stream>>>((const void*)x, W1, dinv, bufH, N);
    k_aggr<<<aB, 256, 0, stream>>>(bufH, off, csr, dinv, b1, bufB, N);
    // layer 2
    k_gemm<true><<<gB, 256, 0, stream>>>((const void*)bufB, W2, dinv, bufH, N);
    k_aggr<<<aB, 256, 0, stream>>>(bufH, off, csr, dinv, b2, bufB, N);

    // mean pool
    const int NPW = 32;  // nodes per wave
    const int waves = (N + NPW - 1) / NPW;
    const int pB = (waves * 64 + 255) / 256;
    k_pool<<<pB, 256, 0, stream>>>(bufB, batch, pooled, cnt, N, NPW);

    // head
    k_head<<<NG, 128, 0, stream>>>(pooled, cnt, pW1, pb1, pW2, pb2, out);
}

// Round 13
// 221.860 us; speedup vs baseline: 2.5560x; 1.0722x over previous
//
#include <hip/hip_runtime.h>
#include <cstdint>
#include <cstddef>

// ---------------------------------------------------------------------------
// SimpleGNN: 2x GCNConv(128->128) + ReLU, global mean pool (64 graphs),
// MLP head 128->128->128 + ReLU, L2 row-normalize.
//
// R13 changes vs R12 (238us; aggr 2x49us = structural gather floor; ledger
// says gemm ~30-40us each hides under the top-5 cut):
//  - k_gemm: 2 row-tiles per block (grid 391; W LDS-staged ONCE, reused),
//    and barrier-free epilogue: D-layout row=(l>>4)*4+r, col=l&15 means the
//    16 lo-lanes of a quarter hold 16 consecutive cols of one row -> store
//    bf16 shorts directly to bufH (full-line coverage). sC tile + 2 barriers
//    deleted; LDS = W only (34816B).
//  - memsets: bcnt/cnt/pooled made contiguous -> single memset.
//  - k_aggr unchanged (49us = beyond-L2 service floor at ~3.4 TB/s).
// ---------------------------------------------------------------------------

using short8 = __attribute__((ext_vector_type(8))) short;   // 8 bf16 (4 VGPRs)
using f32x4v = __attribute__((ext_vector_type(4))) float;   // 4 fp32

// ---------------- bf16 helpers ----------------

static __device__ __forceinline__ unsigned f2bf_rne(float f) {
    unsigned u = __float_as_uint(f);
    return (u + 0x7FFFu + ((u >> 16) & 1u)) >> 16;   // round-nearest-even
}
static __device__ __forceinline__ unsigned pack_bf2(float lo, float hi) {
    return f2bf_rne(lo) | (f2bf_rne(hi) << 16);
}
static __device__ __forceinline__ float bf_lo(unsigned v) {
    return __uint_as_float(v << 16);
}
static __device__ __forceinline__ float bf_hi(unsigned v) {
    return __uint_as_float(v & 0xFFFF0000u);
}

// ---------------- pass 0: bucket counts (bucket = 256 consecutive dst) ----

__global__ void k_bincount(const int* __restrict__ dst, int* __restrict__ bcnt,
                           int E, int NB) {
    __shared__ int h[256];
    int t = threadIdx.x;
    h[t] = 0;
    __syncthreads();
    int base_i = blockIdx.x * 4096;
#pragma unroll
    for (int j = 0; j < 16; ++j) {
        int i = base_i + j * 256 + t;
        if (i < E) atomicAdd(&h[dst[i] >> 8], 1);
    }
    __syncthreads();
    if (t < NB && h[t]) atomicAdd(&bcnt[t], h[t]);
}

// scan bucket counts -> bbase[0..NB], init bcur. NB <= 256.
__global__ void k_bscan(const int* __restrict__ bcnt, int* __restrict__ bbase,
                        int* __restrict__ bcur, int NB) {
    __shared__ int s[256];
    int t = threadIdx.x;
    int v = (t < NB) ? bcnt[t] : 0;
    s[t] = v;
    __syncthreads();
    for (int d = 1; d < 256; d <<= 1) {
        int x = (t >= d) ? s[t - d] : 0;
        __syncthreads();
        s[t] += x;
        __syncthreads();
    }
    if (t < NB) {
        int excl = s[t] - v;
        bbase[t] = excl;
        bcur[t]  = excl;
        if (t == NB - 1) bbase[NB] = s[t];   // total == E
    }
}

// ---------------- pass 1: coarse binning (packed 4B edges) ----------------

__global__ void k_bin(const int* __restrict__ src, const int* __restrict__ dst,
                      int* __restrict__ bcur, int* __restrict__ bkt,
                      int E, int NB) {
    __shared__ int cnt[256];
    __shared__ int pos[256];
    int t = threadIdx.x;
    int base_i = blockIdx.x * 4096;

    cnt[t] = 0;
    __syncthreads();

    int b_[16];
    int v_[16];
#pragma unroll
    for (int j = 0; j < 16; ++j) {
        int i = base_i + j * 256 + t;        // coalesced
        if (i < E) {
            int s = src[i], d = dst[i];
            v_[j] = s | ((d & 255) << 16);   // src(16b) | dlocal(8b)
            int b = d >> 8;
            b_[j] = b;
            atomicAdd(&cnt[b], 1);
        } else {
            b_[j] = -1;
        }
    }
    __syncthreads();

    if (t < NB) {
        int c = cnt[t];
        pos[t] = c ? atomicAdd(&bcur[t], c) : 0;
    }
    __syncthreads();

#pragma unroll
    for (int j = 0; j < 16; ++j) {
        if (b_[j] >= 0) {
            int p = atomicAdd(&pos[b_[j]], 1);
            bkt[p] = v_[j];
        }
    }
}

// ---------------- pass 2: per-bucket local CSR build ----------------

__global__ void k_fill2(const int* __restrict__ bkt, const int* __restrict__ bbase,
                        int* __restrict__ off, float* __restrict__ dinv,
                        int* __restrict__ csr, int N, int E, int NB) {
    __shared__ int hist[256];
    __shared__ int loff[256];
    __shared__ int cur[256];
    int b = blockIdx.x, t = threadIdx.x;     // 1024 threads
    if (t < 256) hist[t] = 0;
    __syncthreads();

    int e0 = bbase[b], e1 = bbase[b + 1];
    for (int i = e0 + t; i < e1; i += 1024)
        atomicAdd(&hist[(bkt[i] >> 16) & 255], 1);
    __syncthreads();

    if (t < 256) loff[t] = hist[t];
    __syncthreads();
    for (int d = 1; d < 256; d <<= 1) {
        int x = 0;
        if (t < 256 && t >= d) x = loff[t - d];
        __syncthreads();
        if (t < 256) loff[t] += x;
        __syncthreads();
    }

    if (t < 256) {
        int n = (b << 8) + t;
        if (n < N) {
            int base = e0 + loff[t] - hist[t];   // exclusive
            off[n]  = base;
            cur[t]  = base;
            dinv[n] = rsqrtf((float)(hist[t] + 1));  // +1 self-loop
        }
    }
    if (b == NB - 1 && t == 0) off[N] = E;
    __syncthreads();

    for (int i = e0 + t; i < e1; i += 1024) {
        int v  = bkt[i];
        int dl = (v >> 16) & 255;
        int p  = atomicAdd(&cur[dl], 1);     // LDS atomic
        csr[p] = v & 0xFFFF;                 // src only
    }
}

// ---------------- MFMA GEMM: hw'[N,128](bf16) = dinv[row]*(in @ W) ----------
// 256 threads = 4 waves; wave = 16 rows x 128 cols; 2 row-tiles per block
// (W LDS-staged once). Barrier-free epilogue via direct bf16 short stores:
// D: lane l, reg r -> C[(l>>4)*4 + r][l&15]; 16 lo-lanes = 16 consecutive
// cols of one row.

template<bool BF16IN>
__global__ __launch_bounds__(256) void k_gemm(
        const void* __restrict__ in_, const float* __restrict__ W,
        const float* __restrict__ dinv, unsigned* __restrict__ outbf, int N) {
    __shared__ unsigned short wbf[128 * 136];       // [col][k], pitch 136

    int t = threadIdx.x;
    int w  = t >> 6;
    int l  = t & 63;
    int lo = l & 15;
    int hi = l >> 4;

    // ---- stage W: coalesced f32 reads, bf16 LDS writes (once per block) ----
#pragma unroll
    for (int i = 0; i < 16; ++i) {
        int idx = (i * 256 + t) * 4;         // 4 consecutive cols, same k
        float4 wv = *reinterpret_cast<const float4*>(W + idx);
        int k = idx >> 7, c = idx & 127;
        wbf[(c    ) * 136 + k] = (unsigned short)f2bf_rne(wv.x);
        wbf[(c + 1) * 136 + k] = (unsigned short)f2bf_rne(wv.y);
        wbf[(c + 2) * 136 + k] = (unsigned short)f2bf_rne(wv.z);
        wbf[(c + 3) * 136 + k] = (unsigned short)f2bf_rne(wv.w);
    }
    __syncthreads();

    unsigned short* outS = (unsigned short*)outbf;

#pragma unroll
    for (int tt = 0; tt < 2; ++tt) {
        int rbase = (blockIdx.x * 2 + tt) * 64 + w * 16;
        if (rbase >= N) continue;            // no barriers below: safe
        int row  = rbase + lo;
        int rowc = (row < N) ? row : (N - 1);

        // A-frags: lane l <- A[l&15][(l>>4)*8 + j]
        short8 a[4];
        if constexpr (BF16IN) {
            const uint4* pu = (const uint4*)in_;
#pragma unroll
            for (int ks = 0; ks < 4; ++ks)
                a[ks] = __builtin_bit_cast(short8, pu[(size_t)rowc * 16 + ks * 4 + hi]);
        } else {
            const float4* pf = (const float4*)in_;
#pragma unroll
            for (int ks = 0; ks < 4; ++ks) {
                float4 fA = pf[(size_t)rowc * 32 + ks * 8 + hi * 2];
                float4 fB = pf[(size_t)rowc * 32 + ks * 8 + hi * 2 + 1];
                short8 s;
                s[0] = (short)f2bf_rne(fA.x); s[1] = (short)f2bf_rne(fA.y);
                s[2] = (short)f2bf_rne(fA.z); s[3] = (short)f2bf_rne(fA.w);
                s[4] = (short)f2bf_rne(fB.x); s[5] = (short)f2bf_rne(fB.y);
                s[6] = (short)f2bf_rne(fB.z); s[7] = (short)f2bf_rne(fB.w);
                a[ks] = s;
            }
        }

        f32x4v acc[8];
#pragma unroll
        for (int i = 0; i < 8; ++i) acc[i] = (f32x4v){0.f, 0.f, 0.f, 0.f};

        // B-frag: lane l <- wbf[col][ks*32 + (l>>4)*8 .. +7] (ds_read_b128)
#pragma unroll
        for (int cp = 0; cp < 2; ++cp) {
            short8 b[4][4];                  // [ct][ks]
#pragma unroll
            for (int ct = 0; ct < 4; ++ct) {
                int col = cp * 64 + ct * 16 + lo;
#pragma unroll
                for (int ks = 0; ks < 4; ++ks)
                    b[ct][ks] = *reinterpret_cast<const short8*>(
                        &wbf[col * 136 + ks * 32 + hi * 8]);
            }
#pragma unroll
            for (int ks = 0; ks < 4; ++ks)
#pragma unroll
                for (int ct = 0; ct < 4; ++ct)
                    acc[cp * 4 + ct] = __builtin_amdgcn_mfma_f32_16x16x32_bf16(
                        a[ks], b[ct][ks], acc[cp * 4 + ct], 0, 0, 0);
        }

        // epilogue: direct bf16 short stores; (hi,r) fixes the row, lo = col
#pragma unroll
        for (int r = 0; r < 4; ++r) {
            int orow = rbase + hi * 4 + r;
            if (orow < N) {
                float d = dinv[orow];
#pragma unroll
                for (int i = 0; i < 8; ++i) {
                    int colb = (i >> 2) * 64 + (i & 3) * 16 + lo;
                    outS[(size_t)orow * 128 + colb] =
                        (unsigned short)f2bf_rne(acc[i][r] * d);
                }
            }
        }
    }
}

// ---------------- aggregation ----------------
// out[n] = relu(dinv[n]*(sum_e hw'[src_e] + hw'[n]) + b), hw' & out bf16.
// One wave per node; 4 edges per quad (quarter-wave x uint4 = 256B/row),
// 8 quads pipelined -> 8 outstanding gathers/lane.

__global__ void k_aggr(const unsigned* __restrict__ hw, const int* __restrict__ off,
                       const int* __restrict__ csr, const float* __restrict__ dinv,
                       const float* __restrict__ bias, unsigned* __restrict__ out, int N) {
    int wid  = (blockIdx.x * blockDim.x + threadIdx.x) >> 6;
    int lane = threadIdx.x & 63;
    if (wid >= N) return;
    int n  = wid;
    int q  = lane >> 4;                       // quarter 0..3
    int li = lane & 15;                       // lane owns cols 8*li .. 8*li+7

    const uint4* hw4 = reinterpret_cast<const uint4*>(hw);

    float a0 = 0.f, a1 = 0.f, a2 = 0.f, a3 = 0.f;
    float a4 = 0.f, a5 = 0.f, a6 = 0.f, a7 = 0.f;
    if (q == 0) {                             // self term hw'[n] in quarter 0
        uint4 v = hw4[(unsigned)(n << 4) + li];
        a0 = bf_lo(v.x); a1 = bf_hi(v.x);
        a2 = bf_lo(v.y); a3 = bf_hi(v.y);
        a4 = bf_lo(v.z); a5 = bf_hi(v.z);
        a6 = bf_lo(v.w); a7 = bf_hi(v.w);
    }

#define ACC8(v) \
    a0 += bf_lo(v.x); a1 += bf_hi(v.x); \
    a2 += bf_lo(v.y); a3 += bf_hi(v.y); \
    a4 += bf_lo(v.z); a5 += bf_hi(v.z); \
    a6 += bf_lo(v.w); a7 += bf_hi(v.w);

    int e = off[n], e1 = off[n + 1];
    while (e < e1) {
        int rem = e1 - e;
        int cnt = rem < 64 ? rem : 64;
        int s_l = N;                          // invalid -> zero row
        if (lane < cnt) s_l = csr[e + lane];
        int jn = (cnt + 3) >> 2;              // edge quads this batch
        int j = 0;
        for (; j + 8 <= jn; j += 8) {
            int s0 = __shfl(s_l, 4 * j + q);
            int s1 = __shfl(s_l, 4 * j + 4 + q);
            int s2 = __shfl(s_l, 4 * j + 8 + q);
            int s3 = __shfl(s_l, 4 * j + 12 + q);
            int s4 = __shfl(s_l, 4 * j + 16 + q);
            int s5 = __shfl(s_l, 4 * j + 20 + q);
            int s6 = __shfl(s_l, 4 * j + 24 + q);
            int s7 = __shfl(s_l, 4 * j + 28 + q);
            uint4 v0 = hw4[(unsigned)(s0 << 4) + li];
            uint4 v1 = hw4[(unsigned)(s1 << 4) + li];
            uint4 v2 = hw4[(unsigned)(s2 << 4) + li];
            uint4 v3 = hw4[(unsigned)(s3 << 4) + li];
            uint4 v4 = hw4[(unsigned)(s4 << 4) + li];
            uint4 v5 = hw4[(unsigned)(s5 << 4) + li];
            uint4 v6 = hw4[(unsigned)(s6 << 4) + li];
            uint4 v7 = hw4[(unsigned)(s7 << 4) + li];
            ACC8(v0) ACC8(v1) ACC8(v2) ACC8(v3)
            ACC8(v4) ACC8(v5) ACC8(v6) ACC8(v7)
        }
        for (; j + 4 <= jn; j += 4) {
            int s0 = __shfl(s_l, 4 * j + q);
            int s1 = __shfl(s_l, 4 * j + 4 + q);
            int s2 = __shfl(s_l, 4 * j + 8 + q);
            int s3 = __shfl(s_l, 4 * j + 12 + q);
            uint4 v0 = hw4[(unsigned)(s0 << 4) + li];
            uint4 v1 = hw4[(unsigned)(s1 << 4) + li];
            uint4 v2 = hw4[(unsigned)(s2 << 4) + li];
            uint4 v3 = hw4[(unsigned)(s3 << 4) + li];
            ACC8(v0) ACC8(v1) ACC8(v2) ACC8(v3)
        }
        for (; j < jn; ++j) {
            int   s = __shfl(s_l, 4 * j + q); // idx>=cnt lanes hold N -> zeros
            uint4 v = hw4[(unsigned)(s << 4) + li];
            ACC8(v)
        }
        e += cnt;
    }
#undef ACC8

    // combine quarters: q0+=q2, q1+=q3 (partner +32), then q0+=q1 (+16)
    int p1 = (lane + 32) & 63;
    a0 += __shfl(a0, p1); a1 += __shfl(a1, p1);
    a2 += __shfl(a2, p1); a3 += __shfl(a3, p1);
    a4 += __shfl(a4, p1); a5 += __shfl(a5, p1);
    a6 += __shfl(a6, p1); a7 += __shfl(a7, p1);
    int p2 = (lane + 16) & 63;
    a0 += __shfl(a0, p2); a1 += __shfl(a1, p2);
    a2 += __shfl(a2, p2); a3 += __shfl(a3, p2);
    a4 += __shfl(a4, p2); a5 += __shfl(a5, p2);
    a6 += __shfl(a6, p2); a7 += __shfl(a7, p2);

    if (q == 0) {
        float di = dinv[n];
        const float4* b4 = reinterpret_cast<const float4*>(bias);
        float4 bA = b4[2 * li], bB = b4[2 * li + 1];
        a0 = fmaxf(fmaf(a0, di, bA.x), 0.f); a1 = fmaxf(fmaf(a1, di, bA.y), 0.f);
        a2 = fmaxf(fmaf(a2, di, bA.z), 0.f); a3 = fmaxf(fmaf(a3, di, bA.w), 0.f);
        a4 = fmaxf(fmaf(a4, di, bB.x), 0.f); a5 = fmaxf(fmaf(a5, di, bB.y), 0.f);
        a6 = fmaxf(fmaf(a6, di, bB.z), 0.f); a7 = fmaxf(fmaf(a7, di, bB.w), 0.f);
        uint4 r = { pack_bf2(a0, a1), pack_bf2(a2, a3),
                    pack_bf2(a4, a5), pack_bf2(a6, a7) };
        reinterpret_cast<uint4*>(out)[(unsigned)(n << 4) + li] = r;
    }
}

// ---------------- global mean pool (batch is sorted, h in bf16) ----------------

__global__ void k_pool(const unsigned* __restrict__ h, const int* __restrict__ batch,
                       float* __restrict__ pooled, int* __restrict__ cnt,
                       int N, int npw) {
    int wid  = (blockIdx.x * blockDim.x + threadIdx.x) >> 6;
    int lane = threadIdx.x & 63;
    int n0 = wid * npw;
    if (n0 >= N) return;
    int n1 = n0 + npw; if (n1 > N) n1 = N;

    float ax = 0.f, ay = 0.f;
    int g = batch[n0];
    int c = 0;
    for (int n = n0; n < n1; ++n) {
        int gn = batch[n];
        if (gn != g) {
            atomicAdd(&pooled[g * 128 + 2 * lane],     ax);
            atomicAdd(&pooled[g * 128 + 2 * lane + 1], ay);
            if (lane == 0) atomicAdd(&cnt[g], c);
            ax = 0.f; ay = 0.f; c = 0; g = gn;
        }
        unsigned v = h[(size_t)n * 64 + lane];
        ax += bf_lo(v); ay += bf_hi(v); ++c;
    }
    atomicAdd(&pooled[g * 128 + 2 * lane],     ax);
    atomicAdd(&pooled[g * 128 + 2 * lane + 1], ay);
    if (lane == 0) atomicAdd(&cnt[g], c);
}

// ---------------- MLP head + L2 normalize (tiny: 64 x 128) ----------------

__global__ void k_head(const float* __restrict__ pooled, const int* __restrict__ cnt,
                       const float* __restrict__ pW1, const float* __restrict__ pb1,
                       const float* __restrict__ pW2, const float* __restrict__ pb2,
                       float* __restrict__ out) {
    __shared__ float hg[128];
    __shared__ float z1[128];
    __shared__ float red[128];
    int g = blockIdx.x, t = threadIdx.x;   // 128 threads

    float c = fmaxf((float)cnt[g], 1.0f);
    hg[t] = pooled[g * 128 + t] / c;
    __syncthreads();

    float a = pb1[t];
#pragma unroll 8
    for (int k = 0; k < 128; ++k) a = fmaf(hg[k], pW1[k * 128 + t], a);
    z1[t] = fmaxf(a, 0.f);
    __syncthreads();

    float z = pb2[t];
#pragma unroll 8
    for (int k = 0; k < 128; ++k) z = fmaf(z1[k], pW2[k * 128 + t], z);

    red[t] = z * z;
    __syncthreads();
    for (int d = 64; d > 0; d >>= 1) {
        if (t < d) red[t] += red[t + d];
        __syncthreads();
    }
    float nrm = fmaxf(sqrtf(red[0]), 1e-12f);
    out[g * 128 + t] = z / nrm;
}

// ---------------------------------------------------------------------------

extern "C" void kernel_launch(void* const* d_in, const int* in_sizes, int n_in,
                              void* d_out, int out_size, void* d_ws, size_t ws_size,
                              hipStream_t stream) {
    const float* x    = (const float*)d_in[0];
    const int*   eidx = (const int*)  d_in[1];
    const int*   batch= (const int*)  d_in[2];
    const float* W1   = (const float*)d_in[4];
    const float* b1   = (const float*)d_in[5];
    const float* W2   = (const float*)d_in[6];
    const float* b2   = (const float*)d_in[7];
    const float* pW1  = (const float*)d_in[8];
    const float* pb1  = (const float*)d_in[9];
    const float* pW2  = (const float*)d_in[10];
    const float* pb2  = (const float*)d_in[11];
    float* out = (float*)d_out;

    const int N  = in_sizes[0] / 128;
    const int E  = in_sizes[1] / 2;
    const int NG = out_size / 128;
    const int NB = (N + 255) >> 8;    // buckets of 256 nodes; NB<=256 (N<65536)

    const int* src = eidx;      // edge_index[0]
    const int* dst = eidx + E;  // edge_index[1]

    // workspace carve-up (256B aligned); zero-init group FIRST (one memset)
    char* p = (char*)d_ws;
    auto alloc = [&](size_t bytes) -> void* {
        void* r = (void*)p;
        p += (bytes + 255) & ~(size_t)255;
        return r;
    };
    char* zstart = p;
    int*      bcnt     = (int*)     alloc((size_t)NB * 4);
    int*      cnt      = (int*)     alloc((size_t)NG * 4);
    float*    pooled   = (float*)   alloc((size_t)NG * 128 * 4);
    size_t zbytes = (size_t)(p - zstart);
    int*      bbase    = (int*)     alloc((size_t)(NB + 1) * 4);
    int*      bcur     = (int*)     alloc((size_t)NB * 4);
    int*      off      = (int*)     alloc((size_t)(N + 1) * 4);
    float*    dinv     = (float*)   alloc((size_t)N * 4);
    int*      bkt      = (int*)     alloc((size_t)E * 4);        // packed edges
    int*      csr      = (int*)     alloc((size_t)E * 4);        // src only
    unsigned* bufH     = (unsigned*)alloc((size_t)(N + 1) * 64 * 4); // bf16 hw' (+zero row)
    unsigned* bufB     = (unsigned*)alloc((size_t)N * 64 * 4);       // bf16 h
    (void)ws_size;

    const int tB = (E + 4095) / 4096;   // 4096-edge tiles

    hipMemsetAsync(zstart, 0, zbytes, stream);                 // bcnt+cnt+pooled
    hipMemsetAsync(bufH + (size_t)N * 64, 0, 256, stream);     // zero dummy row

    // CSR build: count -> scan -> bin -> per-bucket local fill
    k_bincount<<<tB, 256, 0, stream>>>(dst, bcnt, E, NB);
    k_bscan   <<<1, 256, 0, stream>>>(bcnt, bbase, bcur, NB);
    k_bin     <<<tB, 256, 0, stream>>>(src, dst, bcur, bkt, E, NB);
    k_fill2   <<<NB, 1024, 0, stream>>>(bkt, bbase, off, dinv, csr, N, E, NB);

    const int nrt = (N + 63) / 64;              // 64-row tiles
    const int gB  = (nrt + 1) / 2;              // 2 tiles per block
    const int aB  = (N + 3) / 4;                // 4 waves (nodes) per block

    // layer 1: hw' = bf16(dinv*(x @ W1)) ; h1 = bf16(relu(dinv*aggr + b1))
    k_gemm<false><<<gB, 256, 0, stream>>>((const void*)x, W1, dinv, bufH, N);
    k_aggr<<<aB, 256, 0, stream>>>(bufH, off, csr, dinv, b1, bufB, N);
    // layer 2
    k_gemm<true><<<gB, 256, 0, stream>>>((const void*)bufB, W2, dinv, bufH, N);
    k_aggr<<<aB, 256, 0, stream>>>(bufH, off, csr, dinv, b2, bufB, N);

    // mean pool
    const int NPW = 32;  // nodes per wave
    const int waves = (N + NPW - 1) / NPW;
    const int pB = (waves * 64 + 255) / 256;
    k_pool<<<pB, 256, 0, stream>>>(bufB, batch, pooled, cnt, N, NPW);

    // head
    k_head<<<NG, 128, 0, stream>>>(pooled, cnt, pW1, pb1, pW2, pb2, out);
}

// Round 14
// 220.877 us; speedup vs baseline: 2.5673x; 1.0045x over previous
//
#include <hip/hip_runtime.h>
#include <cstdint>
#include <cstddef>

// ---------------------------------------------------------------------------
// SimpleGNN: 2x GCNConv(128->128) + ReLU, global mean pool (64 graphs),
// MLP head 128->128->128 + ReLU, L2 row-normalize.
//
// R14 changes vs R13 (222us; aggr 2x49us = beyond-L2 random-service floor;
// gemm epilogue = 32 scalar 2B stores/thread):
//  - k_gemm: operand-swapped MFMA  acc = mfma(Wfrag, infrag, acc)  computes
//    D=(in@W)^T whose layout puts row=lane&15, 4 consecutive cols in regs
//    -> epilogue is 8 packed uint2 (8B) stores/thread. Load patterns are
//    unchanged (fragment address formulas swap into the same loads).
//  - k_bscan absorbs zeroing of pooled/cnt/bufH-dummy-row (1 less dispatch).
//  - k_aggr/binning unchanged (aggr pinned at 49us, 151MB, ~3.4TB/s across
//    4 rounds of ILP changes -> structural).
// ---------------------------------------------------------------------------

using short8 = __attribute__((ext_vector_type(8))) short;   // 8 bf16 (4 VGPRs)
using f32x4v = __attribute__((ext_vector_type(4))) float;   // 4 fp32

// ---------------- bf16 helpers ----------------

static __device__ __forceinline__ unsigned f2bf_rne(float f) {
    unsigned u = __float_as_uint(f);
    return (u + 0x7FFFu + ((u >> 16) & 1u)) >> 16;   // round-nearest-even
}
static __device__ __forceinline__ unsigned pack_bf2(float lo, float hi) {
    return f2bf_rne(lo) | (f2bf_rne(hi) << 16);
}
static __device__ __forceinline__ float bf_lo(unsigned v) {
    return __uint_as_float(v << 16);
}
static __device__ __forceinline__ float bf_hi(unsigned v) {
    return __uint_as_float(v & 0xFFFF0000u);
}

// ---------------- pass 0: bucket counts (bucket = 256 consecutive dst) ----

__global__ void k_bincount(const int* __restrict__ dst, int* __restrict__ bcnt,
                           int E, int NB) {
    __shared__ int h[256];
    int t = threadIdx.x;
    h[t] = 0;
    __syncthreads();
    int base_i = blockIdx.x * 4096;
#pragma unroll
    for (int j = 0; j < 16; ++j) {
        int i = base_i + j * 256 + t;
        if (i < E) atomicAdd(&h[dst[i] >> 8], 1);
    }
    __syncthreads();
    if (t < NB && h[t]) atomicAdd(&bcnt[t], h[t]);
}

// scan bucket counts -> bbase[0..NB], init bcur; also zero pooled/cnt and
// bufH dummy row (absorbed memsets). NB <= 256.
__global__ void k_bscan(const int* __restrict__ bcnt, int* __restrict__ bbase,
                        int* __restrict__ bcur, int NB,
                        float* __restrict__ pooled, int* __restrict__ cnt,
                        unsigned* __restrict__ hwdummy, int NG) {
    __shared__ int s[256];
    int t = threadIdx.x;
    int v = (t < NB) ? bcnt[t] : 0;
    s[t] = v;
    __syncthreads();
    for (int d = 1; d < 256; d <<= 1) {
        int x = (t >= d) ? s[t - d] : 0;
        __syncthreads();
        s[t] += x;
        __syncthreads();
    }
    if (t < NB) {
        int excl = s[t] - v;
        bbase[t] = excl;
        bcur[t]  = excl;
        if (t == NB - 1) bbase[NB] = s[t];   // total == E
    }
    // absorbed zero-inits (used only by later kernels)
    float4 z4 = {0.f, 0.f, 0.f, 0.f};
    int n4 = NG * 32;                        // pooled = NG*128 floats = NG*32 f4
    for (int i = t; i < n4; i += 256)
        reinterpret_cast<float4*>(pooled)[i] = z4;
    if (t < NG) cnt[t] = 0;
    if (t < 64) hwdummy[t] = 0u;             // 256B dummy row
}

// ---------------- pass 1: coarse binning (packed 4B edges) ----------------

__global__ void k_bin(const int* __restrict__ src, const int* __restrict__ dst,
                      int* __restrict__ bcur, int* __restrict__ bkt,
                      int E, int NB) {
    __shared__ int cnt[256];
    __shared__ int pos[256];
    int t = threadIdx.x;
    int base_i = blockIdx.x * 4096;

    cnt[t] = 0;
    __syncthreads();

    int b_[16];
    int v_[16];
#pragma unroll
    for (int j = 0; j < 16; ++j) {
        int i = base_i + j * 256 + t;        // coalesced
        if (i < E) {
            int s = src[i], d = dst[i];
            v_[j] = s | ((d & 255) << 16);   // src(16b) | dlocal(8b)
            int b = d >> 8;
            b_[j] = b;
            atomicAdd(&cnt[b], 1);
        } else {
            b_[j] = -1;
        }
    }
    __syncthreads();

    if (t < NB) {
        int c = cnt[t];
        pos[t] = c ? atomicAdd(&bcur[t], c) : 0;
    }
    __syncthreads();

#pragma unroll
    for (int j = 0; j < 16; ++j) {
        if (b_[j] >= 0) {
            int p = atomicAdd(&pos[b_[j]], 1);
            bkt[p] = v_[j];
        }
    }
}

// ---------------- pass 2: per-bucket local CSR build ----------------

__global__ void k_fill2(const int* __restrict__ bkt, const int* __restrict__ bbase,
                        int* __restrict__ off, float* __restrict__ dinv,
                        int* __restrict__ csr, int N, int E, int NB) {
    __shared__ int hist[256];
    __shared__ int loff[256];
    __shared__ int cur[256];
    int b = blockIdx.x, t = threadIdx.x;     // 1024 threads
    if (t < 256) hist[t] = 0;
    __syncthreads();

    int e0 = bbase[b], e1 = bbase[b + 1];
    for (int i = e0 + t; i < e1; i += 1024)
        atomicAdd(&hist[(bkt[i] >> 16) & 255], 1);
    __syncthreads();

    if (t < 256) loff[t] = hist[t];
    __syncthreads();
    for (int d = 1; d < 256; d <<= 1) {
        int x = 0;
        if (t < 256 && t >= d) x = loff[t - d];
        __syncthreads();
        if (t < 256) loff[t] += x;
        __syncthreads();
    }

    if (t < 256) {
        int n = (b << 8) + t;
        if (n < N) {
            int base = e0 + loff[t] - hist[t];   // exclusive
            off[n]  = base;
            cur[t]  = base;
            dinv[n] = rsqrtf((float)(hist[t] + 1));  // +1 self-loop
        }
    }
    if (b == NB - 1 && t == 0) off[N] = E;
    __syncthreads();

    for (int i = e0 + t; i < e1; i += 1024) {
        int v  = bkt[i];
        int dl = (v >> 16) & 255;
        int p  = atomicAdd(&cur[dl], 1);     // LDS atomic
        csr[p] = v & 0xFFFF;                 // src only
    }
}

// ---------------- MFMA GEMM: hw'[N,128](bf16) = dinv[row]*(in @ W) ----------
// 256 threads = 4 waves; wave = 16 rows x 128 cols; 2 row-tiles per block
// (W LDS-staged once). OPERAND-SWAPPED MFMA: acc = mfma(Wfrag, infrag, acc)
// computes D=(in@W)^T: D[(l>>4)*4+r][l&15] -> out[row = rbase+(l&15)]
// [col = cp*64+ct*16+(l>>4)*4+r]. r=0..3 = consecutive cols -> uint2 stores.

template<bool BF16IN>
__global__ __launch_bounds__(256) void k_gemm(
        const void* __restrict__ in_, const float* __restrict__ W,
        const float* __restrict__ dinv, unsigned* __restrict__ outbf, int N) {
    __shared__ unsigned short wbf[128 * 136];       // [col][k], pitch 136

    int t = threadIdx.x;
    int w  = t >> 6;
    int l  = t & 63;
    int lo = l & 15;
    int hi = l >> 4;

    // ---- stage W: coalesced f32 reads, bf16 LDS writes (once per block) ----
#pragma unroll
    for (int i = 0; i < 16; ++i) {
        int idx = (i * 256 + t) * 4;         // 4 consecutive cols, same k
        float4 wv = *reinterpret_cast<const float4*>(W + idx);
        int k = idx >> 7, c = idx & 127;
        wbf[(c    ) * 136 + k] = (unsigned short)f2bf_rne(wv.x);
        wbf[(c + 1) * 136 + k] = (unsigned short)f2bf_rne(wv.y);
        wbf[(c + 2) * 136 + k] = (unsigned short)f2bf_rne(wv.z);
        wbf[(c + 3) * 136 + k] = (unsigned short)f2bf_rne(wv.w);
    }
    __syncthreads();

    unsigned short* outS = (unsigned short*)outbf;

#pragma unroll
    for (int tt = 0; tt < 2; ++tt) {
        int rbase = (blockIdx.x * 2 + tt) * 64 + w * 16;
        if (rbase >= N) continue;            // no barriers below: safe
        int row  = rbase + lo;
        int rowc = (row < N) ? row : (N - 1);

        // in-frag ("B" of swapped mfma): lane l <- in[rbase+(l&15)][(l>>4)*8+j]
        short8 a[4];
        if constexpr (BF16IN) {
            const uint4* pu = (const uint4*)in_;
#pragma unroll
            for (int ks = 0; ks < 4; ++ks)
                a[ks] = __builtin_bit_cast(short8, pu[(size_t)rowc * 16 + ks * 4 + hi]);
        } else {
            const float4* pf = (const float4*)in_;
#pragma unroll
            for (int ks = 0; ks < 4; ++ks) {
                float4 fA = pf[(size_t)rowc * 32 + ks * 8 + hi * 2];
                float4 fB = pf[(size_t)rowc * 32 + ks * 8 + hi * 2 + 1];
                short8 s;
                s[0] = (short)f2bf_rne(fA.x); s[1] = (short)f2bf_rne(fA.y);
                s[2] = (short)f2bf_rne(fA.z); s[3] = (short)f2bf_rne(fA.w);
                s[4] = (short)f2bf_rne(fB.x); s[5] = (short)f2bf_rne(fB.y);
                s[6] = (short)f2bf_rne(fB.z); s[7] = (short)f2bf_rne(fB.w);
                a[ks] = s;
            }
        }

        f32x4v acc[8];
#pragma unroll
        for (int i = 0; i < 8; ++i) acc[i] = (f32x4v){0.f, 0.f, 0.f, 0.f};

        // W-frag ("A" of swapped mfma): lane l <- wbf[tile + (l&15)][...]
#pragma unroll
        for (int cp = 0; cp < 2; ++cp) {
            short8 b[4][4];                  // [ct][ks]
#pragma unroll
            for (int ct = 0; ct < 4; ++ct) {
                int col = cp * 64 + ct * 16 + lo;
#pragma unroll
                for (int ks = 0; ks < 4; ++ks)
                    b[ct][ks] = *reinterpret_cast<const short8*>(
                        &wbf[col * 136 + ks * 32 + hi * 8]);
            }
#pragma unroll
            for (int ks = 0; ks < 4; ++ks)
#pragma unroll
                for (int ct = 0; ct < 4; ++ct)
                    acc[cp * 4 + ct] = __builtin_amdgcn_mfma_f32_16x16x32_bf16(
                        b[ct][ks], a[ks], acc[cp * 4 + ct], 0, 0, 0);
        }

        // epilogue: lane owns row = rbase+lo; acc[i][0..3] = 4 consecutive
        // cols at cp*64+ct*16+hi*4 -> one uint2 (8B) store per acc index
        if (row < N) {
            float d = dinv[row];
#pragma unroll
            for (int i = 0; i < 8; ++i) {
                int colb = (i >> 2) * 64 + (i & 3) * 16 + hi * 4;
                uint2 o = { pack_bf2(acc[i][0] * d, acc[i][1] * d),
                            pack_bf2(acc[i][2] * d, acc[i][3] * d) };
                *reinterpret_cast<uint2*>(&outS[(size_t)row * 128 + colb]) = o;
            }
        }
    }
}

// ---------------- aggregation ----------------
// out[n] = relu(dinv[n]*(sum_e hw'[src_e] + hw'[n]) + b), hw' & out bf16.
// One wave per node; 4 edges per quad (quarter-wave x uint4 = 256B/row),
// 8 quads pipelined -> 8 outstanding gathers/lane.

__global__ void k_aggr(const unsigned* __restrict__ hw, const int* __restrict__ off,
                       const int* __restrict__ csr, const float* __restrict__ dinv,
                       const float* __restrict__ bias, unsigned* __restrict__ out, int N) {
    int wid  = (blockIdx.x * blockDim.x + threadIdx.x) >> 6;
    int lane = threadIdx.x & 63;
    if (wid >= N) return;
    int n  = wid;
    int q  = lane >> 4;                       // quarter 0..3
    int li = lane & 15;                       // lane owns cols 8*li .. 8*li+7

    const uint4* hw4 = reinterpret_cast<const uint4*>(hw);

    float a0 = 0.f, a1 = 0.f, a2 = 0.f, a3 = 0.f;
    float a4 = 0.f, a5 = 0.f, a6 = 0.f, a7 = 0.f;
    if (q == 0) {                             // self term hw'[n] in quarter 0
        uint4 v = hw4[(unsigned)(n << 4) + li];
        a0 = bf_lo(v.x); a1 = bf_hi(v.x);
        a2 = bf_lo(v.y); a3 = bf_hi(v.y);
        a4 = bf_lo(v.z); a5 = bf_hi(v.z);
        a6 = bf_lo(v.w); a7 = bf_hi(v.w);
    }

#define ACC8(v) \
    a0 += bf_lo(v.x); a1 += bf_hi(v.x); \
    a2 += bf_lo(v.y); a3 += bf_hi(v.y); \
    a4 += bf_lo(v.z); a5 += bf_hi(v.z); \
    a6 += bf_lo(v.w); a7 += bf_hi(v.w);

    int e = off[n], e1 = off[n + 1];
    while (e < e1) {
        int rem = e1 - e;
        int cnt = rem < 64 ? rem : 64;
        int s_l = N;                          // invalid -> zero row
        if (lane < cnt) s_l = csr[e + lane];
        int jn = (cnt + 3) >> 2;              // edge quads this batch
        int j = 0;
        for (; j + 8 <= jn; j += 8) {
            int s0 = __shfl(s_l, 4 * j + q);
            int s1 = __shfl(s_l, 4 * j + 4 + q);
            int s2 = __shfl(s_l, 4 * j + 8 + q);
            int s3 = __shfl(s_l, 4 * j + 12 + q);
            int s4 = __shfl(s_l, 4 * j + 16 + q);
            int s5 = __shfl(s_l, 4 * j + 20 + q);
            int s6 = __shfl(s_l, 4 * j + 24 + q);
            int s7 = __shfl(s_l, 4 * j + 28 + q);
            uint4 v0 = hw4[(unsigned)(s0 << 4) + li];
            uint4 v1 = hw4[(unsigned)(s1 << 4) + li];
            uint4 v2 = hw4[(unsigned)(s2 << 4) + li];
            uint4 v3 = hw4[(unsigned)(s3 << 4) + li];
            uint4 v4 = hw4[(unsigned)(s4 << 4) + li];
            uint4 v5 = hw4[(unsigned)(s5 << 4) + li];
            uint4 v6 = hw4[(unsigned)(s6 << 4) + li];
            uint4 v7 = hw4[(unsigned)(s7 << 4) + li];
            ACC8(v0) ACC8(v1) ACC8(v2) ACC8(v3)
            ACC8(v4) ACC8(v5) ACC8(v6) ACC8(v7)
        }
        for (; j + 4 <= jn; j += 4) {
            int s0 = __shfl(s_l, 4 * j + q);
            int s1 = __shfl(s_l, 4 * j + 4 + q);
            int s2 = __shfl(s_l, 4 * j + 8 + q);
            int s3 = __shfl(s_l, 4 * j + 12 + q);
            uint4 v0 = hw4[(unsigned)(s0 << 4) + li];
            uint4 v1 = hw4[(unsigned)(s1 << 4) + li];
            uint4 v2 = hw4[(unsigned)(s2 << 4) + li];
            uint4 v3 = hw4[(unsigned)(s3 << 4) + li];
            ACC8(v0) ACC8(v1) ACC8(v2) ACC8(v3)
        }
        for (; j < jn; ++j) {
            int   s = __shfl(s_l, 4 * j + q); // idx>=cnt lanes hold N -> zeros
            uint4 v = hw4[(unsigned)(s << 4) + li];
            ACC8(v)
        }
        e += cnt;
    }
#undef ACC8

    // combine quarters: q0+=q2, q1+=q3 (partner +32), then q0+=q1 (+16)
    int p1 = (lane + 32) & 63;
    a0 += __shfl(a0, p1); a1 += __shfl(a1, p1);
    a2 += __shfl(a2, p1); a3 += __shfl(a3, p1);
    a4 += __shfl(a4, p1); a5 += __shfl(a5, p1);
    a6 += __shfl(a6, p1); a7 += __shfl(a7, p1);
    int p2 = (lane + 16) & 63;
    a0 += __shfl(a0, p2); a1 += __shfl(a1, p2);
    a2 += __shfl(a2, p2); a3 += __shfl(a3, p2);
    a4 += __shfl(a4, p2); a5 += __shfl(a5, p2);
    a6 += __shfl(a6, p2); a7 += __shfl(a7, p2);

    if (q == 0) {
        float di = dinv[n];
        const float4* b4 = reinterpret_cast<const float4*>(bias);
        float4 bA = b4[2 * li], bB = b4[2 * li + 1];
        a0 = fmaxf(fmaf(a0, di, bA.x), 0.f); a1 = fmaxf(fmaf(a1, di, bA.y), 0.f);
        a2 = fmaxf(fmaf(a2, di, bA.z), 0.f); a3 = fmaxf(fmaf(a3, di, bA.w), 0.f);
        a4 = fmaxf(fmaf(a4, di, bB.x), 0.f); a5 = fmaxf(fmaf(a5, di, bB.y), 0.f);
        a6 = fmaxf(fmaf(a6, di, bB.z), 0.f); a7 = fmaxf(fmaf(a7, di, bB.w), 0.f);
        uint4 r = { pack_bf2(a0, a1), pack_bf2(a2, a3),
                    pack_bf2(a4, a5), pack_bf2(a6, a7) };
        reinterpret_cast<uint4*>(out)[(unsigned)(n << 4) + li] = r;
    }
}

// ---------------- global mean pool (batch is sorted, h in bf16) ----------------

__global__ void k_pool(const unsigned* __restrict__ h, const int* __restrict__ batch,
                       float* __restrict__ pooled, int* __restrict__ cnt,
                       int N, int npw) {
    int wid  = (blockIdx.x * blockDim.x + threadIdx.x) >> 6;
    int lane = threadIdx.x & 63;
    int n0 = wid * npw;
    if (n0 >= N) return;
    int n1 = n0 + npw; if (n1 > N) n1 = N;

    float ax = 0.f, ay = 0.f;
    int g = batch[n0];
    int c = 0;
    for (int n = n0; n < n1; ++n) {
        int gn = batch[n];
        if (gn != g) {
            atomicAdd(&pooled[g * 128 + 2 * lane],     ax);
            atomicAdd(&pooled[g * 128 + 2 * lane + 1], ay);
            if (lane == 0) atomicAdd(&cnt[g], c);
            ax = 0.f; ay = 0.f; c = 0; g = gn;
        }
        unsigned v = h[(size_t)n * 64 + lane];
        ax += bf_lo(v); ay += bf_hi(v); ++c;
    }
    atomicAdd(&pooled[g * 128 + 2 * lane],     ax);
    atomicAdd(&pooled[g * 128 + 2 * lane + 1], ay);
    if (lane == 0) atomicAdd(&cnt[g], c);
}

// ---------------- MLP head + L2 normalize (tiny: 64 x 128) ----------------

__global__ void k_head(const float* __restrict__ pooled, const int* __restrict__ cnt,
                       const float* __restrict__ pW1, const float* __restrict__ pb1,
                       const float* __restrict__ pW2, const float* __restrict__ pb2,
                       float* __restrict__ out) {
    __shared__ float hg[128];
    __shared__ float z1[128];
    __shared__ float red[128];
    int g = blockIdx.x, t = threadIdx.x;   // 128 threads

    float c = fmaxf((float)cnt[g], 1.0f);
    hg[t] = pooled[g * 128 + t] / c;
    __syncthreads();

    float a = pb1[t];
#pragma unroll 8
    for (int k = 0; k < 128; ++k) a = fmaf(hg[k], pW1[k * 128 + t], a);
    z1[t] = fmaxf(a, 0.f);
    __syncthreads();

    float z = pb2[t];
#pragma unroll 8
    for (int k = 0; k < 128; ++k) z = fmaf(z1[k], pW2[k * 128 + t], z);

    red[t] = z * z;
    __syncthreads();
    for (int d = 64; d > 0; d >>= 1) {
        if (t < d) red[t] += red[t + d];
        __syncthreads();
    }
    float nrm = fmaxf(sqrtf(red[0]), 1e-12f);
    out[g * 128 + t] = z / nrm;
}

// ---------------------------------------------------------------------------

extern "C" void kernel_launch(void* const* d_in, const int* in_sizes, int n_in,
                              void* d_out, int out_size, void* d_ws, size_t ws_size,
                              hipStream_t stream) {
    const float* x    = (const float*)d_in[0];
    const int*   eidx = (const int*)  d_in[1];
    const int*   batch= (const int*)  d_in[2];
    const float* W1   = (const float*)d_in[4];
    const float* b1   = (const float*)d_in[5];
    const float* W2   = (const float*)d_in[6];
    const float* b2   = (const float*)d_in[7];
    const float* pW1  = (const float*)d_in[8];
    const float* pb1  = (const float*)d_in[9];
    const float* pW2  = (const float*)d_in[10];
    const float* pb2  = (const float*)d_in[11];
    float* out = (float*)d_out;

    const int N  = in_sizes[0] / 128;
    const int E  = in_sizes[1] / 2;
    const int NG = out_size / 128;
    const int NB = (N + 255) >> 8;    // buckets of 256 nodes; NB<=256 (N<65536)

    const int* src = eidx;      // edge_index[0]
    const int* dst = eidx + E;  // edge_index[1]

    // workspace carve-up (256B aligned)
    char* p = (char*)d_ws;
    auto alloc = [&](size_t bytes) -> void* {
        void* r = (void*)p;
        p += (bytes + 255) & ~(size_t)255;
        return r;
    };
    int*      bcnt     = (int*)     alloc((size_t)NB * 4);
    int*      cnt      = (int*)     alloc((size_t)NG * 4);
    float*    pooled   = (float*)   alloc((size_t)NG * 128 * 4);
    int*      bbase    = (int*)     alloc((size_t)(NB + 1) * 4);
    int*      bcur     = (int*)     alloc((size_t)NB * 4);
    int*      off      = (int*)     alloc((size_t)(N + 1) * 4);
    float*    dinv     = (float*)   alloc((size_t)N * 4);
    int*      bkt      = (int*)     alloc((size_t)E * 4);        // packed edges
    int*      csr      = (int*)     alloc((size_t)E * 4);        // src only
    unsigned* bufH     = (unsigned*)alloc((size_t)(N + 1) * 64 * 4); // bf16 hw' (+zero row)
    unsigned* bufB     = (unsigned*)alloc((size_t)N * 64 * 4);       // bf16 h
    (void)ws_size;

    const int tB = (E + 4095) / 4096;   // 4096-edge tiles

    hipMemsetAsync(bcnt, 0, (size_t)NB * 4, stream);   // only pre-bincount zero

    // CSR build: count -> scan(+absorbed zeroing) -> bin -> per-bucket fill
    k_bincount<<<tB, 256, 0, stream>>>(dst, bcnt, E, NB);
    k_bscan   <<<1, 256, 0, stream>>>(bcnt, bbase, bcur, NB,
                                      pooled, cnt, bufH + (size_t)N * 64, NG);
    k_bin     <<<tB, 256, 0, stream>>>(src, dst, bcur, bkt, E, NB);
    k_fill2   <<<NB, 1024, 0, stream>>>(bkt, bbase, off, dinv, csr, N, E, NB);

    const int nrt = (N + 63) / 64;              // 64-row tiles
    const int gB  = (nrt + 1) / 2;              // 2 tiles per block
    const int aB  = (N + 3) / 4;                // 4 waves (nodes) per block

    // layer 1: hw' = bf16(dinv*(x @ W1)) ; h1 = bf16(relu(dinv*aggr + b1))
    k_gemm<false><<<gB, 256, 0, stream>>>((const void*)x, W1, dinv, bufH, N);
    k_aggr<<<aB, 256, 0, stream>>>(bufH, off, csr, dinv, b1, bufB, N);
    // layer 2
    k_gemm<true><<<gB, 256, 0, stream>>>((const void*)bufB, W2, dinv, bufH, N);
    k_aggr<<<aB, 256, 0, stream>>>(bufH, off, csr, dinv, b2, bufB, N);

    // mean pool
    const int NPW = 32;  // nodes per wave
    const int waves = (N + NPW - 1) / NPW;
    const int pB = (waves * 64 + 255) / 256;
    k_pool<<<pB, 256, 0, stream>>>(bufB, batch, pooled, cnt, N, NPW);

    // head
    k_head<<<NG, 128, 0, stream>>>(pooled, cnt, pW1, pb1, pW2, pb2, out);
}